// Round 1
// baseline (40672.888 us; speedup 1.0000x reference)
//
#include <hip/hip_runtime.h>
#include <math.h>

#define DIV_UP(a,b) (((a)+(b)-1)/(b))

__device__ __forceinline__ float sigmoidf_(float x){ return 1.0f/(1.0f+expf(-x)); }

// ------------------------------------------------------------------
// Direct conv, NHWC, weights HWIO. One thread per output element.
// Consecutive threads = consecutive out-channels (coalesced weight reads,
// broadcast input reads within a wave).
// ------------------------------------------------------------------
__global__ __launch_bounds__(256) void conv2d_kernel(
    const float* __restrict__ x, const float* __restrict__ w,
    const float* __restrict__ bias, float* __restrict__ out,
    int N,int H,int W,int Ci,int Ho,int Wo,int Co,
    int KH,int KW,int padH,int padW,int doRelu)
{
  long idx = (long)blockIdx.x*blockDim.x + threadIdx.x;
  long total = (long)N*Ho*Wo*Co;
  if (idx >= total) return;
  int co = (int)(idx % Co);
  long pix = idx / Co;
  int wo = (int)(pix % Wo); long t2 = pix / Wo;
  int ho = (int)(t2 % Ho); int n = (int)(t2 / Ho);
  float acc = bias[co];
  for (int kh = 0; kh < KH; ++kh) {
    int ih = ho - padH + kh;
    if (ih < 0 || ih >= H) continue;
    for (int kw = 0; kw < KW; ++kw) {
      int iw = wo - padW + kw;
      if (iw < 0 || iw >= W) continue;
      const float* xp = x + (((long)n*H + ih)*W + iw)*Ci;
      const float* wp = w + ((long)(kh*KW + kw)*Ci)*Co + co;
      if ((Ci & 3) == 0) {
        #pragma unroll 4
        for (int ci = 0; ci < Ci; ci += 4) {
          float4 xv = *reinterpret_cast<const float4*>(xp + ci);
          acc = fmaf(xv.x, wp[(long)(ci+0)*Co], acc);
          acc = fmaf(xv.y, wp[(long)(ci+1)*Co], acc);
          acc = fmaf(xv.z, wp[(long)(ci+2)*Co], acc);
          acc = fmaf(xv.w, wp[(long)(ci+3)*Co], acc);
        }
      } else {
        for (int ci = 0; ci < Ci; ++ci) acc = fmaf(xp[ci], wp[(long)ci*Co], acc);
      }
    }
  }
  if (doRelu) acc = fmaxf(acc, 0.0f);
  out[idx] = acc;
}

// ------------------------------------------------------------------
// Max pool, NHWC. pad_lo = 0 in all uses (lax SAME puts the odd pad at hi);
// out-of-range taps are simply skipped (== -inf identity).
// ------------------------------------------------------------------
__global__ __launch_bounds__(256) void maxpool_kernel(
    const float* __restrict__ x, float* __restrict__ out,
    int N,int H,int W,int C,int Ho,int Wo,int sH,int sW,int kH,int kW)
{
  long idx = (long)blockIdx.x*blockDim.x + threadIdx.x;
  long total = (long)N*Ho*Wo*C;
  if (idx >= total) return;
  int c = (int)(idx % C);
  long pix = idx / C;
  int wo = (int)(pix % Wo); long t2 = pix / Wo;
  int ho = (int)(t2 % Ho); int n = (int)(t2 / Ho);
  float m = -INFINITY;
  for (int i = 0; i < kH; ++i) {
    int ih = ho*sH + i;
    if (ih >= H) continue;
    for (int j = 0; j < kW; ++j) {
      int iw = wo*sW + j;
      if (iw >= W) continue;
      m = fmaxf(m, x[(((long)n*H + ih)*W + iw)*C + c]);
    }
  }
  out[idx] = m;
}

// ------------------------------------------------------------------
// BN (training) stats: per-channel sum & sumsq via per-block partials +
// global atomics. sums must be zeroed beforehand. C <= 512, blockDim 256.
// ------------------------------------------------------------------
__global__ __launch_bounds__(256) void bn_sums_kernel(
    const float* __restrict__ x, float* __restrict__ sums, long nPix, int C)
{
  long rowsPer = (nPix + gridDim.x - 1) / gridDim.x;
  long r0 = (long)blockIdx.x * rowsPer;
  long r1 = r0 + rowsPer; if (r1 > nPix) r1 = nPix;
  float a0 = 0.f, q0 = 0.f, a1 = 0.f, q1 = 0.f;
  for (long r = r0; r < r1; ++r) {
    const float* xp = x + r*C;
    {
      float v = xp[threadIdx.x];
      a0 += v; q0 += v*v;
    }
    if (C > 256) {
      float v = xp[256 + threadIdx.x];
      a1 += v; q1 += v*v;
    }
  }
  atomicAdd(&sums[threadIdx.x], a0);
  atomicAdd(&sums[C + threadIdx.x], q0);
  if (C > 256) {
    atomicAdd(&sums[256 + threadIdx.x], a1);
    atomicAdd(&sums[C + 256 + threadIdx.x], q1);
  }
}

__global__ __launch_bounds__(256) void bn_apply_relu_kernel(
    float* __restrict__ x, const float* __restrict__ sums,
    const float* __restrict__ scale, const float* __restrict__ bias,
    long total, int C, float invN)
{
  long idx = (long)blockIdx.x*blockDim.x + threadIdx.x;
  if (idx >= total) return;
  int c = (int)(idx % C);
  float mean = sums[c] * invN;
  float var  = sums[C + c] * invN - mean*mean;
  float rstd = rsqrtf(var + 1e-5f);
  float v = (x[idx] - mean) * rstd * scale[c] + bias[c];
  x[idx] = fmaxf(v, 0.0f);
}

// ------------------------------------------------------------------
// fp32 tiled GEMM: C[M,N] = A[M,K] @ B[K,N] + bias. 64x64 tile, TK=16,
// 256 threads, 4x4 per thread. K must be a multiple of 16 (true for all
// uses: 7680, 512, 1024). blockIdx.z selects among up to 3 (B,bias,C) sets
// sharing the same A (q/k/v, fwd/rev LSTM pre-GEMMs).
// ------------------------------------------------------------------
struct GemmOut { const float* B; const float* bias; float* C; };

__global__ __launch_bounds__(256) void gemm64_kernel(
    const float* __restrict__ A, GemmOut g0, GemmOut g1, GemmOut g2,
    int M, int N, int K)
{
  GemmOut g = (blockIdx.z == 0) ? g0 : (blockIdx.z == 1 ? g1 : g2);
  const float* __restrict__ B = g.B;
  __shared__ float As[16][65];
  __shared__ float Bs[16][68];
  int tid = threadIdx.x;
  int m0 = blockIdx.y * 64, n0 = blockIdx.x * 64;
  int ty = tid >> 4, tx = tid & 15;
  int ar = tid >> 2, ac = (tid & 3) << 2;
  int br = tid >> 4, bc = (tid & 15) << 2;
  float acc[4][4] = {};
  for (int k0 = 0; k0 < K; k0 += 16) {
    float4 av = make_float4(0.f, 0.f, 0.f, 0.f);
    if (m0 + ar < M)
      av = *reinterpret_cast<const float4*>(A + (long)(m0 + ar)*K + k0 + ac);
    As[ac+0][ar] = av.x; As[ac+1][ar] = av.y; As[ac+2][ar] = av.z; As[ac+3][ar] = av.w;
    float4 bv;
    if (n0 + bc + 3 < N) {
      bv = *reinterpret_cast<const float4*>(B + (long)(k0 + br)*N + n0 + bc);
    } else {
      const float* bp = B + (long)(k0 + br)*N;
      bv.x = (n0+bc+0 < N) ? bp[n0+bc+0] : 0.f;
      bv.y = (n0+bc+1 < N) ? bp[n0+bc+1] : 0.f;
      bv.z = (n0+bc+2 < N) ? bp[n0+bc+2] : 0.f;
      bv.w = (n0+bc+3 < N) ? bp[n0+bc+3] : 0.f;
    }
    Bs[br][bc+0] = bv.x; Bs[br][bc+1] = bv.y; Bs[br][bc+2] = bv.z; Bs[br][bc+3] = bv.w;
    __syncthreads();
    #pragma unroll
    for (int kk = 0; kk < 16; ++kk) {
      float a0 = As[kk][(ty<<2)+0], a1 = As[kk][(ty<<2)+1];
      float a2 = As[kk][(ty<<2)+2], a3 = As[kk][(ty<<2)+3];
      float b0 = Bs[kk][(tx<<2)+0], b1 = Bs[kk][(tx<<2)+1];
      float b2 = Bs[kk][(tx<<2)+2], b3 = Bs[kk][(tx<<2)+3];
      acc[0][0] = fmaf(a0,b0,acc[0][0]); acc[0][1] = fmaf(a0,b1,acc[0][1]);
      acc[0][2] = fmaf(a0,b2,acc[0][2]); acc[0][3] = fmaf(a0,b3,acc[0][3]);
      acc[1][0] = fmaf(a1,b0,acc[1][0]); acc[1][1] = fmaf(a1,b1,acc[1][1]);
      acc[1][2] = fmaf(a1,b2,acc[1][2]); acc[1][3] = fmaf(a1,b3,acc[1][3]);
      acc[2][0] = fmaf(a2,b0,acc[2][0]); acc[2][1] = fmaf(a2,b1,acc[2][1]);
      acc[2][2] = fmaf(a2,b2,acc[2][2]); acc[2][3] = fmaf(a2,b3,acc[2][3]);
      acc[3][0] = fmaf(a3,b0,acc[3][0]); acc[3][1] = fmaf(a3,b1,acc[3][1]);
      acc[3][2] = fmaf(a3,b2,acc[3][2]); acc[3][3] = fmaf(a3,b3,acc[3][3]);
    }
    __syncthreads();
  }
  #pragma unroll
  for (int i = 0; i < 4; ++i) {
    int m = m0 + (ty<<2) + i;
    if (m >= M) continue;
    #pragma unroll
    for (int j = 0; j < 4; ++j) {
      int n = n0 + (tx<<2) + j;
      if (n < N) g.C[(long)m*N + n] = acc[i][j] + g.bias[n];
    }
  }
}

// ------------------------------------------------------------------
// Attention (T=15, D=512), one block per batch element.
// scores[t][s] = q[t]·k[s]/32, softmax over s, out[s,:] = sum_t P[t][s]*v[t,:]
// ------------------------------------------------------------------
__global__ __launch_bounds__(256) void attention_kernel(
    const float* __restrict__ q, const float* __restrict__ k,
    const float* __restrict__ v, float* __restrict__ out, int T, int D)
{
  int b = blockIdx.x;
  int tid = threadIdx.x;
  __shared__ float P[15][16];
  if (tid < T*T) {
    int t = tid / T, s = tid % T;
    const float* qp = q + ((long)b*T + t)*D;
    const float* kp = k + ((long)b*T + s)*D;
    float acc = 0.f;
    for (int d = 0; d < D; d += 4) {
      float4 qv = *reinterpret_cast<const float4*>(qp + d);
      float4 kv = *reinterpret_cast<const float4*>(kp + d);
      acc += qv.x*kv.x + qv.y*kv.y + qv.z*kv.z + qv.w*kv.w;
    }
    P[t][s] = acc * (1.0f/32.0f);
  }
  __syncthreads();
  if (tid < T) {
    float mx = -INFINITY;
    for (int s = 0; s < T; ++s) mx = fmaxf(mx, P[tid][s]);
    float sum = 0.f;
    for (int s = 0; s < T; ++s) { float e = expf(P[tid][s] - mx); P[tid][s] = e; sum += e; }
    float inv = 1.0f / sum;
    for (int s = 0; s < T; ++s) P[tid][s] *= inv;
  }
  __syncthreads();
  for (int idx = tid; idx < T*D; idx += 256) {
    int s = idx / D, kk2 = idx % D;
    float acc = 0.f;
    #pragma unroll
    for (int t = 0; t < 15; ++t) acc += v[((long)b*15 + t)*D + kk2] * P[t][s];
    out[((long)b*T + s)*D + kk2] = acc;
  }
}

// ------------------------------------------------------------------
// One LSTM step. pre = x@wx+b precomputed (B,T,4H). Each thread: one (b,j),
// 4 recurrent dots over h (staged in LDS). c updated in place, h double-
// buffered (h_in -> h_out). Gate order i,f,g,o. y written at row t with
// given stride/offset (direct concat write).
// ------------------------------------------------------------------
__global__ __launch_bounds__(256) void lstm_step_kernel(
    const float* __restrict__ pre, const float* __restrict__ wh,
    const float* __restrict__ h_in, float* __restrict__ h_out,
    float* __restrict__ c, float* __restrict__ y,
    int t, int T, int H, int ystride)
{
  __shared__ float hs[512];
  int blk = blockIdx.x;
  int b = (blk * 256) / H;
  int jbase = (blk * 256) % H;
  int j = jbase + threadIdx.x;
  for (int k2 = threadIdx.x; k2 < H; k2 += 256) hs[k2] = h_in[b*H + k2];
  __syncthreads();
  int H4 = 4*H;
  float ai = 0.f, af = 0.f, ag = 0.f, ao = 0.f;
  #pragma unroll 4
  for (int k2 = 0; k2 < H; ++k2) {
    float hk = hs[k2];
    const float* wr = wh + (long)k2*H4;
    ai = fmaf(hk, wr[j],       ai);
    af = fmaf(hk, wr[H + j],   af);
    ag = fmaf(hk, wr[2*H + j], ag);
    ao = fmaf(hk, wr[3*H + j], ao);
  }
  const float* p = pre + ((long)b*T + t)*H4;
  float gi = sigmoidf_(p[j]       + ai);
  float gf = sigmoidf_(p[H + j]   + af);
  float gg = tanhf    (p[2*H + j] + ag);
  float go = sigmoidf_(p[3*H + j] + ao);
  int ci = b*H + j;
  float cn = gf * c[ci] + gi * gg;
  c[ci] = cn;
  float hn = go * tanhf(cn);
  h_out[ci] = hn;
  y[((long)b*T + t)*ystride + j] = hn;
}

// ------------------------------------------------------------------
// Host orchestration
// ------------------------------------------------------------------
extern "C" void kernel_launch(void* const* d_in, const int* in_sizes, int n_in,
                              void* d_out, int out_size, void* d_ws, size_t ws_size,
                              hipStream_t stream)
{
  const float* x       = (const float*)d_in[0];
  const float* c1w     = (const float*)d_in[1];  const float* c1b = (const float*)d_in[2];
  const float* c2w     = (const float*)d_in[3];  const float* c2b = (const float*)d_in[4];
  const float* c3w     = (const float*)d_in[5];  const float* c3b = (const float*)d_in[6];
  const float* bn1s    = (const float*)d_in[7];  const float* bn1b = (const float*)d_in[8];
  const float* c4w     = (const float*)d_in[9];  const float* c4b = (const float*)d_in[10];
  const float* bn2s    = (const float*)d_in[11]; const float* bn2b = (const float*)d_in[12];
  const float* c5w     = (const float*)d_in[13]; const float* c5b = (const float*)d_in[14];
  const float* bn3s    = (const float*)d_in[15]; const float* bn3b = (const float*)d_in[16];
  const float* c6w     = (const float*)d_in[17]; const float* c6b = (const float*)d_in[18];
  const float* bn4s    = (const float*)d_in[19]; const float* bn4b = (const float*)d_in[20];
  const float* c7w     = (const float*)d_in[21]; const float* c7b = (const float*)d_in[22];
  const float* bn5s    = (const float*)d_in[23]; const float* bn5b = (const float*)d_in[24];
  const float* wq      = (const float*)d_in[25]; const float* bq = (const float*)d_in[26];
  const float* wk      = (const float*)d_in[27]; const float* bk = (const float*)d_in[28];
  const float* wv      = (const float*)d_in[29]; const float* bv = (const float*)d_in[30];
  const float* l1f_wx  = (const float*)d_in[31]; const float* l1f_wh = (const float*)d_in[32]; const float* l1f_b = (const float*)d_in[33];
  const float* l1r_wx  = (const float*)d_in[34]; const float* l1r_wh = (const float*)d_in[35]; const float* l1r_b = (const float*)d_in[36];
  const float* l2f_wx  = (const float*)d_in[37]; const float* l2f_wh = (const float*)d_in[38]; const float* l2f_b = (const float*)d_in[39];
  const float* l2r_wx  = (const float*)d_in[40]; const float* l2r_wh = (const float*)d_in[41]; const float* l2r_b = (const float*)d_in[42];
  const float* wo      = (const float*)d_in[43]; const float* bo = (const float*)d_in[44];
  float* outp = (float*)d_out;

  float* ws = (float*)d_ws;
  // ping-pong regions
  float* A  = ws;                       // 33,554,432 floats (128 MB)
  float* Bb = ws + 33554432;            //  8,388,608 floats (32 MB)
  float* bnsums = ws + 41943040;        //  1,024 floats
  // small arena inside Bb (only live after the conv stack is done)
  float* q     = Bb;
  float* kk_   = Bb + 245760;
  float* v     = Bb + 491520;
  float* ao    = Bb + 737280;
  float* pre1f = Bb + 983040;
  float* pre1r = Bb + 1474560;
  float* x1    = Bb + 1966080;
  float* pre2f = Bb + 2211840;
  float* pre2r = Bb + 3194880;
  float* x2    = Bb + 4177920;
  float* h1a   = Bb + 4669440;
  float* h1b   = h1a + 8192;
  float* cc1   = h1b + 8192;
  float* h2a   = cc1 + 8192;
  float* h2b   = h2a + 16384;
  float* cc2   = h2b + 16384;

  auto conv = [&](const float* in, const float* w, const float* b, float* out,
                  int N,int H,int W,int Ci,int Ho,int Wo,int Co,
                  int KH,int KW,int pH,int pW,int relu){
    long total = (long)N*Ho*Wo*Co;
    conv2d_kernel<<<(int)DIV_UP(total,256),256,0,stream>>>(in,w,b,out,N,H,W,Ci,Ho,Wo,Co,KH,KW,pH,pW,relu);
  };
  auto pool = [&](const float* in, float* out, int N,int H,int W,int C,
                  int Ho,int Wo,int sH,int sW){
    long total = (long)N*Ho*Wo*C;
    maxpool_kernel<<<(int)DIV_UP(total,256),256,0,stream>>>(in,out,N,H,W,C,Ho,Wo,sH,sW,2,2);
  };
  auto bn = [&](float* buf, long nPix, int C, const float* s, const float* b){
    hipMemsetAsync(bnsums, 0, sizeof(float)*2*C, stream);
    bn_sums_kernel<<<256,256,0,stream>>>(buf, bnsums, nPix, C);
    long total = nPix * C;
    bn_apply_relu_kernel<<<(int)DIV_UP(total,256),256,0,stream>>>(buf, bnsums, s, b, total, C, 1.0f/(float)nPix);
  };
  auto gemm = [&](const float* Am, GemmOut g0, GemmOut g1, GemmOut g2, int nz,
                  int M, int N, int K){
    dim3 grid(DIV_UP(N,64), DIV_UP(M,64), nz);
    gemm64_kernel<<<grid,256,0,stream>>>(Am, g0, g1, g2, M, N, K);
  };

  // ---- conv stack ----
  conv(x,  c1w, c1b, A,  32,64,256,3,   64,256,64,  3,3,1,1, 1);
  pool(A,  Bb, 32,64,256,64,  32,128, 2,2);
  conv(Bb, c2w, c2b, A,  32,32,128,64,  32,128,128, 3,3,1,1, 1);
  pool(A,  Bb, 32,32,128,128, 16,64,  2,2);
  conv(Bb, c3w, c3b, A,  32,16,64,128,  16,64,256,  3,3,1,1, 0);
  bn(A,  32768, 256, bn1s, bn1b);
  conv(A,  c4w, c4b, Bb, 32,16,64,256,  16,64,256,  3,3,1,1, 0);
  bn(Bb, 32768, 256, bn2s, bn2b);
  pool(Bb, A,  32,16,64,256,  16,32,  1,2);
  conv(A,  c5w, c5b, Bb, 32,16,32,256,  16,32,512,  3,3,1,1, 0);
  bn(Bb, 16384, 512, bn3s, bn3b);
  conv(Bb, c6w, c6b, A,  32,16,32,512,  16,32,512,  3,3,1,1, 0);
  bn(A,  16384, 512, bn4s, bn4b);
  pool(A,  Bb, 32,16,32,512,  16,16,  1,2);
  conv(Bb, c7w, c7b, A,  32,16,16,512,  15,15,512,  2,2,0,0, 0);
  bn(A,  7200, 512, bn5s, bn5b);

  // ---- attention ----  A viewed as (480, 7680)
  {
    GemmOut gq{wq, bq, q}, gk{wk, bk, kk_}, gv{wv, bv, v};
    gemm(A, gq, gk, gv, 3, 480, 512, 7680);
    attention_kernel<<<32,256,0,stream>>>(q, kk_, v, ao, 15, 512);
  }

  // ---- LSTM stack 1 (H=256) ----
  {
    GemmOut gf{l1f_wx, l1f_b, pre1f}, gr{l1r_wx, l1r_b, pre1r};
    gemm(ao, gf, gr, gf, 2, 480, 1024, 512);
    hipMemsetAsync(h1a, 0, sizeof(float)*8192, stream);
    hipMemsetAsync(cc1, 0, sizeof(float)*8192, stream);
    float* hb[2] = {h1a, h1b};
    int p = 0;
    for (int i = 0; i < 15; ++i) {     // forward -> first half of x1
      lstm_step_kernel<<<32,256,0,stream>>>(pre1f, l1f_wh, hb[p], hb[1-p], cc1, x1,       i, 15, 256, 512);
      p ^= 1;
    }
    for (int i = 14; i >= 0; --i) {    // reverse (carry continues) -> second half
      lstm_step_kernel<<<32,256,0,stream>>>(pre1r, l1r_wh, hb[p], hb[1-p], cc1, x1 + 256, i, 15, 256, 512);
      p ^= 1;
    }
  }

  // ---- LSTM stack 2 (H=512) ----
  {
    GemmOut gf{l2f_wx, l2f_b, pre2f}, gr{l2r_wx, l2r_b, pre2r};
    gemm(x1, gf, gr, gf, 2, 480, 2048, 512);
    hipMemsetAsync(h2a, 0, sizeof(float)*16384, stream);
    hipMemsetAsync(cc2, 0, sizeof(float)*16384, stream);
    float* hb[2] = {h2a, h2b};
    int p = 0;
    for (int i = 0; i < 15; ++i) {     // forward y2b -> second half of x2
      lstm_step_kernel<<<64,256,0,stream>>>(pre2f, l2f_wh, hb[p], hb[1-p], cc2, x2 + 512, i, 15, 512, 1024);
      p ^= 1;
    }
    for (int i = 14; i >= 0; --i) {    // reverse y3 -> first half of x2
      lstm_step_kernel<<<64,256,0,stream>>>(pre2r, l2r_wh, hb[p], hb[1-p], cc2, x2,       i, 15, 512, 1024);
      p ^= 1;
    }
  }

  // ---- classifier ----
  {
    GemmOut go{wo, bo, outp};
    gemm(x2, go, go, go, 1, 480, 1000, 1024);
  }
}

// Round 2
// 11063.422 us; speedup vs baseline: 3.6763x; 3.6763x over previous
//
#include <hip/hip_runtime.h>
#include <math.h>

#define DIV_UP(a,b) (((a)+(b)-1)/(b))

__device__ __forceinline__ float sigmoidf_(float x){ return 1.0f/(1.0f+expf(-x)); }

// ------------------------------------------------------------------
// Implicit-GEMM conv, NHWC x, HWIO w. C[M=N*Ho*Wo, Co] = im2col(x) @ w.
// 64x64 output tile, TK=16, 256 threads, 4x4 accum per thread.
// w flattened is exactly B[k][Co] with k=(kh*KW+kw)*Ci+ci.
// ------------------------------------------------------------------
__global__ __launch_bounds__(256) void conv_gemm_kernel(
    const float* __restrict__ x, const float* __restrict__ w,
    const float* __restrict__ bias, float* __restrict__ out,
    int N,int H,int W,int Ci,int Ho,int Wo,int Co,
    int KH,int KW,int padH,int padW,int doRelu,int M,int K)
{
  __shared__ float As[16][65];
  __shared__ float Bs[16][68];
  int tid = threadIdx.x;
  int n0 = blockIdx.x * 64;          // Co offset
  int m0 = blockIdx.y * 64;          // pixel offset
  int ty = tid >> 4, tx = tid & 15;
  int ar = tid >> 2, ac = (tid & 3) << 2;
  int br = tid >> 4, bc = (tid & 15) << 2;

  // decode this thread's A-row (pixel) once
  int m = m0 + ar;
  bool mvalid = m < M;
  int mm = mvalid ? m : 0;
  int wo = mm % Wo; int t2 = mm / Wo;
  int ho = t2 % Ho; int nimg = t2 / Ho;

  bool fast = ((Ci & 15) == 0);      // k-chunk of 4 never crosses a (kh,kw) patch
  float acc[4][4] = {};

  for (int k0 = 0; k0 < K; k0 += 16) {
    // ---- A gather (im2col) ----
    float a0=0.f,a1=0.f,a2=0.f,a3=0.f;
    if (fast) {
      int k = k0 + ac;
      int ci = k % Ci; int pq = k / Ci;
      int kw = pq % KW; int kh = pq / KW;
      int ih = ho - padH + kh, iw = wo - padW + kw;
      if (mvalid && ih >= 0 && ih < H && iw >= 0 && iw < W) {
        float4 v = *reinterpret_cast<const float4*>(
            x + (((long)nimg*H + ih)*W + iw)*Ci + ci);
        a0=v.x; a1=v.y; a2=v.z; a3=v.w;
      }
    } else {
      float av[4] = {0.f,0.f,0.f,0.f};
      #pragma unroll
      for (int i = 0; i < 4; ++i) {
        int k = k0 + ac + i;
        if (mvalid && k < K) {
          int ci = k % Ci; int pq = k / Ci;
          int kw = pq % KW; int kh = pq / KW;
          int ih = ho - padH + kh, iw = wo - padW + kw;
          if (ih >= 0 && ih < H && iw >= 0 && iw < W)
            av[i] = x[(((long)nimg*H + ih)*W + iw)*Ci + ci];
        }
      }
      a0=av[0]; a1=av[1]; a2=av[2]; a3=av[3];
    }
    As[ac+0][ar]=a0; As[ac+1][ar]=a1; As[ac+2][ar]=a2; As[ac+3][ar]=a3;

    // ---- B load (weights, contiguous) ----
    {
      int k = k0 + br;
      float4 bv = make_float4(0.f,0.f,0.f,0.f);
      if (k < K)   // Co is a multiple of 64 in all layers -> no n guard
        bv = *reinterpret_cast<const float4*>(w + (long)k*Co + n0 + bc);
      Bs[br][bc+0]=bv.x; Bs[br][bc+1]=bv.y; Bs[br][bc+2]=bv.z; Bs[br][bc+3]=bv.w;
    }
    __syncthreads();
    #pragma unroll
    for (int kk = 0; kk < 16; ++kk) {
      float va0 = As[kk][(ty<<2)+0], va1 = As[kk][(ty<<2)+1];
      float va2 = As[kk][(ty<<2)+2], va3 = As[kk][(ty<<2)+3];
      float vb0 = Bs[kk][(tx<<2)+0], vb1 = Bs[kk][(tx<<2)+1];
      float vb2 = Bs[kk][(tx<<2)+2], vb3 = Bs[kk][(tx<<2)+3];
      acc[0][0]=fmaf(va0,vb0,acc[0][0]); acc[0][1]=fmaf(va0,vb1,acc[0][1]);
      acc[0][2]=fmaf(va0,vb2,acc[0][2]); acc[0][3]=fmaf(va0,vb3,acc[0][3]);
      acc[1][0]=fmaf(va1,vb0,acc[1][0]); acc[1][1]=fmaf(va1,vb1,acc[1][1]);
      acc[1][2]=fmaf(va1,vb2,acc[1][2]); acc[1][3]=fmaf(va1,vb3,acc[1][3]);
      acc[2][0]=fmaf(va2,vb0,acc[2][0]); acc[2][1]=fmaf(va2,vb1,acc[2][1]);
      acc[2][2]=fmaf(va2,vb2,acc[2][2]); acc[2][3]=fmaf(va2,vb3,acc[2][3]);
      acc[3][0]=fmaf(va3,vb0,acc[3][0]); acc[3][1]=fmaf(va3,vb1,acc[3][1]);
      acc[3][2]=fmaf(va3,vb2,acc[3][2]); acc[3][3]=fmaf(va3,vb3,acc[3][3]);
    }
    __syncthreads();
  }
  #pragma unroll
  for (int i = 0; i < 4; ++i) {
    int mo = m0 + (ty<<2) + i;
    if (mo >= M) continue;
    #pragma unroll
    for (int j = 0; j < 4; ++j) {
      int n = n0 + (tx<<2) + j;
      float v = acc[i][j] + bias[n];
      if (doRelu) v = fmaxf(v, 0.0f);
      out[(long)mo*Co + n] = v;
    }
  }
}

// ------------------------------------------------------------------
// Max pool, NHWC. lax SAME puts odd pad at hi; skipped taps == -inf identity.
// ------------------------------------------------------------------
__global__ __launch_bounds__(256) void maxpool_kernel(
    const float* __restrict__ x, float* __restrict__ out,
    int N,int H,int W,int C,int Ho,int Wo,int sH,int sW,int kH,int kW)
{
  long idx = (long)blockIdx.x*blockDim.x + threadIdx.x;
  long total = (long)N*Ho*Wo*C;
  if (idx >= total) return;
  int c = (int)(idx % C);
  long pix = idx / C;
  int wo = (int)(pix % Wo); long t2 = pix / Wo;
  int ho = (int)(t2 % Ho); int n = (int)(t2 / Ho);
  float m = -INFINITY;
  for (int i = 0; i < kH; ++i) {
    int ih = ho*sH + i;
    if (ih >= H) continue;
    for (int j = 0; j < kW; ++j) {
      int iw = wo*sW + j;
      if (iw >= W) continue;
      m = fmaxf(m, x[(((long)n*H + ih)*W + iw)*C + c]);
    }
  }
  out[idx] = m;
}

// ------------------------------------------------------------------
// BN (training) stats: per-channel sum & sumsq via per-block partials +
// global atomics. sums must be zeroed beforehand. C <= 512, blockDim 256.
// ------------------------------------------------------------------
__global__ __launch_bounds__(256) void bn_sums_kernel(
    const float* __restrict__ x, float* __restrict__ sums, long nPix, int C)
{
  long rowsPer = (nPix + gridDim.x - 1) / gridDim.x;
  long r0 = (long)blockIdx.x * rowsPer;
  long r1 = r0 + rowsPer; if (r1 > nPix) r1 = nPix;
  float a0 = 0.f, q0 = 0.f, a1 = 0.f, q1 = 0.f;
  for (long r = r0; r < r1; ++r) {
    const float* xp = x + r*C;
    {
      float v = xp[threadIdx.x];
      a0 += v; q0 += v*v;
    }
    if (C > 256) {
      float v = xp[256 + threadIdx.x];
      a1 += v; q1 += v*v;
    }
  }
  atomicAdd(&sums[threadIdx.x], a0);
  atomicAdd(&sums[C + threadIdx.x], q0);
  if (C > 256) {
    atomicAdd(&sums[256 + threadIdx.x], a1);
    atomicAdd(&sums[C + 256 + threadIdx.x], q1);
  }
}

__global__ __launch_bounds__(256) void bn_apply_relu_kernel(
    float* __restrict__ x, const float* __restrict__ sums,
    const float* __restrict__ scale, const float* __restrict__ bias,
    long total, int C, float invN)
{
  long idx = (long)blockIdx.x*blockDim.x + threadIdx.x;
  if (idx >= total) return;
  int c = (int)(idx % C);
  float mean = sums[c] * invN;
  float var  = sums[C + c] * invN - mean*mean;
  float rstd = rsqrtf(var + 1e-5f);
  float v = (x[idx] - mean) * rstd * scale[c] + bias[c];
  x[idx] = fmaxf(v, 0.0f);
}

// ------------------------------------------------------------------
// fp32 tiled GEMM: C[M,N] = A[M,K] @ B[K,N] + bias. 64x64 tile, TK=16,
// 256 threads, 4x4 per thread. K multiple of 16 in all uses.
// blockIdx.z selects among up to 3 (B,bias,C) sets sharing A.
// ------------------------------------------------------------------
struct GemmOut { const float* B; const float* bias; float* C; };

__global__ __launch_bounds__(256) void gemm64_kernel(
    const float* __restrict__ A, GemmOut g0, GemmOut g1, GemmOut g2,
    int M, int N, int K)
{
  GemmOut g = (blockIdx.z == 0) ? g0 : (blockIdx.z == 1 ? g1 : g2);
  const float* __restrict__ B = g.B;
  __shared__ float As[16][65];
  __shared__ float Bs[16][68];
  int tid = threadIdx.x;
  int m0 = blockIdx.y * 64, n0 = blockIdx.x * 64;
  int ty = tid >> 4, tx = tid & 15;
  int ar = tid >> 2, ac = (tid & 3) << 2;
  int br = tid >> 4, bc = (tid & 15) << 2;
  float acc[4][4] = {};
  for (int k0 = 0; k0 < K; k0 += 16) {
    float4 av = make_float4(0.f, 0.f, 0.f, 0.f);
    if (m0 + ar < M)
      av = *reinterpret_cast<const float4*>(A + (long)(m0 + ar)*K + k0 + ac);
    As[ac+0][ar] = av.x; As[ac+1][ar] = av.y; As[ac+2][ar] = av.z; As[ac+3][ar] = av.w;
    float4 bv;
    if (n0 + bc + 3 < N) {
      bv = *reinterpret_cast<const float4*>(B + (long)(k0 + br)*N + n0 + bc);
    } else {
      const float* bp = B + (long)(k0 + br)*N;
      bv.x = (n0+bc+0 < N) ? bp[n0+bc+0] : 0.f;
      bv.y = (n0+bc+1 < N) ? bp[n0+bc+1] : 0.f;
      bv.z = (n0+bc+2 < N) ? bp[n0+bc+2] : 0.f;
      bv.w = (n0+bc+3 < N) ? bp[n0+bc+3] : 0.f;
    }
    Bs[br][bc+0] = bv.x; Bs[br][bc+1] = bv.y; Bs[br][bc+2] = bv.z; Bs[br][bc+3] = bv.w;
    __syncthreads();
    #pragma unroll
    for (int kk = 0; kk < 16; ++kk) {
      float a0 = As[kk][(ty<<2)+0], a1 = As[kk][(ty<<2)+1];
      float a2 = As[kk][(ty<<2)+2], a3 = As[kk][(ty<<2)+3];
      float b0 = Bs[kk][(tx<<2)+0], b1 = Bs[kk][(tx<<2)+1];
      float b2 = Bs[kk][(tx<<2)+2], b3 = Bs[kk][(tx<<2)+3];
      acc[0][0] = fmaf(a0,b0,acc[0][0]); acc[0][1] = fmaf(a0,b1,acc[0][1]);
      acc[0][2] = fmaf(a0,b2,acc[0][2]); acc[0][3] = fmaf(a0,b3,acc[0][3]);
      acc[1][0] = fmaf(a1,b0,acc[1][0]); acc[1][1] = fmaf(a1,b1,acc[1][1]);
      acc[1][2] = fmaf(a1,b2,acc[1][2]); acc[1][3] = fmaf(a1,b3,acc[1][3]);
      acc[2][0] = fmaf(a2,b0,acc[2][0]); acc[2][1] = fmaf(a2,b1,acc[2][1]);
      acc[2][2] = fmaf(a2,b2,acc[2][2]); acc[2][3] = fmaf(a2,b3,acc[2][3]);
      acc[3][0] = fmaf(a3,b0,acc[3][0]); acc[3][1] = fmaf(a3,b1,acc[3][1]);
      acc[3][2] = fmaf(a3,b2,acc[3][2]); acc[3][3] = fmaf(a3,b3,acc[3][3]);
    }
    __syncthreads();
  }
  #pragma unroll
  for (int i = 0; i < 4; ++i) {
    int m = m0 + (ty<<2) + i;
    if (m >= M) continue;
    #pragma unroll
    for (int j = 0; j < 4; ++j) {
      int n = n0 + (tx<<2) + j;
      if (n < N) g.C[(long)m*N + n] = acc[i][j] + g.bias[n];
    }
  }
}

// ------------------------------------------------------------------
// Attention (T=15, D=512), one block per batch element.
// ------------------------------------------------------------------
__global__ __launch_bounds__(256) void attention_kernel(
    const float* __restrict__ q, const float* __restrict__ k,
    const float* __restrict__ v, float* __restrict__ out, int T, int D)
{
  int b = blockIdx.x;
  int tid = threadIdx.x;
  __shared__ float P[15][16];
  if (tid < T*T) {
    int t = tid / T, s = tid % T;
    const float* qp = q + ((long)b*T + t)*D;
    const float* kp = k + ((long)b*T + s)*D;
    float acc = 0.f;
    for (int d = 0; d < D; d += 4) {
      float4 qv = *reinterpret_cast<const float4*>(qp + d);
      float4 kv = *reinterpret_cast<const float4*>(kp + d);
      acc += qv.x*kv.x + qv.y*kv.y + qv.z*kv.z + qv.w*kv.w;
    }
    P[t][s] = acc * (1.0f/32.0f);
  }
  __syncthreads();
  if (tid < T) {
    float mx = -INFINITY;
    for (int s = 0; s < T; ++s) mx = fmaxf(mx, P[tid][s]);
    float sum = 0.f;
    for (int s = 0; s < T; ++s) { float e = expf(P[tid][s] - mx); P[tid][s] = e; sum += e; }
    float inv = 1.0f / sum;
    for (int s = 0; s < T; ++s) P[tid][s] *= inv;
  }
  __syncthreads();
  for (int idx = tid; idx < T*D; idx += 256) {
    int s = idx / D, kk2 = idx % D;
    float acc = 0.f;
    #pragma unroll
    for (int t = 0; t < 15; ++t) acc += v[((long)b*15 + t)*D + kk2] * P[t][s];
    out[((long)b*T + s)*D + kk2] = acc;
  }
}

// ------------------------------------------------------------------
// One LSTM step. pre = x@wx+b precomputed (B,T,4H). Gate order i,f,g,o.
// ------------------------------------------------------------------
__global__ __launch_bounds__(256) void lstm_step_kernel(
    const float* __restrict__ pre, const float* __restrict__ wh,
    const float* __restrict__ h_in, float* __restrict__ h_out,
    float* __restrict__ c, float* __restrict__ y,
    int t, int T, int H, int ystride)
{
  __shared__ float hs[512];
  int blk = blockIdx.x;
  int b = (blk * 256) / H;
  int jbase = (blk * 256) % H;
  int j = jbase + threadIdx.x;
  for (int k2 = threadIdx.x; k2 < H; k2 += 256) hs[k2] = h_in[b*H + k2];
  __syncthreads();
  int H4 = 4*H;
  float ai = 0.f, af = 0.f, ag = 0.f, ao = 0.f;
  #pragma unroll 4
  for (int k2 = 0; k2 < H; ++k2) {
    float hk = hs[k2];
    const float* wr = wh + (long)k2*H4;
    ai = fmaf(hk, wr[j],       ai);
    af = fmaf(hk, wr[H + j],   af);
    ag = fmaf(hk, wr[2*H + j], ag);
    ao = fmaf(hk, wr[3*H + j], ao);
  }
  const float* p = pre + ((long)b*T + t)*H4;
  float gi = sigmoidf_(p[j]       + ai);
  float gf = sigmoidf_(p[H + j]   + af);
  float gg = tanhf    (p[2*H + j] + ag);
  float go = sigmoidf_(p[3*H + j] + ao);
  int ci = b*H + j;
  float cn = gf * c[ci] + gi * gg;
  c[ci] = cn;
  float hn = go * tanhf(cn);
  h_out[ci] = hn;
  y[((long)b*T + t)*ystride + j] = hn;
}

// ------------------------------------------------------------------
// Host orchestration
// ------------------------------------------------------------------
extern "C" void kernel_launch(void* const* d_in, const int* in_sizes, int n_in,
                              void* d_out, int out_size, void* d_ws, size_t ws_size,
                              hipStream_t stream)
{
  const float* x       = (const float*)d_in[0];
  const float* c1w     = (const float*)d_in[1];  const float* c1b = (const float*)d_in[2];
  const float* c2w     = (const float*)d_in[3];  const float* c2b = (const float*)d_in[4];
  const float* c3w     = (const float*)d_in[5];  const float* c3b = (const float*)d_in[6];
  const float* bn1s    = (const float*)d_in[7];  const float* bn1b = (const float*)d_in[8];
  const float* c4w     = (const float*)d_in[9];  const float* c4b = (const float*)d_in[10];
  const float* bn2s    = (const float*)d_in[11]; const float* bn2b = (const float*)d_in[12];
  const float* c5w     = (const float*)d_in[13]; const float* c5b = (const float*)d_in[14];
  const float* bn3s    = (const float*)d_in[15]; const float* bn3b = (const float*)d_in[16];
  const float* c6w     = (const float*)d_in[17]; const float* c6b = (const float*)d_in[18];
  const float* bn4s    = (const float*)d_in[19]; const float* bn4b = (const float*)d_in[20];
  const float* c7w     = (const float*)d_in[21]; const float* c7b = (const float*)d_in[22];
  const float* bn5s    = (const float*)d_in[23]; const float* bn5b = (const float*)d_in[24];
  const float* wq      = (const float*)d_in[25]; const float* bq = (const float*)d_in[26];
  const float* wk      = (const float*)d_in[27]; const float* bk = (const float*)d_in[28];
  const float* wv      = (const float*)d_in[29]; const float* bv = (const float*)d_in[30];
  const float* l1f_wx  = (const float*)d_in[31]; const float* l1f_wh = (const float*)d_in[32]; const float* l1f_b = (const float*)d_in[33];
  const float* l1r_wx  = (const float*)d_in[34]; const float* l1r_wh = (const float*)d_in[35]; const float* l1r_b = (const float*)d_in[36];
  const float* l2f_wx  = (const float*)d_in[37]; const float* l2f_wh = (const float*)d_in[38]; const float* l2f_b = (const float*)d_in[39];
  const float* l2r_wx  = (const float*)d_in[40]; const float* l2r_wh = (const float*)d_in[41]; const float* l2r_b = (const float*)d_in[42];
  const float* wo      = (const float*)d_in[43]; const float* bo = (const float*)d_in[44];
  float* outp = (float*)d_out;

  float* ws = (float*)d_ws;
  float* A  = ws;                       // 33,554,432 floats (128 MB)
  float* Bb = ws + 33554432;            //  8,388,608 floats (32 MB)
  float* bnsums = ws + 41943040;        //  1,024 floats
  float* q     = Bb;
  float* kk_   = Bb + 245760;
  float* v     = Bb + 491520;
  float* ao    = Bb + 737280;
  float* pre1f = Bb + 983040;
  float* pre1r = Bb + 1474560;
  float* x1    = Bb + 1966080;
  float* pre2f = Bb + 2211840;
  float* pre2r = Bb + 3194880;
  float* x2    = Bb + 4177920;
  float* h1a   = Bb + 4669440;
  float* h1b   = h1a + 8192;
  float* cc1   = h1b + 8192;
  float* h2a   = cc1 + 8192;
  float* h2b   = h2a + 16384;
  float* cc2   = h2b + 16384;

  auto conv = [&](const float* in, const float* w, const float* b, float* out,
                  int N,int H,int W,int Ci,int Ho,int Wo,int Co,
                  int KH,int KW,int pH,int pW,int relu){
    int M = N*Ho*Wo, K = KH*KW*Ci;
    dim3 grid(Co/64, DIV_UP(M,64));
    conv_gemm_kernel<<<grid,256,0,stream>>>(in,w,b,out,N,H,W,Ci,Ho,Wo,Co,KH,KW,pH,pW,relu,M,K);
  };
  auto pool = [&](const float* in, float* out, int N,int H,int W,int C,
                  int Ho,int Wo,int sH,int sW){
    long total = (long)N*Ho*Wo*C;
    maxpool_kernel<<<(int)DIV_UP(total,256),256,0,stream>>>(in,out,N,H,W,C,Ho,Wo,sH,sW,2,2);
  };
  auto bn = [&](float* buf, long nPix, int C, const float* s, const float* b){
    hipMemsetAsync(bnsums, 0, sizeof(float)*2*C, stream);
    bn_sums_kernel<<<256,256,0,stream>>>(buf, bnsums, nPix, C);
    long total = nPix * C;
    bn_apply_relu_kernel<<<(int)DIV_UP(total,256),256,0,stream>>>(buf, bnsums, s, b, total, C, 1.0f/(float)nPix);
  };
  auto gemm = [&](const float* Am, GemmOut g0, GemmOut g1, GemmOut g2, int nz,
                  int M, int N, int K){
    dim3 grid(DIV_UP(N,64), DIV_UP(M,64), nz);
    gemm64_kernel<<<grid,256,0,stream>>>(Am, g0, g1, g2, M, N, K);
  };

  // ---- conv stack ----
  conv(x,  c1w, c1b, A,  32,64,256,3,   64,256,64,  3,3,1,1, 1);
  pool(A,  Bb, 32,64,256,64,  32,128, 2,2);
  conv(Bb, c2w, c2b, A,  32,32,128,64,  32,128,128, 3,3,1,1, 1);
  pool(A,  Bb, 32,32,128,128, 16,64,  2,2);
  conv(Bb, c3w, c3b, A,  32,16,64,128,  16,64,256,  3,3,1,1, 0);
  bn(A,  32768, 256, bn1s, bn1b);
  conv(A,  c4w, c4b, Bb, 32,16,64,256,  16,64,256,  3,3,1,1, 0);
  bn(Bb, 32768, 256, bn2s, bn2b);
  pool(Bb, A,  32,16,64,256,  16,32,  1,2);
  conv(A,  c5w, c5b, Bb, 32,16,32,256,  16,32,512,  3,3,1,1, 0);
  bn(Bb, 16384, 512, bn3s, bn3b);
  conv(Bb, c6w, c6b, A,  32,16,32,512,  16,32,512,  3,3,1,1, 0);
  bn(A,  16384, 512, bn4s, bn4b);
  pool(A,  Bb, 32,16,32,512,  16,16,  1,2);
  conv(Bb, c7w, c7b, A,  32,16,16,512,  15,15,512,  2,2,0,0, 0);
  bn(A,  7200, 512, bn5s, bn5b);

  // ---- attention ----  A viewed as (480, 7680)
  {
    GemmOut gq{wq, bq, q}, gk{wk, bk, kk_}, gv{wv, bv, v};
    gemm(A, gq, gk, gv, 3, 480, 512, 7680);
    attention_kernel<<<32,256,0,stream>>>(q, kk_, v, ao, 15, 512);
  }

  // ---- LSTM stack 1 (H=256) ----
  {
    GemmOut gf{l1f_wx, l1f_b, pre1f}, gr{l1r_wx, l1r_b, pre1r};
    gemm(ao, gf, gr, gf, 2, 480, 1024, 512);
    hipMemsetAsync(h1a, 0, sizeof(float)*8192, stream);
    hipMemsetAsync(cc1, 0, sizeof(float)*8192, stream);
    float* hb[2] = {h1a, h1b};
    int p = 0;
    for (int i = 0; i < 15; ++i) {
      lstm_step_kernel<<<32,256,0,stream>>>(pre1f, l1f_wh, hb[p], hb[1-p], cc1, x1,       i, 15, 256, 512);
      p ^= 1;
    }
    for (int i = 14; i >= 0; --i) {
      lstm_step_kernel<<<32,256,0,stream>>>(pre1r, l1r_wh, hb[p], hb[1-p], cc1, x1 + 256, i, 15, 256, 512);
      p ^= 1;
    }
  }

  // ---- LSTM stack 2 (H=512) ----
  {
    GemmOut gf{l2f_wx, l2f_b, pre2f}, gr{l2r_wx, l2r_b, pre2r};
    gemm(x1, gf, gr, gf, 2, 480, 2048, 512);
    hipMemsetAsync(h2a, 0, sizeof(float)*16384, stream);
    hipMemsetAsync(cc2, 0, sizeof(float)*16384, stream);
    float* hb[2] = {h2a, h2b};
    int p = 0;
    for (int i = 0; i < 15; ++i) {
      lstm_step_kernel<<<64,256,0,stream>>>(pre2f, l2f_wh, hb[p], hb[1-p], cc2, x2 + 512, i, 15, 512, 1024);
      p ^= 1;
    }
    for (int i = 14; i >= 0; --i) {
      lstm_step_kernel<<<64,256,0,stream>>>(pre2r, l2r_wh, hb[p], hb[1-p], cc2, x2,       i, 15, 512, 1024);
      p ^= 1;
    }
  }

  // ---- classifier ----
  {
    GemmOut go{wo, bo, outp};
    gemm(x2, go, go, go, 1, 480, 1000, 1024);
  }
}

// Round 3
// 7735.591 us; speedup vs baseline: 5.2579x; 1.4302x over previous
//
#include <hip/hip_runtime.h>
#include <math.h>

#define DIV_UP(a,b) (((a)+(b)-1)/(b))

typedef _Float16 half_t;
typedef _Float16 half8 __attribute__((ext_vector_type(8)));
typedef float f32x4 __attribute__((ext_vector_type(4)));

#define FLAG_RELU  1
#define FLAG_OUTF32 2
#define FLAG_DENSE 4

__device__ __forceinline__ float sigmoidf_(float x){ return 1.0f/(1.0f+expf(-x)); }

// ------------------------------------------------------------------
// Weight transpose + fp32->fp16 convert: w[K][N] -> wT[N][K]
// ------------------------------------------------------------------
__global__ __launch_bounds__(256) void transpose_cvt_kernel(
    const float* __restrict__ w, half_t* __restrict__ wT, int K, int N)
{
  __shared__ float tile[32][33];
  int kt = blockIdx.y*32, nt = blockIdx.x*32;
  int tx = threadIdx.x & 31, ty = threadIdx.x >> 5;   // ty 0..7
  #pragma unroll
  for (int r = 0; r < 4; ++r) {
    int k = kt + ty + r*8, n = nt + tx;
    tile[ty + r*8][tx] = (k < K && n < N) ? w[(long)k*N + n] : 0.f;
  }
  __syncthreads();
  #pragma unroll
  for (int r = 0; r < 4; ++r) {
    int n = nt + ty + r*8, k = kt + tx;
    if (n < N && k < K) wT[(long)n*K + k] = (half_t)tile[tx][ty + r*8];
  }
}

// ------------------------------------------------------------------
// conv1 special case: x (32,64,256,3) fp32, w (3,3,3,64), out fp16 + ReLU.
// One block per (n, ho) row. Weights in regs (lane co), x rows in LDS.
// ------------------------------------------------------------------
__global__ __launch_bounds__(256) void conv1_kernel(
    const float* __restrict__ x, const float* __restrict__ w,
    const float* __restrict__ bias, half_t* __restrict__ out)
{
  __shared__ float xs[3][258*3];
  int nb = blockIdx.x;            // n*64 + ho
  int n = nb >> 6, ho = nb & 63;
  int tid = threadIdx.x;
  int co = tid & 63;
  float wreg[27];
  #pragma unroll
  for (int k = 0; k < 27; ++k) wreg[k] = w[k*64 + co];
  float bco = bias[co];
  for (int i = tid; i < 3*258*3; i += 256) {
    int row = i / (258*3); int rem = i % (258*3);
    int col = rem / 3;     int ci  = rem % 3;
    int ih = ho - 1 + row; int iw = col - 1;
    float v = 0.f;
    if (ih >= 0 && ih < 64 && iw >= 0 && iw < 256)
      v = x[(((long)n*64 + ih)*256 + iw)*3 + ci];
    xs[row][col*3 + ci] = v;
  }
  __syncthreads();
  int wave = tid >> 6;
  for (int p = 0; p < 64; ++p) {
    int wo = wave*64 + p;
    float acc = bco;
    #pragma unroll
    for (int kh = 0; kh < 3; ++kh)
      #pragma unroll
      for (int kw = 0; kw < 3; ++kw)
        #pragma unroll
        for (int ci = 0; ci < 3; ++ci)
          acc = fmaf(xs[kh][(wo+kw)*3 + ci], wreg[(kh*3+kw)*3 + ci], acc);
    acc = fmaxf(acc, 0.f);
    out[(((long)n*64 + ho)*256 + wo)*64 + co] = (half_t)acc;
  }
}

// ------------------------------------------------------------------
// MFMA implicit-GEMM: out[M,Co] = im2col(x fp16) @ wT^T + bias.
// wT is [Co][K] fp16. 128x128 tile, BK=32, 4 waves (2x2 of 64x64),
// mfma_f32_16x16x32_f16. Dense GEMM via FLAG_DENSE (row-major A, stride K).
// Fragment layouts (HW-verified): A: m=lane&15, k=quad*8+j;
// B: k=quad*8+j, n=lane&15; D: m=quad*4+r, n=lane&15.
// ------------------------------------------------------------------
__global__ __launch_bounds__(256) void mfma_conv_kernel(
    const half_t* __restrict__ x, const half_t* __restrict__ wT,
    const float* __restrict__ bias, void* __restrict__ outPtr,
    int N,int H,int W,int Ci,int Ho,int Wo,int Co,
    int KH,int KW,int padH,int padW,int ciShift,
    int M,int K,int flags)
{
  __shared__ half_t As[128][40];
  __shared__ half_t Bs[128][40];
  int tid = threadIdx.x;
  int m0 = blockIdx.y*128, n0 = blockIdx.x*128;
  int sRow = tid >> 1;
  int sK   = (tid & 1) * 16;

  int am = m0 + sRow;
  bool amv = am < M;
  int amc = amv ? am : 0;
  int wo = 0, ho = 0, nimg = 0;
  bool dense = (flags & FLAG_DENSE);
  if (!dense) {
    wo = amc % Wo; int t2 = amc / Wo;
    ho = t2 % Ho;  nimg = t2 / Ho;
  }
  int bn = n0 + sRow;
  bool bnv = bn < Co;

  int wave = tid >> 6, lane = tid & 63;
  int wm = (wave & 1) * 64, wn = (wave >> 1) * 64;
  int l15 = lane & 15, quad = lane >> 4;

  f32x4 acc[4][4];
  #pragma unroll
  for (int i = 0; i < 4; ++i)
    #pragma unroll
    for (int j = 0; j < 4; ++j)
      acc[i][j] = (f32x4){0.f, 0.f, 0.f, 0.f};

  for (int k0 = 0; k0 < K; k0 += 32) {
    // ---- stage A (im2col gather or dense row) ----
    {
      int kg = k0 + sK;
      const half_t* src = nullptr;
      if (dense) {
        if (amv) src = x + (long)amc*K + kg;
      } else {
        int ci = kg & ((1 << ciShift) - 1);
        int pq = kg >> ciShift;
        int kw = pq % KW, kh = pq / KW;
        int ih = ho - padH + kh, iw = wo - padW + kw;
        if (amv && ih >= 0 && ih < H && iw >= 0 && iw < W)
          src = x + (((long)nimg*H + ih)*W + iw)*(long)Ci + ci;
      }
      half8 v0 = {0,0,0,0,0,0,0,0}, v1 = {0,0,0,0,0,0,0,0};
      if (src) {
        v0 = *reinterpret_cast<const half8*>(src);
        v1 = *reinterpret_cast<const half8*>(src + 8);
      }
      *reinterpret_cast<half8*>(&As[sRow][sK])     = v0;
      *reinterpret_cast<half8*>(&As[sRow][sK + 8]) = v1;
    }
    // ---- stage B (wT rows, contiguous) ----
    {
      int kg = k0 + sK;
      half8 v0 = {0,0,0,0,0,0,0,0}, v1 = {0,0,0,0,0,0,0,0};
      if (bnv) {
        const half_t* src = wT + (long)bn*K + kg;
        v0 = *reinterpret_cast<const half8*>(src);
        v1 = *reinterpret_cast<const half8*>(src + 8);
      }
      *reinterpret_cast<half8*>(&Bs[sRow][sK])     = v0;
      *reinterpret_cast<half8*>(&Bs[sRow][sK + 8]) = v1;
    }
    __syncthreads();
    half8 af[4], bf[4];
    #pragma unroll
    for (int i = 0; i < 4; ++i)
      af[i] = *reinterpret_cast<half8*>(&As[wm + i*16 + l15][quad*8]);
    #pragma unroll
    for (int j = 0; j < 4; ++j)
      bf[j] = *reinterpret_cast<half8*>(&Bs[wn + j*16 + l15][quad*8]);
    #pragma unroll
    for (int i = 0; i < 4; ++i)
      #pragma unroll
      for (int j = 0; j < 4; ++j)
        acc[i][j] = __builtin_amdgcn_mfma_f32_16x16x32_f16(af[i], bf[j], acc[i][j], 0, 0, 0);
    __syncthreads();
  }

  // ---- epilogue ----
  #pragma unroll
  for (int i = 0; i < 4; ++i) {
    #pragma unroll
    for (int r = 0; r < 4; ++r) {
      int m = m0 + wm + i*16 + quad*4 + r;
      if (m >= M) continue;
      #pragma unroll
      for (int j = 0; j < 4; ++j) {
        int n = n0 + wn + j*16 + l15;
        if (n >= Co) continue;
        float v = acc[i][j][r] + bias[n];
        if (flags & FLAG_RELU) v = fmaxf(v, 0.f);
        if (flags & FLAG_OUTF32) ((float*)outPtr)[(long)m*Co + n] = v;
        else ((half_t*)outPtr)[(long)m*Co + n] = (half_t)v;
      }
    }
  }
}

// ------------------------------------------------------------------
// Max pool fp16, NHWC. lax SAME pads at hi; skipped taps == -inf identity.
// ------------------------------------------------------------------
__global__ __launch_bounds__(256) void maxpool_kernel(
    const half_t* __restrict__ x, half_t* __restrict__ out,
    int N,int H,int W,int C,int Ho,int Wo,int sH,int sW)
{
  long idx = (long)blockIdx.x*blockDim.x + threadIdx.x;
  long total = (long)N*Ho*Wo*C;
  if (idx >= total) return;
  int c = (int)(idx % C);
  long pix = idx / C;
  int wo = (int)(pix % Wo); long t2 = pix / Wo;
  int ho = (int)(t2 % Ho); int n = (int)(t2 / Ho);
  float m = -INFINITY;
  for (int i = 0; i < 2; ++i) {
    int ih = ho*sH + i;
    if (ih >= H) continue;
    for (int j = 0; j < 2; ++j) {
      int iw = wo*sW + j;
      if (iw >= W) continue;
      m = fmaxf(m, (float)x[(((long)n*H + ih)*W + iw)*C + c]);
    }
  }
  out[idx] = (half_t)m;
}

// ------------------------------------------------------------------
// BN (training) stats over fp16 activations, fp32 accumulate + atomics.
// ------------------------------------------------------------------
__global__ __launch_bounds__(256) void bn_sums_kernel(
    const half_t* __restrict__ x, float* __restrict__ sums, long nPix, int C)
{
  long rowsPer = (nPix + gridDim.x - 1) / gridDim.x;
  long r0 = (long)blockIdx.x * rowsPer;
  long r1 = r0 + rowsPer; if (r1 > nPix) r1 = nPix;
  float a0 = 0.f, q0 = 0.f, a1 = 0.f, q1 = 0.f;
  for (long r = r0; r < r1; ++r) {
    const half_t* xp = x + r*C;
    { float v = (float)xp[threadIdx.x]; a0 += v; q0 += v*v; }
    if (C > 256) { float v = (float)xp[256 + threadIdx.x]; a1 += v; q1 += v*v; }
  }
  atomicAdd(&sums[threadIdx.x], a0);
  atomicAdd(&sums[C + threadIdx.x], q0);
  if (C > 256) {
    atomicAdd(&sums[256 + threadIdx.x], a1);
    atomicAdd(&sums[C + 256 + threadIdx.x], q1);
  }
}

__global__ __launch_bounds__(256) void bn_apply_relu_kernel(
    half_t* __restrict__ x, const float* __restrict__ sums,
    const float* __restrict__ scale, const float* __restrict__ bias,
    long total, int C, float invN)
{
  long idx = (long)blockIdx.x*blockDim.x + threadIdx.x;
  if (idx >= total) return;
  int c = (int)(idx % C);
  float mean = sums[c] * invN;
  float var  = sums[C + c] * invN - mean*mean;
  float rstd = rsqrtf(var + 1e-5f);
  float v = ((float)x[idx] - mean) * rstd * scale[c] + bias[c];
  x[idx] = (half_t)fmaxf(v, 0.0f);
}

// ------------------------------------------------------------------
// Attention (T=15, D=512), q/k/v fp32, out fp16. One block per batch.
// ------------------------------------------------------------------
__global__ __launch_bounds__(256) void attention_kernel(
    const float* __restrict__ q, const float* __restrict__ k,
    const float* __restrict__ v, half_t* __restrict__ out, int T, int D)
{
  int b = blockIdx.x;
  int tid = threadIdx.x;
  __shared__ float P[15][16];
  if (tid < T*T) {
    int t = tid / T, s = tid % T;
    const float* qp = q + ((long)b*T + t)*D;
    const float* kp = k + ((long)b*T + s)*D;
    float acc = 0.f;
    for (int d = 0; d < D; d += 4) {
      float4 qv = *reinterpret_cast<const float4*>(qp + d);
      float4 kv = *reinterpret_cast<const float4*>(kp + d);
      acc += qv.x*kv.x + qv.y*kv.y + qv.z*kv.z + qv.w*kv.w;
    }
    P[t][s] = acc * (1.0f/32.0f);
  }
  __syncthreads();
  if (tid < T) {
    float mx = -INFINITY;
    for (int s = 0; s < T; ++s) mx = fmaxf(mx, P[tid][s]);
    float sum = 0.f;
    for (int s = 0; s < T; ++s) { float e = expf(P[tid][s] - mx); P[tid][s] = e; sum += e; }
    float inv = 1.0f / sum;
    for (int s = 0; s < T; ++s) P[tid][s] *= inv;
  }
  __syncthreads();
  for (int idx = tid; idx < T*D; idx += 256) {
    int s = idx / D, kk2 = idx % D;
    float acc = 0.f;
    #pragma unroll
    for (int t = 0; t < 15; ++t) acc += v[((long)b*15 + t)*D + kk2] * P[t][s];
    out[((long)b*T + s)*D + kk2] = (half_t)acc;
  }
}

// ------------------------------------------------------------------
// One LSTM step. pre fp32 (B,T,4H); h/c fp32; y written fp16 (GEMM input).
// Gate order i,f,g,o.
// ------------------------------------------------------------------
__global__ __launch_bounds__(256) void lstm_step_kernel(
    const float* __restrict__ pre, const float* __restrict__ wh,
    const float* __restrict__ h_in, float* __restrict__ h_out,
    float* __restrict__ c, half_t* __restrict__ y,
    int t, int T, int H, int ystride)
{
  __shared__ float hs[512];
  int blk = blockIdx.x;
  int b = (blk * 256) / H;
  int jbase = (blk * 256) % H;
  int j = jbase + threadIdx.x;
  for (int k2 = threadIdx.x; k2 < H; k2 += 256) hs[k2] = h_in[b*H + k2];
  __syncthreads();
  int H4 = 4*H;
  float ai = 0.f, af = 0.f, ag = 0.f, ao = 0.f;
  #pragma unroll 4
  for (int k2 = 0; k2 < H; ++k2) {
    float hk = hs[k2];
    const float* wr = wh + (long)k2*H4;
    ai = fmaf(hk, wr[j],       ai);
    af = fmaf(hk, wr[H + j],   af);
    ag = fmaf(hk, wr[2*H + j], ag);
    ao = fmaf(hk, wr[3*H + j], ao);
  }
  const float* p = pre + ((long)b*T + t)*H4;
  float gi = sigmoidf_(p[j]       + ai);
  float gf = sigmoidf_(p[H + j]   + af);
  float gg = tanhf    (p[2*H + j] + ag);
  float go = sigmoidf_(p[3*H + j] + ao);
  int ci = b*H + j;
  float cn = gf * c[ci] + gi * gg;
  c[ci] = cn;
  float hn = go * tanhf(cn);
  h_out[ci] = hn;
  y[((long)b*T + t)*ystride + j] = (half_t)hn;
}

// ------------------------------------------------------------------
// Host orchestration
// ------------------------------------------------------------------
extern "C" void kernel_launch(void* const* d_in, const int* in_sizes, int n_in,
                              void* d_out, int out_size, void* d_ws, size_t ws_size,
                              hipStream_t stream)
{
  const float* x       = (const float*)d_in[0];
  const float* c1w     = (const float*)d_in[1];  const float* c1b = (const float*)d_in[2];
  const float* c2w     = (const float*)d_in[3];  const float* c2b = (const float*)d_in[4];
  const float* c3w     = (const float*)d_in[5];  const float* c3b = (const float*)d_in[6];
  const float* bn1s    = (const float*)d_in[7];  const float* bn1b = (const float*)d_in[8];
  const float* c4w     = (const float*)d_in[9];  const float* c4b = (const float*)d_in[10];
  const float* bn2s    = (const float*)d_in[11]; const float* bn2b = (const float*)d_in[12];
  const float* c5w     = (const float*)d_in[13]; const float* c5b = (const float*)d_in[14];
  const float* bn3s    = (const float*)d_in[15]; const float* bn3b = (const float*)d_in[16];
  const float* c6w     = (const float*)d_in[17]; const float* c6b = (const float*)d_in[18];
  const float* bn4s    = (const float*)d_in[19]; const float* bn4b = (const float*)d_in[20];
  const float* c7w     = (const float*)d_in[21]; const float* c7b = (const float*)d_in[22];
  const float* bn5s    = (const float*)d_in[23]; const float* bn5b = (const float*)d_in[24];
  const float* wq      = (const float*)d_in[25]; const float* bq = (const float*)d_in[26];
  const float* wk      = (const float*)d_in[27]; const float* bk = (const float*)d_in[28];
  const float* wv      = (const float*)d_in[29]; const float* bv = (const float*)d_in[30];
  const float* l1f_wx  = (const float*)d_in[31]; const float* l1f_wh = (const float*)d_in[32]; const float* l1f_b = (const float*)d_in[33];
  const float* l1r_wx  = (const float*)d_in[34]; const float* l1r_wh = (const float*)d_in[35]; const float* l1r_b = (const float*)d_in[36];
  const float* l2f_wx  = (const float*)d_in[37]; const float* l2f_wh = (const float*)d_in[38]; const float* l2f_b = (const float*)d_in[39];
  const float* l2r_wx  = (const float*)d_in[40]; const float* l2r_wh = (const float*)d_in[41]; const float* l2r_b = (const float*)d_in[42];
  const float* wo      = (const float*)d_in[43]; const float* bo = (const float*)d_in[44];
  float* outp = (float*)d_out;

  char* base = (char*)d_ws;
  half_t* actA = (half_t*)base;                    // 33,554,432 halves
  half_t* actB = (half_t*)(base + 67108864);       // 16,777,216 halves
  half_t* wtA  = (half_t*)(base + 100663296);      // 21,512,192 halves
  float*  f32a = (float*)(base + 143687680);
  half_t* h16a = (half_t*)(base + 158736384);

  half_t* wt2  = wtA;
  half_t* wt3  = wtA + 73728;
  half_t* wt4  = wtA + 368640;
  half_t* wt5  = wtA + 958464;
  half_t* wt6  = wtA + 2138112;
  half_t* wt7  = wtA + 4497408;
  half_t* wtq  = wtA + 5545984;
  half_t* wtk  = wtA + 9478144;
  half_t* wtv  = wtA + 13410304;
  half_t* wt1f = wtA + 17342464;
  half_t* wt1r = wtA + 17866752;
  half_t* wt2f = wtA + 18391040;
  half_t* wt2r = wtA + 19439616;
  half_t* wto  = wtA + 20488192;

  float* q     = f32a;
  float* kk_   = f32a + 245760;
  float* v     = f32a + 491520;
  float* pre1f = f32a + 737280;
  float* pre1r = f32a + 1228800;
  float* pre2f = f32a + 1720320;
  float* pre2r = f32a + 2703360;
  float* h1a   = f32a + 3686400;
  float* h1b   = f32a + 3694592;
  float* cc1   = f32a + 3702784;
  float* h2a   = f32a + 3710976;
  float* h2b   = f32a + 3727360;
  float* cc2   = f32a + 3743744;
  float* bnsums= f32a + 3760128;

  half_t* ao = h16a;
  half_t* x1 = h16a + 245760;
  half_t* x2 = h16a + 491520;

  auto tpose = [&](const float* w, half_t* wT, int K, int N){
    dim3 grid(DIV_UP(N,32), DIV_UP(K,32));
    transpose_cvt_kernel<<<grid,256,0,stream>>>(w, wT, K, N);
  };
  auto convm = [&](const half_t* in, const half_t* wt, const float* b, void* out,
                   int N,int H,int W,int Ci,int Ho,int Wo,int Co,
                   int KH,int KW,int pH,int pW,int flags){
    int M = N*Ho*Wo, K = KH*KW*Ci;
    int ciShift = __builtin_ctz((unsigned)Ci);
    dim3 grid(DIV_UP(Co,128), DIV_UP(M,128));
    mfma_conv_kernel<<<grid,256,0,stream>>>(in,wt,b,out,N,H,W,Ci,Ho,Wo,Co,
                                            KH,KW,pH,pW,ciShift,M,K,flags);
  };
  auto gemm = [&](const half_t* A, const half_t* wt, const float* b, void* out,
                  int M, int Nn, int K, int flags){
    dim3 grid(DIV_UP(Nn,128), DIV_UP(M,128));
    mfma_conv_kernel<<<grid,256,0,stream>>>(A,wt,b,out,1,1,1,K,1,1,Nn,
                                            1,1,0,0,0,M,K,flags|FLAG_DENSE);
  };
  auto pool = [&](const half_t* in, half_t* out, int N,int H,int W,int C,
                  int Ho,int Wo,int sH,int sW){
    long total = (long)N*Ho*Wo*C;
    maxpool_kernel<<<(int)DIV_UP(total,256),256,0,stream>>>(in,out,N,H,W,C,Ho,Wo,sH,sW);
  };
  auto bn = [&](half_t* buf, long nPix, int C, const float* s, const float* b){
    hipMemsetAsync(bnsums, 0, sizeof(float)*2*C, stream);
    bn_sums_kernel<<<256,256,0,stream>>>(buf, bnsums, nPix, C);
    long total = nPix * C;
    bn_apply_relu_kernel<<<(int)DIV_UP(total,256),256,0,stream>>>(buf, bnsums, s, b, total, C, 1.0f/(float)nPix);
  };

  // ---- weight preconversion (independent of activations) ----
  tpose(c2w, wt2, 576, 128);
  tpose(c3w, wt3, 1152, 256);
  tpose(c4w, wt4, 2304, 256);
  tpose(c5w, wt5, 2304, 512);
  tpose(c6w, wt6, 4608, 512);
  tpose(c7w, wt7, 2048, 512);
  tpose(wq,  wtq, 7680, 512);
  tpose(wk,  wtk, 7680, 512);
  tpose(wv,  wtv, 7680, 512);
  tpose(l1f_wx, wt1f, 512, 1024);
  tpose(l1r_wx, wt1r, 512, 1024);
  tpose(l2f_wx, wt2f, 512, 2048);
  tpose(l2r_wx, wt2r, 512, 2048);
  tpose(wo, wto, 1024, 1000);

  // ---- conv stack (activations fp16) ----
  conv1_kernel<<<2048,256,0,stream>>>(x, c1w, c1b, actA);
  pool(actA, actB, 32,64,256,64,  32,128, 2,2);
  convm(actB, wt2, c2b, actA, 32,32,128,64,  32,128,128, 3,3,1,1, FLAG_RELU);
  pool(actA, actB, 32,32,128,128, 16,64, 2,2);
  convm(actB, wt3, c3b, actA, 32,16,64,128,  16,64,256,  3,3,1,1, 0);
  bn(actA, 32768, 256, bn1s, bn1b);
  convm(actA, wt4, c4b, actB, 32,16,64,256,  16,64,256,  3,3,1,1, 0);
  bn(actB, 32768, 256, bn2s, bn2b);
  pool(actB, actA, 32,16,64,256,  16,32, 1,2);
  convm(actA, wt5, c5b, actB, 32,16,32,256,  16,32,512,  3,3,1,1, 0);
  bn(actB, 16384, 512, bn3s, bn3b);
  convm(actB, wt6, c6b, actA, 32,16,32,512,  16,32,512,  3,3,1,1, 0);
  bn(actA, 16384, 512, bn4s, bn4b);
  pool(actA, actB, 32,16,32,512,  16,16, 1,2);
  convm(actB, wt7, c7b, actA, 32,16,16,512,  15,15,512,  2,2,0,0, 0);
  bn(actA, 7200, 512, bn5s, bn5b);

  // ---- attention: actA viewed as (480, 7680) fp16 ----
  gemm(actA, wtq, bq, q,   480, 512, 7680, FLAG_OUTF32);
  gemm(actA, wtk, bk, kk_, 480, 512, 7680, FLAG_OUTF32);
  gemm(actA, wtv, bv, v,   480, 512, 7680, FLAG_OUTF32);
  attention_kernel<<<32,256,0,stream>>>(q, kk_, v, ao, 15, 512);

  // ---- LSTM stack 1 (H=256) ----
  gemm(ao, wt1f, l1f_b, pre1f, 480, 1024, 512, FLAG_OUTF32);
  gemm(ao, wt1r, l1r_b, pre1r, 480, 1024, 512, FLAG_OUTF32);
  hipMemsetAsync(h1a, 0, sizeof(float)*8192, stream);
  hipMemsetAsync(cc1, 0, sizeof(float)*8192, stream);
  {
    float* hb[2] = {h1a, h1b};
    int p = 0;
    for (int i = 0; i < 15; ++i) {
      lstm_step_kernel<<<32,256,0,stream>>>(pre1f, l1f_wh, hb[p], hb[1-p], cc1, x1,       i, 15, 256, 512);
      p ^= 1;
    }
    for (int i = 14; i >= 0; --i) {
      lstm_step_kernel<<<32,256,0,stream>>>(pre1r, l1r_wh, hb[p], hb[1-p], cc1, x1 + 256, i, 15, 256, 512);
      p ^= 1;
    }
  }

  // ---- LSTM stack 2 (H=512) ----
  gemm(x1, wt2f, l2f_b, pre2f, 480, 2048, 512, FLAG_OUTF32);
  gemm(x1, wt2r, l2r_b, pre2r, 480, 2048, 512, FLAG_OUTF32);
  hipMemsetAsync(h2a, 0, sizeof(float)*16384, stream);
  hipMemsetAsync(cc2, 0, sizeof(float)*16384, stream);
  {
    float* hb[2] = {h2a, h2b};
    int p = 0;
    for (int i = 0; i < 15; ++i) {
      lstm_step_kernel<<<64,256,0,stream>>>(pre2f, l2f_wh, hb[p], hb[1-p], cc2, x2 + 512, i, 15, 512, 1024);
      p ^= 1;
    }
    for (int i = 14; i >= 0; --i) {
      lstm_step_kernel<<<64,256,0,stream>>>(pre2r, l2r_wh, hb[p], hb[1-p], cc2, x2,       i, 15, 512, 1024);
      p ^= 1;
    }
  }

  // ---- classifier ----
  gemm(x2, wto, bo, outp, 480, 1000, 1024, FLAG_OUTF32);
}

// Round 4
// 2613.563 us; speedup vs baseline: 15.5622x; 2.9598x over previous
//
#include <hip/hip_runtime.h>
#include <math.h>

#define DIV_UP(a,b) (((a)+(b)-1)/(b))

typedef _Float16 half_t;
typedef _Float16 half8 __attribute__((ext_vector_type(8)));
typedef float f32x4 __attribute__((ext_vector_type(4)));

#define FLAG_RELU  1
#define FLAG_OUTF32 2
#define FLAG_DENSE 4

__device__ __forceinline__ float fsig_(float x){ return 1.0f/(1.0f+__expf(-x)); }
__device__ __forceinline__ float ftanh_(float x){
  float ax = fabsf(x);
  float e = __expf(-2.0f*ax);
  float t = (1.0f - e)/(1.0f + e);
  return copysignf(t, x);
}

// ------------------------------------------------------------------
// Weight transpose + fp32->fp16 convert: w[K][N] -> wT[N][K]
// ------------------------------------------------------------------
__global__ __launch_bounds__(256) void transpose_cvt_kernel(
    const float* __restrict__ w, half_t* __restrict__ wT, int K, int N)
{
  __shared__ float tile[32][33];
  int kt = blockIdx.y*32, nt = blockIdx.x*32;
  int tx = threadIdx.x & 31, ty = threadIdx.x >> 5;   // ty 0..7
  #pragma unroll
  for (int r = 0; r < 4; ++r) {
    int k = kt + ty + r*8, n = nt + tx;
    tile[ty + r*8][tx] = (k < K && n < N) ? w[(long)k*N + n] : 0.f;
  }
  __syncthreads();
  #pragma unroll
  for (int r = 0; r < 4; ++r) {
    int n = nt + ty + r*8, k = kt + tx;
    if (n < N && k < K) wT[(long)n*K + k] = (half_t)tile[tx][ty + r*8];
  }
}

// ------------------------------------------------------------------
// conv1 special case: x (32,64,256,3) fp32, w (3,3,3,64), out fp16 + ReLU.
// ------------------------------------------------------------------
__global__ __launch_bounds__(256) void conv1_kernel(
    const float* __restrict__ x, const float* __restrict__ w,
    const float* __restrict__ bias, half_t* __restrict__ out)
{
  __shared__ float xs[3][258*3];
  int nb = blockIdx.x;            // n*64 + ho
  int n = nb >> 6, ho = nb & 63;
  int tid = threadIdx.x;
  int co = tid & 63;
  float wreg[27];
  #pragma unroll
  for (int k = 0; k < 27; ++k) wreg[k] = w[k*64 + co];
  float bco = bias[co];
  for (int i = tid; i < 3*258*3; i += 256) {
    int row = i / (258*3); int rem = i % (258*3);
    int col = rem / 3;     int ci  = rem % 3;
    int ih = ho - 1 + row; int iw = col - 1;
    float v = 0.f;
    if (ih >= 0 && ih < 64 && iw >= 0 && iw < 256)
      v = x[(((long)n*64 + ih)*256 + iw)*3 + ci];
    xs[row][col*3 + ci] = v;
  }
  __syncthreads();
  int wave = tid >> 6;
  for (int p = 0; p < 64; ++p) {
    int wo = wave*64 + p;
    float acc = bco;
    #pragma unroll
    for (int kh = 0; kh < 3; ++kh)
      #pragma unroll
      for (int kw = 0; kw < 3; ++kw)
        #pragma unroll
        for (int ci = 0; ci < 3; ++ci)
          acc = fmaf(xs[kh][(wo+kw)*3 + ci], wreg[(kh*3+kw)*3 + ci], acc);
    acc = fmaxf(acc, 0.f);
    out[(((long)n*64 + ho)*256 + wo)*64 + co] = (half_t)acc;
  }
}

// ------------------------------------------------------------------
// MFMA implicit-GEMM: out[M,Co] = im2col(x fp16) @ wT^T + bias.
// wT is [Co][K] fp16. 128x128 tile, BK=32, 4 waves (2x2 of 64x64).
// ------------------------------------------------------------------
__global__ __launch_bounds__(256) void mfma_conv_kernel(
    const half_t* __restrict__ x, const half_t* __restrict__ wT,
    const float* __restrict__ bias, void* __restrict__ outPtr,
    int N,int H,int W,int Ci,int Ho,int Wo,int Co,
    int KH,int KW,int padH,int padW,int ciShift,
    int M,int K,int flags)
{
  __shared__ half_t As[128][40];
  __shared__ half_t Bs[128][40];
  int tid = threadIdx.x;
  int m0 = blockIdx.y*128, n0 = blockIdx.x*128;
  int sRow = tid >> 1;
  int sK   = (tid & 1) * 16;

  int am = m0 + sRow;
  bool amv = am < M;
  int amc = amv ? am : 0;
  int wo = 0, ho = 0, nimg = 0;
  bool dense = (flags & FLAG_DENSE);
  if (!dense) {
    wo = amc % Wo; int t2 = amc / Wo;
    ho = t2 % Ho;  nimg = t2 / Ho;
  }
  int bn = n0 + sRow;
  bool bnv = bn < Co;

  int wave = tid >> 6, lane = tid & 63;
  int wm = (wave & 1) * 64, wn = (wave >> 1) * 64;
  int l15 = lane & 15, quad = lane >> 4;

  f32x4 acc[4][4];
  #pragma unroll
  for (int i = 0; i < 4; ++i)
    #pragma unroll
    for (int j = 0; j < 4; ++j)
      acc[i][j] = (f32x4){0.f, 0.f, 0.f, 0.f};

  for (int k0 = 0; k0 < K; k0 += 32) {
    {
      int kg = k0 + sK;
      const half_t* src = nullptr;
      if (dense) {
        if (amv) src = x + (long)amc*K + kg;
      } else {
        int ci = kg & ((1 << ciShift) - 1);
        int pq = kg >> ciShift;
        int kw = pq % KW, kh = pq / KW;
        int ih = ho - padH + kh, iw = wo - padW + kw;
        if (amv && ih >= 0 && ih < H && iw >= 0 && iw < W)
          src = x + (((long)nimg*H + ih)*W + iw)*(long)Ci + ci;
      }
      half8 v0 = {0,0,0,0,0,0,0,0}, v1 = {0,0,0,0,0,0,0,0};
      if (src) {
        v0 = *reinterpret_cast<const half8*>(src);
        v1 = *reinterpret_cast<const half8*>(src + 8);
      }
      *reinterpret_cast<half8*>(&As[sRow][sK])     = v0;
      *reinterpret_cast<half8*>(&As[sRow][sK + 8]) = v1;
    }
    {
      int kg = k0 + sK;
      half8 v0 = {0,0,0,0,0,0,0,0}, v1 = {0,0,0,0,0,0,0,0};
      if (bnv) {
        const half_t* src = wT + (long)bn*K + kg;
        v0 = *reinterpret_cast<const half8*>(src);
        v1 = *reinterpret_cast<const half8*>(src + 8);
      }
      *reinterpret_cast<half8*>(&Bs[sRow][sK])     = v0;
      *reinterpret_cast<half8*>(&Bs[sRow][sK + 8]) = v1;
    }
    __syncthreads();
    half8 af[4], bf[4];
    #pragma unroll
    for (int i = 0; i < 4; ++i)
      af[i] = *reinterpret_cast<half8*>(&As[wm + i*16 + l15][quad*8]);
    #pragma unroll
    for (int j = 0; j < 4; ++j)
      bf[j] = *reinterpret_cast<half8*>(&Bs[wn + j*16 + l15][quad*8]);
    #pragma unroll
    for (int i = 0; i < 4; ++i)
      #pragma unroll
      for (int j = 0; j < 4; ++j)
        acc[i][j] = __builtin_amdgcn_mfma_f32_16x16x32_f16(af[i], bf[j], acc[i][j], 0, 0, 0);
    __syncthreads();
  }

  #pragma unroll
  for (int i = 0; i < 4; ++i) {
    #pragma unroll
    for (int r = 0; r < 4; ++r) {
      int m = m0 + wm + i*16 + quad*4 + r;
      if (m >= M) continue;
      #pragma unroll
      for (int j = 0; j < 4; ++j) {
        int n = n0 + wn + j*16 + l15;
        if (n >= Co) continue;
        float v = acc[i][j][r] + bias[n];
        if (flags & FLAG_RELU) v = fmaxf(v, 0.f);
        if (flags & FLAG_OUTF32) ((float*)outPtr)[(long)m*Co + n] = v;
        else ((half_t*)outPtr)[(long)m*Co + n] = (half_t)v;
      }
    }
  }
}

// ------------------------------------------------------------------
// Max pool fp16, NHWC.
// ------------------------------------------------------------------
__global__ __launch_bounds__(256) void maxpool_kernel(
    const half_t* __restrict__ x, half_t* __restrict__ out,
    int N,int H,int W,int C,int Ho,int Wo,int sH,int sW)
{
  long idx = (long)blockIdx.x*blockDim.x + threadIdx.x;
  long total = (long)N*Ho*Wo*C;
  if (idx >= total) return;
  int c = (int)(idx % C);
  long pix = idx / C;
  int wo = (int)(pix % Wo); long t2 = pix / Wo;
  int ho = (int)(t2 % Ho); int n = (int)(t2 / Ho);
  float m = -INFINITY;
  for (int i = 0; i < 2; ++i) {
    int ih = ho*sH + i;
    if (ih >= H) continue;
    for (int j = 0; j < 2; ++j) {
      int iw = wo*sW + j;
      if (iw >= W) continue;
      m = fmaxf(m, (float)x[(((long)n*H + ih)*W + iw)*C + c]);
    }
  }
  out[idx] = (half_t)m;
}

// ------------------------------------------------------------------
// BN (training) stats over fp16 activations, fp32 accumulate + atomics.
// ------------------------------------------------------------------
__global__ __launch_bounds__(256) void bn_sums_kernel(
    const half_t* __restrict__ x, float* __restrict__ sums, long nPix, int C)
{
  long rowsPer = (nPix + gridDim.x - 1) / gridDim.x;
  long r0 = (long)blockIdx.x * rowsPer;
  long r1 = r0 + rowsPer; if (r1 > nPix) r1 = nPix;
  float a0 = 0.f, q0 = 0.f, a1 = 0.f, q1 = 0.f;
  for (long r = r0; r < r1; ++r) {
    const half_t* xp = x + r*C;
    { float v = (float)xp[threadIdx.x]; a0 += v; q0 += v*v; }
    if (C > 256) { float v = (float)xp[256 + threadIdx.x]; a1 += v; q1 += v*v; }
  }
  atomicAdd(&sums[threadIdx.x], a0);
  atomicAdd(&sums[C + threadIdx.x], q0);
  if (C > 256) {
    atomicAdd(&sums[256 + threadIdx.x], a1);
    atomicAdd(&sums[C + 256 + threadIdx.x], q1);
  }
}

__global__ __launch_bounds__(256) void bn_apply_relu_kernel(
    half_t* __restrict__ x, const float* __restrict__ sums,
    const float* __restrict__ scale, const float* __restrict__ bias,
    long total, int C, float invN)
{
  long idx = (long)blockIdx.x*blockDim.x + threadIdx.x;
  if (idx >= total) return;
  int c = (int)(idx % C);
  float mean = sums[c] * invN;
  float var  = sums[C + c] * invN - mean*mean;
  float rstd = rsqrtf(var + 1e-5f);
  float v = ((float)x[idx] - mean) * rstd * scale[c] + bias[c];
  x[idx] = (half_t)fmaxf(v, 0.0f);
}

// ------------------------------------------------------------------
// Attention (T=15, D=512), q/k/v fp32, out fp16.
// ------------------------------------------------------------------
__global__ __launch_bounds__(256) void attention_kernel(
    const float* __restrict__ q, const float* __restrict__ k,
    const float* __restrict__ v, half_t* __restrict__ out, int T, int D)
{
  int b = blockIdx.x;
  int tid = threadIdx.x;
  __shared__ float P[15][16];
  if (tid < T*T) {
    int t = tid / T, s = tid % T;
    const float* qp = q + ((long)b*T + t)*D;
    const float* kp = k + ((long)b*T + s)*D;
    float acc = 0.f;
    for (int d = 0; d < D; d += 4) {
      float4 qv = *reinterpret_cast<const float4*>(qp + d);
      float4 kv = *reinterpret_cast<const float4*>(kp + d);
      acc += qv.x*kv.x + qv.y*kv.y + qv.z*kv.z + qv.w*kv.w;
    }
    P[t][s] = acc * (1.0f/32.0f);
  }
  __syncthreads();
  if (tid < T) {
    float mx = -INFINITY;
    for (int s = 0; s < T; ++s) mx = fmaxf(mx, P[tid][s]);
    float sum = 0.f;
    for (int s = 0; s < T; ++s) { float e = expf(P[tid][s] - mx); P[tid][s] = e; sum += e; }
    float inv = 1.0f / sum;
    for (int s = 0; s < T; ++s) P[tid][s] *= inv;
  }
  __syncthreads();
  for (int idx = tid; idx < T*D; idx += 256) {
    int s = idx / D, kk2 = idx % D;
    float acc = 0.f;
    #pragma unroll
    for (int t = 0; t < 15; ++t) acc += v[((long)b*15 + t)*D + kk2] * P[t][s];
    out[((long)b*T + s)*D + kk2] = (half_t)acc;
  }
}

// ------------------------------------------------------------------
// Persistent bidirectional LSTM stack. One launch per stack (fwd then rev,
// carry chained as in reference). Grid = H/16 blocks, 256 threads, all
// co-resident (<= 32 blocks on 256 CUs). Each block owns 16 hidden units:
// - LDS-resident fp16 weight slice wh[:, {g*H+j}] as BsT[64][K] (reloaded
//   once at the fwd->rev switch, block-local so no grid sync needed)
// - cell state c in registers for all 30 steps
// - h ping-pongs through global fp16 double buffer with a device-scope
//   release/acquire grid barrier (monotonic counter, memset each launch)
// Per step: stage h -> LDS, MFMA 32xK @ Kx64 (wave = gate), gate LDS
// roundtrip, thread-local c/h update, y written directly into the concat slot.
// ------------------------------------------------------------------
#define MAXK 512
__global__ __launch_bounds__(256, 1) void lstm_persistent_kernel(
    const float* __restrict__ preF, const float* __restrict__ preR,
    const float* __restrict__ whF, const float* __restrict__ whR,
    half_t* __restrict__ hbuf, half_t* __restrict__ y,
    int* __restrict__ counter, int H, int nblk,
    int ystride, int yoffF, int yoffR)
{
  __shared__ half_t BsT[64][MAXK + 8];
  __shared__ half_t hs[32][MAXK + 8];
  __shared__ float gates[32][65];
  int tid = threadIdx.x;
  int jb0 = blockIdx.x * 16;
  int H4 = 4 * H;
  int lane = tid & 63, wave = tid >> 6;
  int l15 = lane & 15, quad = lane >> 4;
  int halfH = H >> 1;

  float cst[2] = {0.f, 0.f};   // cell state: units u = tid, tid+256

  // stage forward weights (one-time)
  for (int idx = tid; idx < H*64; idx += 256) {
    int k = idx >> 6, c = idx & 63;
    int g = c >> 4, jj = c & 15;
    BsT[c][k] = (half_t)whF[(long)k*H4 + g*H + jb0 + jj];
  }
  const float* pre = preF;
  int yoff = yoffF;
  __syncthreads();

  for (int s = 0; s < 30; ++s) {
    if (s == 15) {               // fwd -> rev: swap weights (block-local)
      __syncthreads();
      for (int idx = tid; idx < H*64; idx += 256) {
        int k = idx >> 6, c = idx & 63;
        int g = c >> 4, jj = c & 15;
        BsT[c][k] = (half_t)whR[(long)k*H4 + g*H + jb0 + jj];
      }
      pre = preR; yoff = yoffR;
      __syncthreads();
    }
    int t = (s < 15) ? s : 29 - s;

    // stage h(prev) from global ping buffer
    const half_t* hsrc = hbuf + (long)(s & 1) * 32 * H;
    for (int idx = tid; idx < 32*halfH; idx += 256) {
      int row = idx / halfH, col = idx % halfH;
      *reinterpret_cast<unsigned*>(&hs[row][col*2]) =
          *reinterpret_cast<const unsigned*>(hsrc + (long)row*H + col*2);
    }
    __syncthreads();

    // recurrent GEMM: wave = gate (n-tile), m-tiles = batch 0..15 / 16..31
    f32x4 acc0 = {0.f,0.f,0.f,0.f}, acc1 = {0.f,0.f,0.f,0.f};
    for (int k0 = 0; k0 < H; k0 += 32) {
      half8 bf = *reinterpret_cast<half8*>(&BsT[wave*16 + l15][k0 + quad*8]);
      half8 a0 = *reinterpret_cast<half8*>(&hs[l15][k0 + quad*8]);
      half8 a1 = *reinterpret_cast<half8*>(&hs[16 + l15][k0 + quad*8]);
      acc0 = __builtin_amdgcn_mfma_f32_16x16x32_f16(a0, bf, acc0, 0, 0, 0);
      acc1 = __builtin_amdgcn_mfma_f32_16x16x32_f16(a1, bf, acc1, 0, 0, 0);
    }
    #pragma unroll
    for (int r = 0; r < 4; ++r) {
      gates[quad*4 + r][wave*16 + l15]      = acc0[r];
      gates[16 + quad*4 + r][wave*16 + l15] = acc1[r];
    }
    __syncthreads();

    // thread-local c/h update: units u = tid + p*256 -> b=u>>4, jj=u&15
    half_t* hdst = hbuf + (long)((s + 1) & 1) * 32 * H;
    #pragma unroll
    for (int p = 0; p < 2; ++p) {
      int u = tid + p*256;
      int b = u >> 4, jj = u & 15;
      const float* pp = pre + (long)(b*15 + t)*H4 + jb0 + jj;
      float gi = pp[0]   + gates[b][jj];
      float gf = pp[H]   + gates[b][16 + jj];
      float gg = pp[2*H] + gates[b][32 + jj];
      float go = pp[3*H] + gates[b][48 + jj];
      gi = fsig_(gi); gf = fsig_(gf); gg = ftanh_(gg); go = fsig_(go);
      float cn = gf * cst[p] + gi * gg;
      cst[p] = cn;
      float hn = go * ftanh_(cn);
      hdst[(long)b*H + jb0 + jj] = (half_t)hn;
      y[(long)(b*15 + t)*ystride + yoff + jb0 + jj] = (half_t)hn;
    }

    if (s < 29) {
      __syncthreads();           // all h stores issued & waited per-wave
      if (tid == 0) {
        __hip_atomic_fetch_add(counter, 1, __ATOMIC_RELEASE, __HIP_MEMORY_SCOPE_AGENT);
        int target = (s + 1) * nblk;
        while (__hip_atomic_load(counter, __ATOMIC_RELAXED, __HIP_MEMORY_SCOPE_AGENT) < target)
          __builtin_amdgcn_s_sleep(1);
      }
      __syncthreads();
      // per-thread acquire: invalidate caches before reading other blocks' h
      __hip_atomic_load(counter, __ATOMIC_ACQUIRE, __HIP_MEMORY_SCOPE_AGENT);
    }
  }
}

// ------------------------------------------------------------------
// Host orchestration
// ------------------------------------------------------------------
extern "C" void kernel_launch(void* const* d_in, const int* in_sizes, int n_in,
                              void* d_out, int out_size, void* d_ws, size_t ws_size,
                              hipStream_t stream)
{
  const float* x       = (const float*)d_in[0];
  const float* c1w     = (const float*)d_in[1];  const float* c1b = (const float*)d_in[2];
  const float* c2w     = (const float*)d_in[3];  const float* c2b = (const float*)d_in[4];
  const float* c3w     = (const float*)d_in[5];  const float* c3b = (const float*)d_in[6];
  const float* bn1s    = (const float*)d_in[7];  const float* bn1b = (const float*)d_in[8];
  const float* c4w     = (const float*)d_in[9];  const float* c4b = (const float*)d_in[10];
  const float* bn2s    = (const float*)d_in[11]; const float* bn2b = (const float*)d_in[12];
  const float* c5w     = (const float*)d_in[13]; const float* c5b = (const float*)d_in[14];
  const float* bn3s    = (const float*)d_in[15]; const float* bn3b = (const float*)d_in[16];
  const float* c6w     = (const float*)d_in[17]; const float* c6b = (const float*)d_in[18];
  const float* bn4s    = (const float*)d_in[19]; const float* bn4b = (const float*)d_in[20];
  const float* c7w     = (const float*)d_in[21]; const float* c7b = (const float*)d_in[22];
  const float* bn5s    = (const float*)d_in[23]; const float* bn5b = (const float*)d_in[24];
  const float* wq      = (const float*)d_in[25]; const float* bq = (const float*)d_in[26];
  const float* wk      = (const float*)d_in[27]; const float* bk = (const float*)d_in[28];
  const float* wv      = (const float*)d_in[29]; const float* bv = (const float*)d_in[30];
  const float* l1f_wx  = (const float*)d_in[31]; const float* l1f_wh = (const float*)d_in[32]; const float* l1f_b = (const float*)d_in[33];
  const float* l1r_wx  = (const float*)d_in[34]; const float* l1r_wh = (const float*)d_in[35]; const float* l1r_b = (const float*)d_in[36];
  const float* l2f_wx  = (const float*)d_in[37]; const float* l2f_wh = (const float*)d_in[38]; const float* l2f_b = (const float*)d_in[39];
  const float* l2r_wx  = (const float*)d_in[40]; const float* l2r_wh = (const float*)d_in[41]; const float* l2r_b = (const float*)d_in[42];
  const float* wo      = (const float*)d_in[43]; const float* bo = (const float*)d_in[44];
  float* outp = (float*)d_out;

  char* base = (char*)d_ws;
  half_t* actA = (half_t*)base;                    // 33,554,432 halves
  half_t* actB = (half_t*)(base + 67108864);       // 16,777,216 halves
  half_t* wtA  = (half_t*)(base + 100663296);      // ~21.5M halves
  float*  f32a = (float*)(base + 143687680);
  half_t* h16a = (half_t*)(base + 158736384);

  half_t* wt2  = wtA;
  half_t* wt3  = wtA + 73728;
  half_t* wt4  = wtA + 368640;
  half_t* wt5  = wtA + 958464;
  half_t* wt6  = wtA + 2138112;
  half_t* wt7  = wtA + 4497408;
  half_t* wtq  = wtA + 5545984;
  half_t* wtk  = wtA + 9478144;
  half_t* wtv  = wtA + 13410304;
  half_t* wt1f = wtA + 17342464;
  half_t* wt1r = wtA + 17866752;
  half_t* wt2f = wtA + 18391040;
  half_t* wt2r = wtA + 19439616;
  half_t* wto  = wtA + 20488192;

  float* q     = f32a;
  float* kk_   = f32a + 245760;
  float* v     = f32a + 491520;
  float* pre1f = f32a + 737280;
  float* pre1r = f32a + 1228800;
  float* pre2f = f32a + 1720320;
  float* pre2r = f32a + 2703360;
  int*   counters = (int*)(f32a + 3686400);  // 2 ints (separate lines)
  float* bnsums= f32a + 3760128;

  half_t* ao  = h16a;
  half_t* x1  = h16a + 245760;
  half_t* x2  = h16a + 491520;
  half_t* hb1 = h16a + 983040;    // 2 x 32 x 256 fp16
  half_t* hb2 = hb1 + 16384;      // 2 x 32 x 512 fp16

  auto tpose = [&](const float* w, half_t* wT, int K, int N){
    dim3 grid(DIV_UP(N,32), DIV_UP(K,32));
    transpose_cvt_kernel<<<grid,256,0,stream>>>(w, wT, K, N);
  };
  auto convm = [&](const half_t* in, const half_t* wt, const float* b, void* out,
                   int N,int H,int W,int Ci,int Ho,int Wo,int Co,
                   int KH,int KW,int pH,int pW,int flags){
    int M = N*Ho*Wo, K = KH*KW*Ci;
    int ciShift = __builtin_ctz((unsigned)Ci);
    dim3 grid(DIV_UP(Co,128), DIV_UP(M,128));
    mfma_conv_kernel<<<grid,256,0,stream>>>(in,wt,b,out,N,H,W,Ci,Ho,Wo,Co,
                                            KH,KW,pH,pW,ciShift,M,K,flags);
  };
  auto gemm = [&](const half_t* A, const half_t* wt, const float* b, void* out,
                  int M, int Nn, int K, int flags){
    dim3 grid(DIV_UP(Nn,128), DIV_UP(M,128));
    mfma_conv_kernel<<<grid,256,0,stream>>>(A,wt,b,out,1,1,1,K,1,1,Nn,
                                            1,1,0,0,0,M,K,flags|FLAG_DENSE);
  };
  auto pool = [&](const half_t* in, half_t* out, int N,int H,int W,int C,
                  int Ho,int Wo,int sH,int sW){
    long total = (long)N*Ho*Wo*C;
    maxpool_kernel<<<(int)DIV_UP(total,256),256,0,stream>>>(in,out,N,H,W,C,Ho,Wo,sH,sW);
  };
  auto bn = [&](half_t* buf, long nPix, int C, const float* s, const float* b){
    hipMemsetAsync(bnsums, 0, sizeof(float)*2*C, stream);
    bn_sums_kernel<<<256,256,0,stream>>>(buf, bnsums, nPix, C);
    long total = nPix * C;
    bn_apply_relu_kernel<<<(int)DIV_UP(total,256),256,0,stream>>>(buf, bnsums, s, b, total, C, 1.0f/(float)nPix);
  };

  // ---- weight preconversion ----
  tpose(c2w, wt2, 576, 128);
  tpose(c3w, wt3, 1152, 256);
  tpose(c4w, wt4, 2304, 256);
  tpose(c5w, wt5, 2304, 512);
  tpose(c6w, wt6, 4608, 512);
  tpose(c7w, wt7, 2048, 512);
  tpose(wq,  wtq, 7680, 512);
  tpose(wk,  wtk, 7680, 512);
  tpose(wv,  wtv, 7680, 512);
  tpose(l1f_wx, wt1f, 512, 1024);
  tpose(l1r_wx, wt1r, 512, 1024);
  tpose(l2f_wx, wt2f, 512, 2048);
  tpose(l2r_wx, wt2r, 512, 2048);
  tpose(wo, wto, 1024, 1000);

  // ---- conv stack (activations fp16) ----
  conv1_kernel<<<2048,256,0,stream>>>(x, c1w, c1b, actA);
  pool(actA, actB, 32,64,256,64,  32,128, 2,2);
  convm(actB, wt2, c2b, actA, 32,32,128,64,  32,128,128, 3,3,1,1, FLAG_RELU);
  pool(actA, actB, 32,32,128,128, 16,64, 2,2);
  convm(actB, wt3, c3b, actA, 32,16,64,128,  16,64,256,  3,3,1,1, 0);
  bn(actA, 32768, 256, bn1s, bn1b);
  convm(actA, wt4, c4b, actB, 32,16,64,256,  16,64,256,  3,3,1,1, 0);
  bn(actB, 32768, 256, bn2s, bn2b);
  pool(actB, actA, 32,16,64,256,  16,32, 1,2);
  convm(actA, wt5, c5b, actB, 32,16,32,256,  16,32,512,  3,3,1,1, 0);
  bn(actB, 16384, 512, bn3s, bn3b);
  convm(actB, wt6, c6b, actA, 32,16,32,512,  16,32,512,  3,3,1,1, 0);
  bn(actA, 16384, 512, bn4s, bn4b);
  pool(actA, actB, 32,16,32,512,  16,16, 1,2);
  convm(actB, wt7, c7b, actA, 32,16,16,512,  15,15,512,  2,2,0,0, 0);
  bn(actA, 7200, 512, bn5s, bn5b);

  // ---- attention: actA viewed as (480, 7680) fp16 ----
  gemm(actA, wtq, bq, q,   480, 512, 7680, FLAG_OUTF32);
  gemm(actA, wtk, bk, kk_, 480, 512, 7680, FLAG_OUTF32);
  gemm(actA, wtv, bv, v,   480, 512, 7680, FLAG_OUTF32);
  attention_kernel<<<32,256,0,stream>>>(q, kk_, v, ao, 15, 512);

  // ---- LSTM stack 1 (H=256): persistent, 16 blocks ----
  gemm(ao, wt1f, l1f_b, pre1f, 480, 1024, 512, FLAG_OUTF32);
  gemm(ao, wt1r, l1r_b, pre1r, 480, 1024, 512, FLAG_OUTF32);
  hipMemsetAsync(counters, 0, 2*sizeof(int), stream);
  hipMemsetAsync(hb1, 0, sizeof(half_t)*2*32*256, stream);
  lstm_persistent_kernel<<<16,256,0,stream>>>(
      pre1f, pre1r, l1f_wh, l1r_wh, hb1, x1, counters, 256, 16, 512, 0, 256);

  // ---- LSTM stack 2 (H=512): persistent, 32 blocks ----
  gemm(x1, wt2f, l2f_b, pre2f, 480, 2048, 512, FLAG_OUTF32);
  gemm(x1, wt2r, l2r_b, pre2r, 480, 2048, 512, FLAG_OUTF32);
  hipMemsetAsync(hb2, 0, sizeof(half_t)*2*32*512, stream);
  lstm_persistent_kernel<<<32,256,0,stream>>>(
      pre2f, pre2r, l2f_wh, l2r_wh, hb2, x2, counters + 1, 512, 32, 1024, 512, 0);

  // ---- classifier ----
  gemm(x2, wto, bo, outp, 480, 1000, 1024, FLAG_OUTF32);
}

// Round 5
// 2085.484 us; speedup vs baseline: 19.5029x; 1.2532x over previous
//
#include <hip/hip_runtime.h>
#include <math.h>

#define DIV_UP(a,b) (((a)+(b)-1)/(b))

typedef _Float16 half_t;
typedef _Float16 half8 __attribute__((ext_vector_type(8)));
typedef float f32x4 __attribute__((ext_vector_type(4)));

#define FLAG_RELU  1
#define FLAG_OUTF32 2

#define GLDS16(src, dst) \
  __builtin_amdgcn_global_load_lds((const __attribute__((address_space(1))) void*)(src), \
                                   (__attribute__((address_space(3))) void*)(dst), 16, 0, 0)

__device__ __forceinline__ float fsig_(float x){ return 1.0f/(1.0f+__expf(-x)); }
__device__ __forceinline__ float ftanh_(float x){
  float ax = fabsf(x);
  float e = __expf(-2.0f*ax);
  float t = (1.0f - e)/(1.0f + e);
  return copysignf(t, x);
}

// ------------------------------------------------------------------
// Weight transpose + fp32->fp16 convert: w[K][N] -> wT[N][K]
// ------------------------------------------------------------------
__global__ __launch_bounds__(256) void transpose_cvt_kernel(
    const float* __restrict__ w, half_t* __restrict__ wT, int K, int N)
{
  __shared__ float tile[32][33];
  int kt = blockIdx.y*32, nt = blockIdx.x*32;
  int tx = threadIdx.x & 31, ty = threadIdx.x >> 5;
  #pragma unroll
  for (int r = 0; r < 4; ++r) {
    int k = kt + ty + r*8, n = nt + tx;
    tile[ty + r*8][tx] = (k < K && n < N) ? w[(long)k*N + n] : 0.f;
  }
  __syncthreads();
  #pragma unroll
  for (int r = 0; r < 4; ++r) {
    int n = nt + ty + r*8, k = kt + tx;
    if (n < N && k < K) wT[(long)n*K + k] = (half_t)tile[tx][ty + r*8];
  }
}

// ------------------------------------------------------------------
// conv1 special case: x (32,64,256,3) fp32, w (3,3,3,64), out fp16 + ReLU.
// ------------------------------------------------------------------
__global__ __launch_bounds__(256) void conv1_kernel(
    const float* __restrict__ x, const float* __restrict__ w,
    const float* __restrict__ bias, half_t* __restrict__ out)
{
  __shared__ float xs[3][258*3];
  int nb = blockIdx.x;            // n*64 + ho
  int n = nb >> 6, ho = nb & 63;
  int tid = threadIdx.x;
  int co = tid & 63;
  float wreg[27];
  #pragma unroll
  for (int k = 0; k < 27; ++k) wreg[k] = w[k*64 + co];
  float bco = bias[co];
  for (int i = tid; i < 3*258*3; i += 256) {
    int row = i / (258*3); int rem = i % (258*3);
    int col = rem / 3;     int ci  = rem % 3;
    int ih = ho - 1 + row; int iw = col - 1;
    float v = 0.f;
    if (ih >= 0 && ih < 64 && iw >= 0 && iw < 256)
      v = x[(((long)n*64 + ih)*256 + iw)*3 + ci];
    xs[row][col*3 + ci] = v;
  }
  __syncthreads();
  int wave = tid >> 6;
  for (int p = 0; p < 64; ++p) {
    int wo = wave*64 + p;
    float acc = bco;
    #pragma unroll
    for (int kh = 0; kh < 3; ++kh)
      #pragma unroll
      for (int kw = 0; kw < 3; ++kw)
        #pragma unroll
        for (int ci = 0; ci < 3; ++ci)
          acc = fmaf(xs[kh][(wo+kw)*3 + ci], wreg[(kh*3+kw)*3 + ci], acc);
    acc = fmaxf(acc, 0.f);
    out[(((long)n*64 + ho)*256 + wo)*64 + co] = (half_t)acc;
  }
}

// ------------------------------------------------------------------
// MFMA implicit-GEMM conv/GEMM: out[M,Co] = im2col(x fp16) @ wT^T + bias.
// 128x128 tile, BK=32, 4 waves (2x2 of 64x64), mfma_f32_16x16x32_f16.
// A and B staged via global_load_lds width-16 into lane-ordered LDS
// (dst = wave-uniform base + lane*16). Tap loop hoisted: no div/mod in
// the K loop. OOB lanes load from a 16B zero buffer. Dense GEMM = the
// KH=KW=H=W=Ho=Wo=1, Ci=K case.
// ------------------------------------------------------------------
__global__ __launch_bounds__(256) void mfma_conv_kernel(
    const half_t* __restrict__ x, const half_t* __restrict__ wT,
    const float* __restrict__ bias, void* __restrict__ outPtr,
    const half_t* __restrict__ zbuf,
    int N,int H,int W,int Ci,int Ho,int Wo,int Co,
    int KH,int KW,int padH,int padW,
    int M,int K,int flags)
{
  __shared__ half_t As[128*32];
  __shared__ half_t Bs[128*32];
  int tid = threadIdx.x;
  int m0 = blockIdx.y*128, n0 = blockIdx.x*128;
  int wave = tid >> 6, lane = tid & 63;
  int l15 = lane & 15, quad = lane >> 4;
  int wm = (wave & 1) * 64, wn = (wave >> 1) * 64;
  int colOff = (tid & 3) * 8;      // halves within a 32-chunk
  int rIdx = tid >> 2;             // 0..63: row within half-tile

  // A row decode per chunk c (rows c*64 + rIdx)
  int ho_[2], wo_[2], ni_[2]; bool av_[2];
  #pragma unroll
  for (int c = 0; c < 2; ++c) {
    int m = m0 + c*64 + rIdx;
    av_[c] = m < M;
    int mm = av_[c] ? m : 0;
    wo_[c] = mm % Wo; int t2 = mm / Wo;
    ho_[c] = t2 % Ho; ni_[c] = t2 / Ho;
  }
  // B base per chunk
  const half_t* bBase[2];
  #pragma unroll
  for (int c = 0; c < 2; ++c) {
    int n = n0 + c*64 + rIdx;
    bBase[c] = (n < Co) ? (wT + (long)n*K + colOff) : nullptr;
  }
  // wave-uniform LDS destinations
  half_t* aDst[2] = { As + wave*512, As + 2048 + wave*512 };
  half_t* bDst[2] = { Bs + wave*512, Bs + 2048 + wave*512 };

  f32x4 acc[4][4];
  #pragma unroll
  for (int i = 0; i < 4; ++i)
    #pragma unroll
    for (int j = 0; j < 4; ++j)
      acc[i][j] = (f32x4){0.f, 0.f, 0.f, 0.f};

  int kg = 0;
  for (int kh = 0; kh < KH; ++kh) {
    for (int kw = 0; kw < KW; ++kw) {
      const half_t* aTap[2];
      #pragma unroll
      for (int c = 0; c < 2; ++c) {
        int ih = ho_[c] - padH + kh, iw = wo_[c] - padW + kw;
        bool v = av_[c] && ih >= 0 && ih < H && iw >= 0 && iw < W;
        aTap[c] = v ? (x + (((long)ni_[c]*H + ih)*W + iw)*(long)Ci + colOff)
                    : nullptr;
      }
      for (int ci = 0; ci < Ci; ci += 32, kg += 32) {
        #pragma unroll
        for (int c = 0; c < 2; ++c) {
          const half_t* sa = aTap[c] ? aTap[c] + ci : zbuf;
          GLDS16(sa, aDst[c]);
          const half_t* sb = bBase[c] ? bBase[c] + kg : zbuf;
          GLDS16(sb, bDst[c]);
        }
        __syncthreads();
        half8 af[4], bf[4];
        #pragma unroll
        for (int i = 0; i < 4; ++i)
          af[i] = *reinterpret_cast<half8*>(&As[(wm + i*16 + l15)*32 + quad*8]);
        #pragma unroll
        for (int j = 0; j < 4; ++j)
          bf[j] = *reinterpret_cast<half8*>(&Bs[(wn + j*16 + l15)*32 + quad*8]);
        #pragma unroll
        for (int i = 0; i < 4; ++i)
          #pragma unroll
          for (int j = 0; j < 4; ++j)
            acc[i][j] = __builtin_amdgcn_mfma_f32_16x16x32_f16(af[i], bf[j], acc[i][j], 0, 0, 0);
        __syncthreads();
      }
    }
  }

  #pragma unroll
  for (int i = 0; i < 4; ++i) {
    #pragma unroll
    for (int r = 0; r < 4; ++r) {
      int m = m0 + wm + i*16 + quad*4 + r;
      if (m >= M) continue;
      #pragma unroll
      for (int j = 0; j < 4; ++j) {
        int n = n0 + wn + j*16 + l15;
        if (n >= Co) continue;
        float v = acc[i][j][r] + bias[n];
        if (flags & FLAG_RELU) v = fmaxf(v, 0.f);
        if (flags & FLAG_OUTF32) ((float*)outPtr)[(long)m*Co + n] = v;
        else ((half_t*)outPtr)[(long)m*Co + n] = (half_t)v;
      }
    }
  }
}

// ------------------------------------------------------------------
// Max pool fp16, NHWC, 8 channels per thread.
// ------------------------------------------------------------------
__global__ __launch_bounds__(256) void maxpool8_kernel(
    const half_t* __restrict__ x, half_t* __restrict__ out,
    int N,int H,int W,int C,int Ho,int Wo,int sH,int sW)
{
  int C8 = C >> 3;
  long idx = (long)blockIdx.x*256 + threadIdx.x;
  long total8 = (long)N*Ho*Wo*C8;
  if (idx >= total8) return;
  int cb = (int)(idx % C8);
  long pix = idx / C8;
  int wo = (int)(pix % Wo); long t2 = pix / Wo;
  int ho = (int)(t2 % Ho); int n = (int)(t2 / Ho);
  int c = cb * 8;
  float m[8];
  #pragma unroll
  for (int e = 0; e < 8; ++e) m[e] = -INFINITY;
  for (int i = 0; i < 2; ++i) {
    int ih = ho*sH + i;
    if (ih >= H) continue;
    for (int j = 0; j < 2; ++j) {
      int iw = wo*sW + j;
      if (iw >= W) continue;
      half8 v = *reinterpret_cast<const half8*>(x + (((long)n*H + ih)*W + iw)*C + c);
      #pragma unroll
      for (int e = 0; e < 8; ++e) m[e] = fmaxf(m[e], (float)v[e]);
    }
  }
  half8 o;
  #pragma unroll
  for (int e = 0; e < 8; ++e) o[e] = (half_t)m[e];
  *reinterpret_cast<half8*>(out + idx*8) = o;
}

// ------------------------------------------------------------------
// BN (training) stats over fp16 activations, fp32 accumulate + atomics.
// ------------------------------------------------------------------
__global__ __launch_bounds__(256) void bn_sums_kernel(
    const half_t* __restrict__ x, float* __restrict__ sums, long nPix, int C)
{
  long rowsPer = (nPix + gridDim.x - 1) / gridDim.x;
  long r0 = (long)blockIdx.x * rowsPer;
  long r1 = r0 + rowsPer; if (r1 > nPix) r1 = nPix;
  float a0 = 0.f, q0 = 0.f, a1 = 0.f, q1 = 0.f;
  for (long r = r0; r < r1; ++r) {
    const half_t* xp = x + r*C;
    { float v = (float)xp[threadIdx.x]; a0 += v; q0 += v*v; }
    if (C > 256) { float v = (float)xp[256 + threadIdx.x]; a1 += v; q1 += v*v; }
  }
  atomicAdd(&sums[threadIdx.x], a0);
  atomicAdd(&sums[C + threadIdx.x], q0);
  if (C > 256) {
    atomicAdd(&sums[256 + threadIdx.x], a1);
    atomicAdd(&sums[C + 256 + threadIdx.x], q1);
  }
}

__global__ __launch_bounds__(256) void bn_apply_relu8_kernel(
    half_t* __restrict__ x, const float* __restrict__ sums,
    const float* __restrict__ scale, const float* __restrict__ bias,
    long total8, int C, float invN)
{
  long idx = (long)blockIdx.x*256 + threadIdx.x;
  if (idx >= total8) return;
  int c = (int)((idx*8) % C);
  half8 v = *reinterpret_cast<half8*>(x + idx*8);
  half8 o;
  #pragma unroll
  for (int e = 0; e < 8; ++e) {
    float mean = sums[c+e] * invN;
    float var  = sums[C + c+e] * invN - mean*mean;
    float rstd = rsqrtf(var + 1e-5f);
    float y = ((float)v[e] - mean) * rstd * scale[c+e] + bias[c+e];
    o[e] = (half_t)fmaxf(y, 0.0f);
  }
  *reinterpret_cast<half8*>(x + idx*8) = o;
}

// ------------------------------------------------------------------
// Attention (T=15, D=512), q/k/v fp32, out fp16.
// ------------------------------------------------------------------
__global__ __launch_bounds__(256) void attention_kernel(
    const float* __restrict__ q, const float* __restrict__ k,
    const float* __restrict__ v, half_t* __restrict__ out, int T, int D)
{
  int b = blockIdx.x;
  int tid = threadIdx.x;
  __shared__ float P[15][16];
  if (tid < T*T) {
    int t = tid / T, s = tid % T;
    const float* qp = q + ((long)b*T + t)*D;
    const float* kp = k + ((long)b*T + s)*D;
    float acc = 0.f;
    for (int d = 0; d < D; d += 4) {
      float4 qv = *reinterpret_cast<const float4*>(qp + d);
      float4 kv = *reinterpret_cast<const float4*>(kp + d);
      acc += qv.x*kv.x + qv.y*kv.y + qv.z*kv.z + qv.w*kv.w;
    }
    P[t][s] = acc * (1.0f/32.0f);
  }
  __syncthreads();
  if (tid < T) {
    float mx = -INFINITY;
    for (int s = 0; s < T; ++s) mx = fmaxf(mx, P[tid][s]);
    float sum = 0.f;
    for (int s = 0; s < T; ++s) { float e = expf(P[tid][s] - mx); P[tid][s] = e; sum += e; }
    float inv = 1.0f / sum;
    for (int s = 0; s < T; ++s) P[tid][s] *= inv;
  }
  __syncthreads();
  for (int idx = tid; idx < T*D; idx += 256) {
    int s = idx / D, kk2 = idx % D;
    float acc = 0.f;
    #pragma unroll
    for (int t = 0; t < 15; ++t) acc += v[((long)b*15 + t)*D + kk2] * P[t][s];
    out[((long)b*T + s)*D + kk2] = (half_t)acc;
  }
}

// ------------------------------------------------------------------
// Persistent bidirectional LSTM stack. Same structure as round 4, but the
// grid barrier is a flag ARRAY (one padded line per block, release store +
// 64-lane parallel poll) instead of a contended RMW counter; h is exchanged
// as packed 32-bit agent-scope atomic stores.
// ------------------------------------------------------------------
#define MAXK 512
__global__ __launch_bounds__(256, 1) void lstm_persistent_kernel(
    const float* __restrict__ preF, const float* __restrict__ preR,
    const float* __restrict__ whF, const float* __restrict__ whR,
    half_t* __restrict__ hbuf, half_t* __restrict__ y,
    int* __restrict__ flags, int H, int nblk,
    int ystride, int yoffF, int yoffR)
{
  __shared__ half_t BsT[64][MAXK + 8];
  __shared__ half_t hs[32][MAXK + 8];
  __shared__ float gates[32][65];
  int tid = threadIdx.x;
  int jb0 = blockIdx.x * 16;
  int H4 = 4 * H;
  int lane = tid & 63, wave = tid >> 6;
  int l15 = lane & 15, quad = lane >> 4;
  int chunks = H >> 3;

  float cst[2] = {0.f, 0.f};   // cell state for units (b, jj0), (b, jj0+1)

  for (int idx = tid; idx < H*64; idx += 256) {
    int k = idx >> 6, c = idx & 63;
    int g = c >> 4, jj = c & 15;
    BsT[c][k] = (half_t)whF[(long)k*H4 + g*H + jb0 + jj];
  }
  const float* pre = preF;
  int yoff = yoffF;
  __syncthreads();

  for (int s = 0; s < 30; ++s) {
    if (s == 15) {               // fwd -> rev (carry chains through)
      __syncthreads();
      for (int idx = tid; idx < H*64; idx += 256) {
        int k = idx >> 6, c = idx & 63;
        int g = c >> 4, jj = c & 15;
        BsT[c][k] = (half_t)whR[(long)k*H4 + g*H + jb0 + jj];
      }
      pre = preR; yoff = yoffR;
      __syncthreads();
    }
    int t = (s < 15) ? s : 29 - s;

    // stage h(prev) from global ping buffer (vectorized)
    const half_t* hsrc = hbuf + (long)(s & 1) * 32 * H;
    for (int idx = tid; idx < 32*chunks; idx += 256) {
      int row = idx / chunks, col = (idx - row*chunks) * 8;
      *reinterpret_cast<half8*>(&hs[row][col]) =
          *reinterpret_cast<const half8*>(hsrc + (long)row*H + col);
    }
    __syncthreads();

    // recurrent GEMM: wave = gate, m-tiles = batches 0..15 / 16..31
    f32x4 acc0 = {0.f,0.f,0.f,0.f}, acc1 = {0.f,0.f,0.f,0.f};
    for (int k0 = 0; k0 < H; k0 += 32) {
      half8 bf = *reinterpret_cast<half8*>(&BsT[wave*16 + l15][k0 + quad*8]);
      half8 a0 = *reinterpret_cast<half8*>(&hs[l15][k0 + quad*8]);
      half8 a1 = *reinterpret_cast<half8*>(&hs[16 + l15][k0 + quad*8]);
      acc0 = __builtin_amdgcn_mfma_f32_16x16x32_f16(a0, bf, acc0, 0, 0, 0);
      acc1 = __builtin_amdgcn_mfma_f32_16x16x32_f16(a1, bf, acc1, 0, 0, 0);
    }
    #pragma unroll
    for (int r = 0; r < 4; ++r) {
      gates[quad*4 + r][wave*16 + l15]      = acc0[r];
      gates[16 + quad*4 + r][wave*16 + l15] = acc1[r];
    }
    __syncthreads();

    // c/h update: thread owns units (b, jj0) and (b, jj0+1)
    {
      int b = tid >> 3;
      int jj0 = (tid & 7) * 2;
      const float* pp = pre + (long)(b*15 + t)*H4 + jb0 + jj0;
      half_t hn2[2];
      #pragma unroll
      for (int p = 0; p < 2; ++p) {
        int jj = jj0 + p;
        float gi = pp[p]       + gates[b][jj];
        float gf = pp[H + p]   + gates[b][16 + jj];
        float gg = pp[2*H + p] + gates[b][32 + jj];
        float go = pp[3*H + p] + gates[b][48 + jj];
        gi = fsig_(gi); gf = fsig_(gf); gg = ftanh_(gg); go = fsig_(go);
        float cn = gf * cst[p] + gi * gg;
        cst[p] = cn;
        hn2[p] = (half_t)(go * ftanh_(cn));
      }
      unsigned hpack = *reinterpret_cast<unsigned*>(hn2);
      half_t* hdst = hbuf + (long)((s + 1) & 1) * 32 * H;
      __hip_atomic_store((unsigned*)(hdst + (long)b*H + jb0 + jj0), hpack,
                         __ATOMIC_RELAXED, __HIP_MEMORY_SCOPE_AGENT);
      *reinterpret_cast<unsigned*>(&y[(long)(b*15 + t)*ystride + yoff + jb0 + jj0]) = hpack;
    }

    if (s < 29) {
      __syncthreads();           // all h stores complete (vmcnt drained)
      if (tid == 0)
        __hip_atomic_store(&flags[blockIdx.x*16], s + 1,
                           __ATOMIC_RELEASE, __HIP_MEMORY_SCOPE_AGENT);
      if (tid < 64) {
        int target = s + 1;
        for (;;) {
          int vv = (tid < nblk)
            ? __hip_atomic_load(&flags[tid*16], __ATOMIC_RELAXED, __HIP_MEMORY_SCOPE_AGENT)
            : target;
          if (__all(vv >= target)) break;
          __builtin_amdgcn_s_sleep(4);
        }
      }
      __syncthreads();
      // acquire: order subsequent h reads after observed flags
      __hip_atomic_load(&flags[0], __ATOMIC_ACQUIRE, __HIP_MEMORY_SCOPE_AGENT);
    }
  }
}

// ------------------------------------------------------------------
// Host orchestration
// ------------------------------------------------------------------
extern "C" void kernel_launch(void* const* d_in, const int* in_sizes, int n_in,
                              void* d_out, int out_size, void* d_ws, size_t ws_size,
                              hipStream_t stream)
{
  const float* x       = (const float*)d_in[0];
  const float* c1w     = (const float*)d_in[1];  const float* c1b = (const float*)d_in[2];
  const float* c2w     = (const float*)d_in[3];  const float* c2b = (const float*)d_in[4];
  const float* c3w     = (const float*)d_in[5];  const float* c3b = (const float*)d_in[6];
  const float* bn1s    = (const float*)d_in[7];  const float* bn1b = (const float*)d_in[8];
  const float* c4w     = (const float*)d_in[9];  const float* c4b = (const float*)d_in[10];
  const float* bn2s    = (const float*)d_in[11]; const float* bn2b = (const float*)d_in[12];
  const float* c5w     = (const float*)d_in[13]; const float* c5b = (const float*)d_in[14];
  const float* bn3s    = (const float*)d_in[15]; const float* bn3b = (const float*)d_in[16];
  const float* c6w     = (const float*)d_in[17]; const float* c6b = (const float*)d_in[18];
  const float* bn4s    = (const float*)d_in[19]; const float* bn4b = (const float*)d_in[20];
  const float* c7w     = (const float*)d_in[21]; const float* c7b = (const float*)d_in[22];
  const float* bn5s    = (const float*)d_in[23]; const float* bn5b = (const float*)d_in[24];
  const float* wq      = (const float*)d_in[25]; const float* bq = (const float*)d_in[26];
  const float* wk      = (const float*)d_in[27]; const float* bk = (const float*)d_in[28];
  const float* wv      = (const float*)d_in[29]; const float* bv = (const float*)d_in[30];
  const float* l1f_wx  = (const float*)d_in[31]; const float* l1f_wh = (const float*)d_in[32]; const float* l1f_b = (const float*)d_in[33];
  const float* l1r_wx  = (const float*)d_in[34]; const float* l1r_wh = (const float*)d_in[35]; const float* l1r_b = (const float*)d_in[36];
  const float* l2f_wx  = (const float*)d_in[37]; const float* l2f_wh = (const float*)d_in[38]; const float* l2f_b = (const float*)d_in[39];
  const float* l2r_wx  = (const float*)d_in[40]; const float* l2r_wh = (const float*)d_in[41]; const float* l2r_b = (const float*)d_in[42];
  const float* wo      = (const float*)d_in[43]; const float* bo = (const float*)d_in[44];
  float* outp = (float*)d_out;

  char* base = (char*)d_ws;
  half_t* actA = (half_t*)base;                    // 33,554,432 halves
  half_t* actB = (half_t*)(base + 67108864);       // 16,777,216 halves
  half_t* wtA  = (half_t*)(base + 100663296);
  float*  f32a = (float*)(base + 143687680);
  half_t* h16a = (half_t*)(base + 158736384);

  half_t* wt2  = wtA;
  half_t* wt3  = wtA + 73728;
  half_t* wt4  = wtA + 368640;
  half_t* wt5  = wtA + 958464;
  half_t* wt6  = wtA + 2138112;
  half_t* wt7  = wtA + 4497408;
  half_t* wtq  = wtA + 5545984;
  half_t* wtk  = wtA + 9478144;
  half_t* wtv  = wtA + 13410304;
  half_t* wt1f = wtA + 17342464;
  half_t* wt1r = wtA + 17866752;
  half_t* wt2f = wtA + 18391040;
  half_t* wt2r = wtA + 19439616;
  half_t* wto  = wtA + 20488192;

  float* q     = f32a;
  float* kk_   = f32a + 245760;
  float* v     = f32a + 491520;
  float* pre1f = f32a + 737280;
  float* pre1r = f32a + 1228800;
  float* pre2f = f32a + 1720320;
  float* pre2r = f32a + 2703360;
  float* bnsums= f32a + 3760128;

  half_t* ao  = h16a;
  half_t* x1  = h16a + 245760;
  half_t* x2  = h16a + 491520;
  half_t* hb1 = h16a + 983040;    // 2 x 32 x 256 fp16
  half_t* hb2 = hb1 + 16384;      // 2 x 32 x 512 fp16
  int*    flags1 = (int*)(hb2 + 32768);   // 512 ints (32 x 16 pad)
  int*    flags2 = flags1 + 512;
  half_t* zbuf   = (half_t*)(flags2 + 512);  // 16 halves of zeros

  auto tpose = [&](const float* w, half_t* wT, int K, int N){
    dim3 grid(DIV_UP(N,32), DIV_UP(K,32));
    transpose_cvt_kernel<<<grid,256,0,stream>>>(w, wT, K, N);
  };
  auto convm = [&](const half_t* in, const half_t* wt, const float* b, void* out,
                   int N,int H,int W,int Ci,int Ho,int Wo,int Co,
                   int KH,int KW,int pH,int pW,int flags){
    int M = N*Ho*Wo, K = KH*KW*Ci;
    dim3 grid(DIV_UP(Co,128), DIV_UP(M,128));
    mfma_conv_kernel<<<grid,256,0,stream>>>(in,wt,b,out,zbuf,N,H,W,Ci,Ho,Wo,Co,
                                            KH,KW,pH,pW,M,K,flags);
  };
  auto gemm = [&](const half_t* A, const half_t* wt, const float* b, void* out,
                  int M, int Nn, int K, int flags){
    dim3 grid(DIV_UP(Nn,128), DIV_UP(M,128));
    mfma_conv_kernel<<<grid,256,0,stream>>>(A,wt,b,out,zbuf,M,1,1,K,1,1,Nn,
                                            1,1,0,0,M,K,flags);
  };
  auto pool = [&](const half_t* in, half_t* out, int N,int H,int W,int C,
                  int Ho,int Wo,int sH,int sW){
    long total8 = (long)N*Ho*Wo*(C/8);
    maxpool8_kernel<<<(int)DIV_UP(total8,256),256,0,stream>>>(in,out,N,H,W,C,Ho,Wo,sH,sW);
  };
  auto bn = [&](half_t* buf, long nPix, int C, const float* s, const float* b){
    hipMemsetAsync(bnsums, 0, sizeof(float)*2*C, stream);
    bn_sums_kernel<<<1024,256,0,stream>>>(buf, bnsums, nPix, C);
    long total8 = nPix * C / 8;
    bn_apply_relu8_kernel<<<(int)DIV_UP(total8,256),256,0,stream>>>(buf, bnsums, s, b, total8, C, 1.0f/(float)nPix);
  };

  // zero scratch used for OOB loads + barrier flags + h buffers
  hipMemsetAsync(zbuf, 0, sizeof(half_t)*16, stream);
  hipMemsetAsync(flags1, 0, sizeof(int)*1024, stream);
  hipMemsetAsync(hb1, 0, sizeof(half_t)*(16384 + 32768), stream);

  // ---- weight preconversion ----
  tpose(c2w, wt2, 576, 128);
  tpose(c3w, wt3, 1152, 256);
  tpose(c4w, wt4, 2304, 256);
  tpose(c5w, wt5, 2304, 512);
  tpose(c6w, wt6, 4608, 512);
  tpose(c7w, wt7, 2048, 512);
  tpose(wq,  wtq, 7680, 512);
  tpose(wk,  wtk, 7680, 512);
  tpose(wv,  wtv, 7680, 512);
  tpose(l1f_wx, wt1f, 512, 1024);
  tpose(l1r_wx, wt1r, 512, 1024);
  tpose(l2f_wx, wt2f, 512, 2048);
  tpose(l2r_wx, wt2r, 512, 2048);
  tpose(wo, wto, 1024, 1000);

  // ---- conv stack (activations fp16) ----
  conv1_kernel<<<2048,256,0,stream>>>(x, c1w, c1b, actA);
  pool(actA, actB, 32,64,256,64,  32,128, 2,2);
  convm(actB, wt2, c2b, actA, 32,32,128,64,  32,128,128, 3,3,1,1, FLAG_RELU);
  pool(actA, actB, 32,32,128,128, 16,64, 2,2);
  convm(actB, wt3, c3b, actA, 32,16,64,128,  16,64,256,  3,3,1,1, 0);
  bn(actA, 32768, 256, bn1s, bn1b);
  convm(actA, wt4, c4b, actB, 32,16,64,256,  16,64,256,  3,3,1,1, 0);
  bn(actB, 32768, 256, bn2s, bn2b);
  pool(actB, actA, 32,16,64,256,  16,32, 1,2);
  convm(actA, wt5, c5b, actB, 32,16,32,256,  16,32,512,  3,3,1,1, 0);
  bn(actB, 16384, 512, bn3s, bn3b);
  convm(actB, wt6, c6b, actA, 32,16,32,512,  16,32,512,  3,3,1,1, 0);
  bn(actA, 16384, 512, bn4s, bn4b);
  pool(actA, actB, 32,16,32,512,  16,16, 1,2);
  convm(actB, wt7, c7b, actA, 32,16,16,512,  15,15,512,  2,2,0,0, 0);
  bn(actA, 7200, 512, bn5s, bn5b);

  // ---- attention: actA viewed as (480, 7680) fp16 ----
  gemm(actA, wtq, bq, q,   480, 512, 7680, FLAG_OUTF32);
  gemm(actA, wtk, bk, kk_, 480, 512, 7680, FLAG_OUTF32);
  gemm(actA, wtv, bv, v,   480, 512, 7680, FLAG_OUTF32);
  attention_kernel<<<32,256,0,stream>>>(q, kk_, v, ao, 15, 512);

  // ---- LSTM stack 1 (H=256): persistent, 16 blocks ----
  gemm(ao, wt1f, l1f_b, pre1f, 480, 1024, 512, FLAG_OUTF32);
  gemm(ao, wt1r, l1r_b, pre1r, 480, 1024, 512, FLAG_OUTF32);
  lstm_persistent_kernel<<<16,256,0,stream>>>(
      pre1f, pre1r, l1f_wh, l1r_wh, hb1, x1, flags1, 256, 16, 512, 0, 256);

  // ---- LSTM stack 2 (H=512): persistent, 32 blocks ----
  gemm(x1, wt2f, l2f_b, pre2f, 480, 2048, 512, FLAG_OUTF32);
  gemm(x1, wt2r, l2r_b, pre2r, 480, 2048, 512, FLAG_OUTF32);
  lstm_persistent_kernel<<<32,256,0,stream>>>(
      pre2f, pre2r, l2f_wh, l2r_wh, hb2, x2, flags2, 512, 32, 1024, 512, 0);

  // ---- classifier ----
  gemm(x2, wto, bo, outp, 480, 1000, 1024, FLAG_OUTF32);
}

// Round 6
// 1552.399 us; speedup vs baseline: 26.2000x; 1.3434x over previous
//
#include <hip/hip_runtime.h>
#include <math.h>

#define DIV_UP(a,b) (((a)+(b)-1)/(b))

typedef _Float16 half_t;
typedef _Float16 half8 __attribute__((ext_vector_type(8)));
typedef float f32x4 __attribute__((ext_vector_type(4)));

#define FLAG_RELU  1
#define FLAG_OUTF32 2

#define GLDS16(src, dst) \
  __builtin_amdgcn_global_load_lds((const __attribute__((address_space(1))) void*)(src), \
                                   (__attribute__((address_space(3))) void*)(dst), 16, 0, 0)

__device__ __forceinline__ float fsig_(float x){ return 1.0f/(1.0f+__expf(-x)); }
__device__ __forceinline__ float ftanh_(float x){
  float ax = fabsf(x);
  float e = __expf(-2.0f*ax);
  float t = (1.0f - e)/(1.0f + e);
  return copysignf(t, x);
}

// ------------------------------------------------------------------
// Weight transpose + fp32->fp16 convert: w[K][N] -> wT[N][K]
// ------------------------------------------------------------------
__global__ __launch_bounds__(256) void transpose_cvt_kernel(
    const float* __restrict__ w, half_t* __restrict__ wT, int K, int N)
{
  __shared__ float tile[32][33];
  int kt = blockIdx.y*32, nt = blockIdx.x*32;
  int tx = threadIdx.x & 31, ty = threadIdx.x >> 5;
  #pragma unroll
  for (int r = 0; r < 4; ++r) {
    int k = kt + ty + r*8, n = nt + tx;
    tile[ty + r*8][tx] = (k < K && n < N) ? w[(long)k*N + n] : 0.f;
  }
  __syncthreads();
  #pragma unroll
  for (int r = 0; r < 4; ++r) {
    int n = nt + ty + r*8, k = kt + tx;
    if (n < N && k < K) wT[(long)n*K + k] = (half_t)tile[tx][ty + r*8];
  }
}

// ------------------------------------------------------------------
// conv1 special case: x (32,64,256,3) fp32, w (3,3,3,64), out fp16 + ReLU.
// ------------------------------------------------------------------
__global__ __launch_bounds__(256) void conv1_kernel(
    const float* __restrict__ x, const float* __restrict__ w,
    const float* __restrict__ bias, half_t* __restrict__ out)
{
  __shared__ float xs[3][258*3];
  int nb = blockIdx.x;            // n*64 + ho
  int n = nb >> 6, ho = nb & 63;
  int tid = threadIdx.x;
  int co = tid & 63;
  float wreg[27];
  #pragma unroll
  for (int k = 0; k < 27; ++k) wreg[k] = w[k*64 + co];
  float bco = bias[co];
  for (int i = tid; i < 3*258*3; i += 256) {
    int row = i / (258*3); int rem = i % (258*3);
    int col = rem / 3;     int ci  = rem % 3;
    int ih = ho - 1 + row; int iw = col - 1;
    float v = 0.f;
    if (ih >= 0 && ih < 64 && iw >= 0 && iw < 256)
      v = x[(((long)n*64 + ih)*256 + iw)*3 + ci];
    xs[row][col*3 + ci] = v;
  }
  __syncthreads();
  int wave = tid >> 6;
  for (int p = 0; p < 64; ++p) {
    int wo = wave*64 + p;
    float acc = bco;
    #pragma unroll
    for (int kh = 0; kh < 3; ++kh)
      #pragma unroll
      for (int kw = 0; kw < 3; ++kw)
        #pragma unroll
        for (int ci = 0; ci < 3; ++ci)
          acc = fmaf(xs[kh][(wo+kw)*3 + ci], wreg[(kh*3+kw)*3 + ci], acc);
    acc = fmaxf(acc, 0.f);
    out[(((long)n*64 + ho)*256 + wo)*64 + co] = (half_t)acc;
  }
}

// ------------------------------------------------------------------
// MFMA implicit-GEMM conv/GEMM: out[M,Co] = im2col(x fp16) @ wT^T + bias.
// 128x128 tile, BK=32, 4 waves, mfma_f32_16x16x32_f16, global_load_lds
// width-16 staging. blockIdx.z selects among up to 3 (wT,bias,out) sets
// sharing the same A (qkv, LSTM pre-GEMM pairs). Dense GEMM = 1x1 case.
// ------------------------------------------------------------------
struct GOut { const half_t* wT; const float* bias; void* out; };

__global__ __launch_bounds__(256) void mfma_conv_kernel(
    const half_t* __restrict__ x, GOut g0, GOut g1, GOut g2,
    const half_t* __restrict__ zbuf,
    int N,int H,int W,int Ci,int Ho,int Wo,int Co,
    int KH,int KW,int padH,int padW,
    int M,int K,int flags)
{
  GOut g = (blockIdx.z == 0) ? g0 : (blockIdx.z == 1 ? g1 : g2);
  const half_t* __restrict__ wT = g.wT;
  __shared__ half_t As[128*32];
  __shared__ half_t Bs[128*32];
  int tid = threadIdx.x;
  int m0 = blockIdx.y*128, n0 = blockIdx.x*128;
  int wave = tid >> 6, lane = tid & 63;
  int l15 = lane & 15, quad = lane >> 4;
  int wm = (wave & 1) * 64, wn = (wave >> 1) * 64;
  int colOff = (tid & 3) * 8;      // halves within a 32-chunk
  int rIdx = tid >> 2;             // 0..63: row within half-tile

  int ho_[2], wo_[2], ni_[2]; bool av_[2];
  #pragma unroll
  for (int c = 0; c < 2; ++c) {
    int m = m0 + c*64 + rIdx;
    av_[c] = m < M;
    int mm = av_[c] ? m : 0;
    wo_[c] = mm % Wo; int t2 = mm / Wo;
    ho_[c] = t2 % Ho; ni_[c] = t2 / Ho;
  }
  const half_t* bBase[2];
  #pragma unroll
  for (int c = 0; c < 2; ++c) {
    int n = n0 + c*64 + rIdx;
    bBase[c] = (n < Co) ? (wT + (long)n*K + colOff) : nullptr;
  }
  half_t* aDst[2] = { As + wave*512, As + 2048 + wave*512 };
  half_t* bDst[2] = { Bs + wave*512, Bs + 2048 + wave*512 };

  f32x4 acc[4][4];
  #pragma unroll
  for (int i = 0; i < 4; ++i)
    #pragma unroll
    for (int j = 0; j < 4; ++j)
      acc[i][j] = (f32x4){0.f, 0.f, 0.f, 0.f};

  int kg = 0;
  for (int kh = 0; kh < KH; ++kh) {
    for (int kw = 0; kw < KW; ++kw) {
      const half_t* aTap[2];
      #pragma unroll
      for (int c = 0; c < 2; ++c) {
        int ih = ho_[c] - padH + kh, iw = wo_[c] - padW + kw;
        bool v = av_[c] && ih >= 0 && ih < H && iw >= 0 && iw < W;
        aTap[c] = v ? (x + (((long)ni_[c]*H + ih)*W + iw)*(long)Ci + colOff)
                    : nullptr;
      }
      for (int ci = 0; ci < Ci; ci += 32, kg += 32) {
        #pragma unroll
        for (int c = 0; c < 2; ++c) {
          const half_t* sa = aTap[c] ? aTap[c] + ci : zbuf;
          GLDS16(sa, aDst[c]);
          const half_t* sb = bBase[c] ? bBase[c] + kg : zbuf;
          GLDS16(sb, bDst[c]);
        }
        __syncthreads();
        half8 af[4], bf[4];
        #pragma unroll
        for (int i = 0; i < 4; ++i)
          af[i] = *reinterpret_cast<half8*>(&As[(wm + i*16 + l15)*32 + quad*8]);
        #pragma unroll
        for (int j = 0; j < 4; ++j)
          bf[j] = *reinterpret_cast<half8*>(&Bs[(wn + j*16 + l15)*32 + quad*8]);
        #pragma unroll
        for (int i = 0; i < 4; ++i)
          #pragma unroll
          for (int j = 0; j < 4; ++j)
            acc[i][j] = __builtin_amdgcn_mfma_f32_16x16x32_f16(af[i], bf[j], acc[i][j], 0, 0, 0);
        __syncthreads();
      }
    }
  }

  #pragma unroll
  for (int i = 0; i < 4; ++i) {
    #pragma unroll
    for (int r = 0; r < 4; ++r) {
      int m = m0 + wm + i*16 + quad*4 + r;
      if (m >= M) continue;
      #pragma unroll
      for (int j = 0; j < 4; ++j) {
        int n = n0 + wn + j*16 + l15;
        if (n >= Co) continue;
        float v = acc[i][j][r] + g.bias[n];
        if (flags & FLAG_RELU) v = fmaxf(v, 0.f);
        if (flags & FLAG_OUTF32) ((float*)g.out)[(long)m*Co + n] = v;
        else ((half_t*)g.out)[(long)m*Co + n] = (half_t)v;
      }
    }
  }
}

// ------------------------------------------------------------------
// Max pool fp16, NHWC, 8 channels per thread.
// ------------------------------------------------------------------
__global__ __launch_bounds__(256) void maxpool8_kernel(
    const half_t* __restrict__ x, half_t* __restrict__ out,
    int N,int H,int W,int C,int Ho,int Wo,int sH,int sW)
{
  int C8 = C >> 3;
  long idx = (long)blockIdx.x*256 + threadIdx.x;
  long total8 = (long)N*Ho*Wo*C8;
  if (idx >= total8) return;
  int cb = (int)(idx % C8);
  long pix = idx / C8;
  int wo = (int)(pix % Wo); long t2 = pix / Wo;
  int ho = (int)(t2 % Ho); int n = (int)(t2 / Ho);
  int c = cb * 8;
  float m[8];
  #pragma unroll
  for (int e = 0; e < 8; ++e) m[e] = -INFINITY;
  for (int i = 0; i < 2; ++i) {
    int ih = ho*sH + i;
    if (ih >= H) continue;
    for (int j = 0; j < 2; ++j) {
      int iw = wo*sW + j;
      if (iw >= W) continue;
      half8 v = *reinterpret_cast<const half8*>(x + (((long)n*H + ih)*W + iw)*C + c);
      #pragma unroll
      for (int e = 0; e < 8; ++e) m[e] = fmaxf(m[e], (float)v[e]);
    }
  }
  half8 o;
  #pragma unroll
  for (int e = 0; e < 8; ++e) o[e] = (half_t)m[e];
  *reinterpret_cast<half8*>(out + idx*8) = o;
}

// ------------------------------------------------------------------
// BN (training) stats over fp16 activations, fp32 accumulate + atomics.
// ------------------------------------------------------------------
__global__ __launch_bounds__(256) void bn_sums_kernel(
    const half_t* __restrict__ x, float* __restrict__ sums, long nPix, int C)
{
  long rowsPer = (nPix + gridDim.x - 1) / gridDim.x;
  long r0 = (long)blockIdx.x * rowsPer;
  long r1 = r0 + rowsPer; if (r1 > nPix) r1 = nPix;
  float a0 = 0.f, q0 = 0.f, a1 = 0.f, q1 = 0.f;
  for (long r = r0; r < r1; ++r) {
    const half_t* xp = x + r*C;
    { float v = (float)xp[threadIdx.x]; a0 += v; q0 += v*v; }
    if (C > 256) { float v = (float)xp[256 + threadIdx.x]; a1 += v; q1 += v*v; }
  }
  atomicAdd(&sums[threadIdx.x], a0);
  atomicAdd(&sums[C + threadIdx.x], q0);
  if (C > 256) {
    atomicAdd(&sums[256 + threadIdx.x], a1);
    atomicAdd(&sums[C + 256 + threadIdx.x], q1);
  }
}

__global__ __launch_bounds__(256) void bn_apply_relu8_kernel(
    half_t* __restrict__ x, const float* __restrict__ sums,
    const float* __restrict__ scale, const float* __restrict__ bias,
    long total8, int C, float invN)
{
  long idx = (long)blockIdx.x*256 + threadIdx.x;
  if (idx >= total8) return;
  int c = (int)((idx*8) % C);
  half8 v = *reinterpret_cast<half8*>(x + idx*8);
  half8 o;
  #pragma unroll
  for (int e = 0; e < 8; ++e) {
    float mean = sums[c+e] * invN;
    float var  = sums[C + c+e] * invN - mean*mean;
    float rstd = rsqrtf(var + 1e-5f);
    float y = ((float)v[e] - mean) * rstd * scale[c+e] + bias[c+e];
    o[e] = (half_t)fmaxf(y, 0.0f);
  }
  *reinterpret_cast<half8*>(x + idx*8) = o;
}

// ------------------------------------------------------------------
// Attention (T=15, D=512), q/k/v fp32, out fp16.
// ------------------------------------------------------------------
__global__ __launch_bounds__(256) void attention_kernel(
    const float* __restrict__ q, const float* __restrict__ k,
    const float* __restrict__ v, half_t* __restrict__ out, int T, int D)
{
  int b = blockIdx.x;
  int tid = threadIdx.x;
  __shared__ float P[15][16];
  if (tid < T*T) {
    int t = tid / T, s = tid % T;
    const float* qp = q + ((long)b*T + t)*D;
    const float* kp = k + ((long)b*T + s)*D;
    float acc = 0.f;
    for (int d = 0; d < D; d += 4) {
      float4 qv = *reinterpret_cast<const float4*>(qp + d);
      float4 kv = *reinterpret_cast<const float4*>(kp + d);
      acc += qv.x*kv.x + qv.y*kv.y + qv.z*kv.z + qv.w*kv.w;
    }
    P[t][s] = acc * (1.0f/32.0f);
  }
  __syncthreads();
  if (tid < T) {
    float mx = -INFINITY;
    for (int s = 0; s < T; ++s) mx = fmaxf(mx, P[tid][s]);
    float sum = 0.f;
    for (int s = 0; s < T; ++s) { float e = expf(P[tid][s] - mx); P[tid][s] = e; sum += e; }
    float inv = 1.0f / sum;
    for (int s = 0; s < T; ++s) P[tid][s] *= inv;
  }
  __syncthreads();
  for (int idx = tid; idx < T*D; idx += 256) {
    int s = idx / D, kk2 = idx % D;
    float acc = 0.f;
    #pragma unroll
    for (int t = 0; t < 15; ++t) acc += v[((long)b*15 + t)*D + kk2] * P[t][s];
    out[((long)b*T + s)*D + kk2] = (half_t)acc;
  }
}

// ------------------------------------------------------------------
// Persistent bidirectional LSTM stack. Cross-block exchange uses ONLY
// relaxed agent-scope atomics (sc0/sc1 -> coherence point, no L1/L2
// maintenance): h stores, flag store, flag polls, and h staging loads
// (batched 8 deep for MLP). Ordering: __syncthreads() drains vmcnt
// before the flag store; readers poll flags then load h.
// ------------------------------------------------------------------
#define MAXK 512
__global__ __launch_bounds__(256, 1) void lstm_persistent_kernel(
    const float* __restrict__ preF, const float* __restrict__ preR,
    const float* __restrict__ whF, const float* __restrict__ whR,
    half_t* __restrict__ hbuf, half_t* __restrict__ y,
    int* __restrict__ flags, int H, int nblk,
    int ystride, int yoffF, int yoffR)
{
  __shared__ half_t BsT[64][MAXK + 8];
  __shared__ half_t hs[32][MAXK + 8];
  __shared__ float gates[32][65];
  int tid = threadIdx.x;
  int jb0 = blockIdx.x * 16;
  int H4 = 4 * H;
  int lane = tid & 63, wave = tid >> 6;
  int l15 = lane & 15, quad = lane >> 4;
  int hcs = (H == 512) ? 8 : 7;          // log2(H/2): u32 chunks per row
  int nIter = (32 << hcs) >> 8;          // total u32 / 256 threads

  float cst[2] = {0.f, 0.f};

  for (int idx = tid; idx < H*64; idx += 256) {
    int k = idx >> 6, c = idx & 63;
    int g = c >> 4, jj = c & 15;
    BsT[c][k] = (half_t)whF[(long)k*H4 + g*H + jb0 + jj];
  }
  const float* pre = preF;
  int yoff = yoffF;
  __syncthreads();

  for (int s = 0; s < 30; ++s) {
    if (s == 15) {               // fwd -> rev (carry chains through)
      __syncthreads();
      for (int idx = tid; idx < H*64; idx += 256) {
        int k = idx >> 6, c = idx & 63;
        int g = c >> 4, jj = c & 15;
        BsT[c][k] = (half_t)whR[(long)k*H4 + g*H + jb0 + jj];
      }
      pre = preR; yoff = yoffR;
      __syncthreads();
    }
    int t = (s < 15) ? s : 29 - s;

    // stage h(prev): relaxed agent-scope u32 loads, 8 in flight
    const unsigned* hsrc = (const unsigned*)(hbuf + (long)(s & 1) * 32 * H);
    for (int base = 0; base < nIter; base += 8) {
      unsigned tmp[8];
      #pragma unroll
      for (int u = 0; u < 8; ++u) {
        int idx = tid + (base + u)*256;
        tmp[u] = __hip_atomic_load(hsrc + idx, __ATOMIC_RELAXED, __HIP_MEMORY_SCOPE_AGENT);
      }
      #pragma unroll
      for (int u = 0; u < 8; ++u) {
        int idx = tid + (base + u)*256;
        int row = idx >> hcs, col = (idx & ((1 << hcs) - 1)) * 2;
        *reinterpret_cast<unsigned*>(&hs[row][col]) = tmp[u];
      }
    }
    __syncthreads();

    // recurrent GEMM: wave = gate, m-tiles = batches 0..15 / 16..31
    f32x4 acc0 = {0.f,0.f,0.f,0.f}, acc1 = {0.f,0.f,0.f,0.f};
    for (int k0 = 0; k0 < H; k0 += 32) {
      half8 bf = *reinterpret_cast<half8*>(&BsT[wave*16 + l15][k0 + quad*8]);
      half8 a0 = *reinterpret_cast<half8*>(&hs[l15][k0 + quad*8]);
      half8 a1 = *reinterpret_cast<half8*>(&hs[16 + l15][k0 + quad*8]);
      acc0 = __builtin_amdgcn_mfma_f32_16x16x32_f16(a0, bf, acc0, 0, 0, 0);
      acc1 = __builtin_amdgcn_mfma_f32_16x16x32_f16(a1, bf, acc1, 0, 0, 0);
    }
    #pragma unroll
    for (int r = 0; r < 4; ++r) {
      gates[quad*4 + r][wave*16 + l15]      = acc0[r];
      gates[16 + quad*4 + r][wave*16 + l15] = acc1[r];
    }
    __syncthreads();

    // c/h update: thread owns units (b, jj0) and (b, jj0+1)
    {
      int b = tid >> 3;
      int jj0 = (tid & 7) * 2;
      const float* pp = pre + (long)(b*15 + t)*H4 + jb0 + jj0;
      half_t hn2[2];
      #pragma unroll
      for (int p = 0; p < 2; ++p) {
        int jj = jj0 + p;
        float gi = pp[p]       + gates[b][jj];
        float gf = pp[H + p]   + gates[b][16 + jj];
        float gg = pp[2*H + p] + gates[b][32 + jj];
        float go = pp[3*H + p] + gates[b][48 + jj];
        gi = fsig_(gi); gf = fsig_(gf); gg = ftanh_(gg); go = fsig_(go);
        float cn = gf * cst[p] + gi * gg;
        cst[p] = cn;
        hn2[p] = (half_t)(go * ftanh_(cn));
      }
      unsigned hpack = *reinterpret_cast<unsigned*>(hn2);
      half_t* hdst = hbuf + (long)((s + 1) & 1) * 32 * H;
      __hip_atomic_store((unsigned*)(hdst + (long)b*H + jb0 + jj0), hpack,
                         __ATOMIC_RELAXED, __HIP_MEMORY_SCOPE_AGENT);
      *reinterpret_cast<unsigned*>(&y[(long)(b*15 + t)*ystride + yoff + jb0 + jj0]) = hpack;
    }

    if (s < 29) {
      __syncthreads();           // vmcnt(0): h stores acked at coherence point
      if (tid == 0)
        __hip_atomic_store(&flags[blockIdx.x*16], s + 1,
                           __ATOMIC_RELAXED, __HIP_MEMORY_SCOPE_AGENT);
      if (tid < 64) {
        int target = s + 1;
        for (;;) {
          int vv = (tid < nblk)
            ? __hip_atomic_load(&flags[tid*16], __ATOMIC_RELAXED, __HIP_MEMORY_SCOPE_AGENT)
            : target;
          if (__all(vv >= target)) break;
          __builtin_amdgcn_s_sleep(2);
        }
      }
      __syncthreads();
    }
  }
}

// ------------------------------------------------------------------
// Host orchestration
// ------------------------------------------------------------------
extern "C" void kernel_launch(void* const* d_in, const int* in_sizes, int n_in,
                              void* d_out, int out_size, void* d_ws, size_t ws_size,
                              hipStream_t stream)
{
  const float* x       = (const float*)d_in[0];
  const float* c1w     = (const float*)d_in[1];  const float* c1b = (const float*)d_in[2];
  const float* c2w     = (const float*)d_in[3];  const float* c2b = (const float*)d_in[4];
  const float* c3w     = (const float*)d_in[5];  const float* c3b = (const float*)d_in[6];
  const float* bn1s    = (const float*)d_in[7];  const float* bn1b = (const float*)d_in[8];
  const float* c4w     = (const float*)d_in[9];  const float* c4b = (const float*)d_in[10];
  const float* bn2s    = (const float*)d_in[11]; const float* bn2b = (const float*)d_in[12];
  const float* c5w     = (const float*)d_in[13]; const float* c5b = (const float*)d_in[14];
  const float* bn3s    = (const float*)d_in[15]; const float* bn3b = (const float*)d_in[16];
  const float* c6w     = (const float*)d_in[17]; const float* c6b = (const float*)d_in[18];
  const float* bn4s    = (const float*)d_in[19]; const float* bn4b = (const float*)d_in[20];
  const float* c7w     = (const float*)d_in[21]; const float* c7b = (const float*)d_in[22];
  const float* bn5s    = (const float*)d_in[23]; const float* bn5b = (const float*)d_in[24];
  const float* wq      = (const float*)d_in[25]; const float* bq = (const float*)d_in[26];
  const float* wk      = (const float*)d_in[27]; const float* bk = (const float*)d_in[28];
  const float* wv      = (const float*)d_in[29]; const float* bv = (const float*)d_in[30];
  const float* l1f_wx  = (const float*)d_in[31]; const float* l1f_wh = (const float*)d_in[32]; const float* l1f_b = (const float*)d_in[33];
  const float* l1r_wx  = (const float*)d_in[34]; const float* l1r_wh = (const float*)d_in[35]; const float* l1r_b = (const float*)d_in[36];
  const float* l2f_wx  = (const float*)d_in[37]; const float* l2f_wh = (const float*)d_in[38]; const float* l2f_b = (const float*)d_in[39];
  const float* l2r_wx  = (const float*)d_in[40]; const float* l2r_wh = (const float*)d_in[41]; const float* l2r_b = (const float*)d_in[42];
  const float* wo      = (const float*)d_in[43]; const float* bo = (const float*)d_in[44];
  float* outp = (float*)d_out;

  char* base = (char*)d_ws;
  half_t* actA = (half_t*)base;
  half_t* actB = (half_t*)(base + 67108864);
  half_t* wtA  = (half_t*)(base + 100663296);
  float*  f32a = (float*)(base + 143687680);
  half_t* h16a = (half_t*)(base + 158736384);

  half_t* wt2  = wtA;
  half_t* wt3  = wtA + 73728;
  half_t* wt4  = wtA + 368640;
  half_t* wt5  = wtA + 958464;
  half_t* wt6  = wtA + 2138112;
  half_t* wt7  = wtA + 4497408;
  half_t* wtq  = wtA + 5545984;
  half_t* wtk  = wtA + 9478144;
  half_t* wtv  = wtA + 13410304;
  half_t* wt1f = wtA + 17342464;
  half_t* wt1r = wtA + 17866752;
  half_t* wt2f = wtA + 18391040;
  half_t* wt2r = wtA + 19439616;
  half_t* wto  = wtA + 20488192;

  float* q     = f32a;
  float* kk_   = f32a + 245760;
  float* v     = f32a + 491520;
  float* pre1f = f32a + 737280;
  float* pre1r = f32a + 1228800;
  float* pre2f = f32a + 1720320;
  float* pre2r = f32a + 2703360;
  float* bnsums= f32a + 3760128;

  half_t* ao  = h16a;
  half_t* x1  = h16a + 245760;
  half_t* x2  = h16a + 491520;
  half_t* hb1 = h16a + 983040;    // 2 x 32 x 256 fp16
  half_t* hb2 = hb1 + 16384;      // 2 x 32 x 512 fp16
  int*    flags1 = (int*)(hb2 + 32768);
  int*    flags2 = flags1 + 512;
  half_t* zbuf   = (half_t*)(flags2 + 512);

  auto tpose = [&](const float* w, half_t* wT, int K, int N){
    dim3 grid(DIV_UP(N,32), DIV_UP(K,32));
    transpose_cvt_kernel<<<grid,256,0,stream>>>(w, wT, K, N);
  };
  auto convm = [&](const half_t* in, const half_t* wt, const float* b, void* out,
                   int N,int H,int W,int Ci,int Ho,int Wo,int Co,
                   int KH,int KW,int pH,int pW,int flags){
    int M = N*Ho*Wo, K = KH*KW*Ci;
    dim3 grid(DIV_UP(Co,128), DIV_UP(M,128), 1);
    GOut g{wt, b, out};
    mfma_conv_kernel<<<grid,256,0,stream>>>(in,g,g,g,zbuf,N,H,W,Ci,Ho,Wo,Co,
                                            KH,KW,pH,pW,M,K,flags);
  };
  auto gemm3 = [&](const half_t* A, GOut g0, GOut g1, GOut g2, int nz,
                   int M, int Nn, int K, int flags){
    dim3 grid(DIV_UP(Nn,128), DIV_UP(M,128), nz);
    mfma_conv_kernel<<<grid,256,0,stream>>>(A,g0,g1,g2,zbuf,M,1,1,K,1,1,Nn,
                                            1,1,0,0,M,K,flags);
  };
  auto pool = [&](const half_t* in, half_t* out, int N,int H,int W,int C,
                  int Ho,int Wo,int sH,int sW){
    long total8 = (long)N*Ho*Wo*(C/8);
    maxpool8_kernel<<<(int)DIV_UP(total8,256),256,0,stream>>>(in,out,N,H,W,C,Ho,Wo,sH,sW);
  };
  auto bn = [&](half_t* buf, long nPix, int C, const float* s, const float* b){
    hipMemsetAsync(bnsums, 0, sizeof(float)*2*C, stream);
    bn_sums_kernel<<<1024,256,0,stream>>>(buf, bnsums, nPix, C);
    long total8 = nPix * C / 8;
    bn_apply_relu8_kernel<<<(int)DIV_UP(total8,256),256,0,stream>>>(buf, bnsums, s, b, total8, C, 1.0f/(float)nPix);
  };

  hipMemsetAsync(zbuf, 0, sizeof(half_t)*16, stream);
  hipMemsetAsync(flags1, 0, sizeof(int)*1024, stream);
  hipMemsetAsync(hb1, 0, sizeof(half_t)*(16384 + 32768), stream);

  // ---- weight preconversion ----
  tpose(c2w, wt2, 576, 128);
  tpose(c3w, wt3, 1152, 256);
  tpose(c4w, wt4, 2304, 256);
  tpose(c5w, wt5, 2304, 512);
  tpose(c6w, wt6, 4608, 512);
  tpose(c7w, wt7, 2048, 512);
  tpose(wq,  wtq, 7680, 512);
  tpose(wk,  wtk, 7680, 512);
  tpose(wv,  wtv, 7680, 512);
  tpose(l1f_wx, wt1f, 512, 1024);
  tpose(l1r_wx, wt1r, 512, 1024);
  tpose(l2f_wx, wt2f, 512, 2048);
  tpose(l2r_wx, wt2r, 512, 2048);
  tpose(wo, wto, 1024, 1000);

  // ---- conv stack (activations fp16) ----
  conv1_kernel<<<2048,256,0,stream>>>(x, c1w, c1b, actA);
  pool(actA, actB, 32,64,256,64,  32,128, 2,2);
  convm(actB, wt2, c2b, actA, 32,32,128,64,  32,128,128, 3,3,1,1, FLAG_RELU);
  pool(actA, actB, 32,32,128,128, 16,64, 2,2);
  convm(actB, wt3, c3b, actA, 32,16,64,128,  16,64,256,  3,3,1,1, 0);
  bn(actA, 32768, 256, bn1s, bn1b);
  convm(actA, wt4, c4b, actB, 32,16,64,256,  16,64,256,  3,3,1,1, 0);
  bn(actB, 32768, 256, bn2s, bn2b);
  pool(actB, actA, 32,16,64,256,  16,32, 1,2);
  convm(actA, wt5, c5b, actB, 32,16,32,256,  16,32,512,  3,3,1,1, 0);
  bn(actB, 16384, 512, bn3s, bn3b);
  convm(actB, wt6, c6b, actA, 32,16,32,512,  16,32,512,  3,3,1,1, 0);
  bn(actA, 16384, 512, bn4s, bn4b);
  pool(actA, actB, 32,16,32,512,  16,16, 1,2);
  convm(actB, wt7, c7b, actA, 32,16,16,512,  15,15,512,  2,2,0,0, 0);
  bn(actA, 7200, 512, bn5s, bn5b);

  // ---- attention: fused qkv GEMM, grid.z = 3 ----
  gemm3(actA, GOut{wtq, bq, q}, GOut{wtk, bk, kk_}, GOut{wtv, bv, v}, 3,
        480, 512, 7680, FLAG_OUTF32);
  attention_kernel<<<32,256,0,stream>>>(q, kk_, v, ao, 15, 512);

  // ---- LSTM stack 1 (H=256): fused pre-GEMMs + persistent kernel ----
  gemm3(ao, GOut{wt1f, l1f_b, pre1f}, GOut{wt1r, l1r_b, pre1r},
        GOut{wt1r, l1r_b, pre1r}, 2, 480, 1024, 512, FLAG_OUTF32);
  lstm_persistent_kernel<<<16,256,0,stream>>>(
      pre1f, pre1r, l1f_wh, l1r_wh, hb1, x1, flags1, 256, 16, 512, 0, 256);

  // ---- LSTM stack 2 (H=512) ----
  gemm3(x1, GOut{wt2f, l2f_b, pre2f}, GOut{wt2r, l2r_b, pre2r},
        GOut{wt2r, l2r_b, pre2r}, 2, 480, 2048, 512, FLAG_OUTF32);
  lstm_persistent_kernel<<<32,256,0,stream>>>(
      pre2f, pre2r, l2f_wh, l2r_wh, hb2, x2, flags2, 512, 32, 1024, 512, 0);

  // ---- classifier ----
  gemm3(x2, GOut{wto, bo, outp}, GOut{wto, bo, outp}, GOut{wto, bo, outp}, 1,
        480, 1000, 1024, FLAG_OUTF32);
}

// Round 7
// 1479.782 us; speedup vs baseline: 27.4857x; 1.0491x over previous
//
#include <hip/hip_runtime.h>
#include <math.h>

#define DIV_UP(a,b) (((a)+(b)-1)/(b))

typedef _Float16 half_t;
typedef _Float16 half8 __attribute__((ext_vector_type(8)));
typedef float f32x4 __attribute__((ext_vector_type(4)));

#define FLAG_RELU   1
#define FLAG_OUTF32 2
#define FLAG_SPLITK 4
#define FLAG_ATOMIC 8

#define GLDS16(src, dst) \
  __builtin_amdgcn_global_load_lds((const __attribute__((address_space(1))) void*)(src), \
                                   (__attribute__((address_space(3))) void*)(dst), 16, 0, 0)

__device__ __forceinline__ float fsig_(float x){ return 1.0f/(1.0f+__expf(-x)); }
__device__ __forceinline__ float ftanh_(float x){
  float ax = fabsf(x);
  float e = __expf(-2.0f*ax);
  float t = (1.0f - e)/(1.0f + e);
  return copysignf(t, x);
}

// ------------------------------------------------------------------
// ALL weight transposes (fp32 [K][N] -> fp16 [N][K]) in ONE launch.
// Tile table via prefix sums; 32x32 tiles.
// ------------------------------------------------------------------
struct TpAll {
  const float* src[14];
  half_t* dst[14];
  int K[14];
  int N[14];
  int prefix[15];
};

__global__ __launch_bounds__(256) void transpose_cvt_all_kernel(TpAll a)
{
  __shared__ float tile[32][33];
  int bid = blockIdx.x;
  int z = 0;
  while (bid >= a.prefix[z+1]) ++z;
  int local = bid - a.prefix[z];
  const float* w = a.src[z];
  half_t* wT = a.dst[z];
  int K = a.K[z], N = a.N[z];
  int tilesX = (N + 31) >> 5;
  int nt = (local % tilesX) * 32;
  int kt = (local / tilesX) * 32;
  int tx = threadIdx.x & 31, ty = threadIdx.x >> 5;
  #pragma unroll
  for (int r = 0; r < 4; ++r) {
    int k = kt + ty + r*8, n = nt + tx;
    tile[ty + r*8][tx] = (k < K && n < N) ? w[(long)k*N + n] : 0.f;
  }
  __syncthreads();
  #pragma unroll
  for (int r = 0; r < 4; ++r) {
    int n = nt + ty + r*8, k = kt + tx;
    if (n < N && k < K) wT[(long)n*K + k] = (half_t)tile[tx][ty + r*8];
  }
}

// ------------------------------------------------------------------
// conv1 special case: x (32,64,256,3) fp32, w (3,3,3,64), out fp16 + ReLU.
// ------------------------------------------------------------------
__global__ __launch_bounds__(256) void conv1_kernel(
    const float* __restrict__ x, const float* __restrict__ w,
    const float* __restrict__ bias, half_t* __restrict__ out)
{
  __shared__ float xs[3][258*3];
  int nb = blockIdx.x;            // n*64 + ho
  int n = nb >> 6, ho = nb & 63;
  int tid = threadIdx.x;
  int co = tid & 63;
  float wreg[27];
  #pragma unroll
  for (int k = 0; k < 27; ++k) wreg[k] = w[k*64 + co];
  float bco = bias[co];
  for (int i = tid; i < 3*258*3; i += 256) {
    int row = i / (258*3); int rem = i % (258*3);
    int col = rem / 3;     int ci  = rem % 3;
    int ih = ho - 1 + row; int iw = col - 1;
    float v = 0.f;
    if (ih >= 0 && ih < 64 && iw >= 0 && iw < 256)
      v = x[(((long)n*64 + ih)*256 + iw)*3 + ci];
    xs[row][col*3 + ci] = v;
  }
  __syncthreads();
  int wave = tid >> 6;
  for (int p = 0; p < 64; ++p) {
    int wo = wave*64 + p;
    float acc = bco;
    #pragma unroll
    for (int kh = 0; kh < 3; ++kh)
      #pragma unroll
      for (int kw = 0; kw < 3; ++kw)
        #pragma unroll
        for (int ci = 0; ci < 3; ++ci)
          acc = fmaf(xs[kh][(wo+kw)*3 + ci], wreg[(kh*3+kw)*3 + ci], acc);
    acc = fmaxf(acc, 0.f);
    out[(((long)n*64 + ho)*256 + wo)*64 + co] = (half_t)acc;
  }
}

// ------------------------------------------------------------------
// MFMA implicit-GEMM conv/GEMM. 128x128 tile, BK=32, 4 waves,
// mfma_f32_16x16x32_f16, global_load_lds width-16 staging.
// blockIdx.z: output selector (up to 3 sharing A) OR K-split index
// (FLAG_SPLITK, f32 atomicAdd epilogue into bias-prefilled out).
// ------------------------------------------------------------------
struct GOut { const half_t* wT; const float* bias; void* out; };

__global__ __launch_bounds__(256) void mfma_conv_kernel(
    const half_t* __restrict__ x, GOut g0, GOut g1, GOut g2,
    const half_t* __restrict__ zbuf,
    int N,int H,int W,int Ci,int Ho,int Wo,int Co,
    int KH,int KW,int padH,int padW,
    int M,int K,int flags,int splitS)
{
  GOut g;
  int ciBeg = 0, ciEnd = Ci;
  if (flags & FLAG_SPLITK) {
    g = g0;
    int span = Ci / splitS;
    ciBeg = blockIdx.z * span;
    ciEnd = ciBeg + span;
  } else {
    g = (blockIdx.z == 0) ? g0 : (blockIdx.z == 1 ? g1 : g2);
  }
  const half_t* __restrict__ wT = g.wT;
  __shared__ half_t As[128*32];
  __shared__ half_t Bs[128*32];
  int tid = threadIdx.x;
  int m0 = blockIdx.y*128, n0 = blockIdx.x*128;
  int wave = tid >> 6, lane = tid & 63;
  int l15 = lane & 15, quad = lane >> 4;
  int wm = (wave & 1) * 64, wn = (wave >> 1) * 64;
  int colOff = (tid & 3) * 8;      // halves within a 32-chunk
  int rIdx = tid >> 2;             // 0..63: row within half-tile

  int ho_[2], wo_[2], ni_[2]; bool av_[2];
  #pragma unroll
  for (int c = 0; c < 2; ++c) {
    int m = m0 + c*64 + rIdx;
    av_[c] = m < M;
    int mm = av_[c] ? m : 0;
    wo_[c] = mm % Wo; int t2 = mm / Wo;
    ho_[c] = t2 % Ho; ni_[c] = t2 / Ho;
  }
  const half_t* bBase[2];
  #pragma unroll
  for (int c = 0; c < 2; ++c) {
    int n = n0 + c*64 + rIdx;
    bBase[c] = (n < Co) ? (wT + (long)n*K + colOff) : nullptr;
  }
  half_t* aDst[2] = { As + wave*512, As + 2048 + wave*512 };
  half_t* bDst[2] = { Bs + wave*512, Bs + 2048 + wave*512 };

  f32x4 acc[4][4];
  #pragma unroll
  for (int i = 0; i < 4; ++i)
    #pragma unroll
    for (int j = 0; j < 4; ++j)
      acc[i][j] = (f32x4){0.f, 0.f, 0.f, 0.f};

  int kg = ciBeg;
  for (int kh = 0; kh < KH; ++kh) {
    for (int kw = 0; kw < KW; ++kw) {
      const half_t* aTap[2];
      #pragma unroll
      for (int c = 0; c < 2; ++c) {
        int ih = ho_[c] - padH + kh, iw = wo_[c] - padW + kw;
        bool v = av_[c] && ih >= 0 && ih < H && iw >= 0 && iw < W;
        aTap[c] = v ? (x + (((long)ni_[c]*H + ih)*W + iw)*(long)Ci + colOff)
                    : nullptr;
      }
      for (int ci = ciBeg; ci < ciEnd; ci += 32, kg += 32) {
        #pragma unroll
        for (int c = 0; c < 2; ++c) {
          const half_t* sa = aTap[c] ? aTap[c] + ci : zbuf;
          GLDS16(sa, aDst[c]);
          const half_t* sb = bBase[c] ? bBase[c] + kg : zbuf;
          GLDS16(sb, bDst[c]);
        }
        __syncthreads();
        half8 af[4], bf[4];
        #pragma unroll
        for (int i = 0; i < 4; ++i)
          af[i] = *reinterpret_cast<half8*>(&As[(wm + i*16 + l15)*32 + quad*8]);
        #pragma unroll
        for (int j = 0; j < 4; ++j)
          bf[j] = *reinterpret_cast<half8*>(&Bs[(wn + j*16 + l15)*32 + quad*8]);
        #pragma unroll
        for (int i = 0; i < 4; ++i)
          #pragma unroll
          for (int j = 0; j < 4; ++j)
            acc[i][j] = __builtin_amdgcn_mfma_f32_16x16x32_f16(af[i], bf[j], acc[i][j], 0, 0, 0);
        __syncthreads();
      }
    }
  }

  #pragma unroll
  for (int i = 0; i < 4; ++i) {
    #pragma unroll
    for (int r = 0; r < 4; ++r) {
      int m = m0 + wm + i*16 + quad*4 + r;
      if (m >= M) continue;
      #pragma unroll
      for (int j = 0; j < 4; ++j) {
        int n = n0 + wn + j*16 + l15;
        if (n >= Co) continue;
        if (flags & FLAG_ATOMIC) {
          atomicAdd(&((float*)g.out)[(long)m*Co + n], acc[i][j][r]);
        } else {
          float v = acc[i][j][r] + g.bias[n];
          if (flags & FLAG_RELU) v = fmaxf(v, 0.f);
          if (flags & FLAG_OUTF32) ((float*)g.out)[(long)m*Co + n] = v;
          else ((half_t*)g.out)[(long)m*Co + n] = (half_t)v;
        }
      }
    }
  }
}

// ------------------------------------------------------------------
// Max pool fp16, NHWC, 8 channels per thread.
// ------------------------------------------------------------------
__global__ __launch_bounds__(256) void maxpool8_kernel(
    const half_t* __restrict__ x, half_t* __restrict__ out,
    int N,int H,int W,int C,int Ho,int Wo,int sH,int sW)
{
  int C8 = C >> 3;
  long idx = (long)blockIdx.x*256 + threadIdx.x;
  long total8 = (long)N*Ho*Wo*C8;
  if (idx >= total8) return;
  int cb = (int)(idx % C8);
  long pix = idx / C8;
  int wo = (int)(pix % Wo); long t2 = pix / Wo;
  int ho = (int)(t2 % Ho); int n = (int)(t2 / Ho);
  int c = cb * 8;
  float m[8];
  #pragma unroll
  for (int e = 0; e < 8; ++e) m[e] = -INFINITY;
  for (int i = 0; i < 2; ++i) {
    int ih = ho*sH + i;
    if (ih >= H) continue;
    for (int j = 0; j < 2; ++j) {
      int iw = wo*sW + j;
      if (iw >= W) continue;
      half8 v = *reinterpret_cast<const half8*>(x + (((long)n*H + ih)*W + iw)*C + c);
      #pragma unroll
      for (int e = 0; e < 8; ++e) m[e] = fmaxf(m[e], (float)v[e]);
    }
  }
  half8 o;
  #pragma unroll
  for (int e = 0; e < 8; ++e) o[e] = (half_t)m[e];
  *reinterpret_cast<half8*>(out + idx*8) = o;
}

// ------------------------------------------------------------------
// BN sums: half8 loads, threads-per-row layout, LDS block reduction,
// then one atomicAdd pair per channel per block. sums pre-zeroed.
// ------------------------------------------------------------------
__global__ __launch_bounds__(256) void bn_sums8_kernel(
    const half_t* __restrict__ x, float* __restrict__ sums, long nPix, int C)
{
  __shared__ float red[256][16];
  int cpr = C >> 3;                  // threads per row (32 or 64)
  int rpb = 256 / cpr;               // rows in flight (8 or 4)
  int tid = threadIdx.x;
  int c8 = (tid % cpr) * 8;
  int rsub = tid / cpr;
  long rowsPer = (nPix + gridDim.x - 1) / gridDim.x;
  long r0 = (long)blockIdx.x * rowsPer + rsub;
  long rEnd = (long)(blockIdx.x + 1) * rowsPer;
  if (rEnd > nPix) rEnd = nPix;
  float s[8] = {0,0,0,0,0,0,0,0}, q[8] = {0,0,0,0,0,0,0,0};
  for (long r = r0; r < rEnd; r += rpb) {
    half8 v = *reinterpret_cast<const half8*>(x + r*C + c8);
    #pragma unroll
    for (int e = 0; e < 8; ++e) { float f = (float)v[e]; s[e] += f; q[e] += f*f; }
  }
  #pragma unroll
  for (int e = 0; e < 8; ++e) { red[tid][e] = s[e]; red[tid][8+e] = q[e]; }
  __syncthreads();
  if (rsub == 0) {
    for (int r = 1; r < rpb; ++r)
      #pragma unroll
      for (int e = 0; e < 8; ++e) { s[e] += red[tid + r*cpr][e]; q[e] += red[tid + r*cpr][8+e]; }
    #pragma unroll
    for (int e = 0; e < 8; ++e) {
      atomicAdd(&sums[c8 + e], s[e]);
      atomicAdd(&sums[C + c8 + e], q[e]);
    }
  }
}

__global__ __launch_bounds__(256) void bn_apply_relu8_kernel(
    half_t* __restrict__ x, const float* __restrict__ sums,
    const float* __restrict__ scale, const float* __restrict__ bias,
    long total8, int C, float invN)
{
  long idx = (long)blockIdx.x*256 + threadIdx.x;
  if (idx >= total8) return;
  int c = (int)((idx*8) % C);
  half8 v = *reinterpret_cast<half8*>(x + idx*8);
  half8 o;
  #pragma unroll
  for (int e = 0; e < 8; ++e) {
    float mean = sums[c+e] * invN;
    float var  = sums[C + c+e] * invN - mean*mean;
    float rstd = rsqrtf(var + 1e-5f);
    float y = ((float)v[e] - mean) * rstd * scale[c+e] + bias[c+e];
    o[e] = (half_t)fmaxf(y, 0.0f);
  }
  *reinterpret_cast<half8*>(x + idx*8) = o;
}

// ------------------------------------------------------------------
// Bias prefill for the split-K qkv GEMM output (480 x 1536 f32).
// ------------------------------------------------------------------
__global__ __launch_bounds__(256) void bias_fill_kernel(
    float* __restrict__ out, const float* __restrict__ b0,
    const float* __restrict__ b1, const float* __restrict__ b2, int total)
{
  int idx = blockIdx.x*256 + threadIdx.x;
  if (idx >= total) return;
  int n = idx % 1536;
  float v = (n < 512) ? b0[n] : (n < 1024 ? b1[n-512] : b2[n-1024]);
  out[idx] = v;
}

// ------------------------------------------------------------------
// Attention (T=15, D=512), qkv interleaved f32 rows of ld=1536, out fp16.
// ------------------------------------------------------------------
__global__ __launch_bounds__(256) void attention_kernel(
    const float* __restrict__ qkv, half_t* __restrict__ out,
    int T, int D, int ld)
{
  int b = blockIdx.x;
  int tid = threadIdx.x;
  __shared__ float P[15][16];
  if (tid < T*T) {
    int t = tid / T, s = tid % T;
    const float* qp = qkv + ((long)b*T + t)*ld;
    const float* kp = qkv + ((long)b*T + s)*ld + 512;
    float acc = 0.f;
    for (int d = 0; d < D; d += 4) {
      float4 qv = *reinterpret_cast<const float4*>(qp + d);
      float4 kv = *reinterpret_cast<const float4*>(kp + d);
      acc += qv.x*kv.x + qv.y*kv.y + qv.z*kv.z + qv.w*kv.w;
    }
    P[t][s] = acc * (1.0f/32.0f);
  }
  __syncthreads();
  if (tid < T) {
    float mx = -INFINITY;
    for (int s = 0; s < T; ++s) mx = fmaxf(mx, P[tid][s]);
    float sum = 0.f;
    for (int s = 0; s < T; ++s) { float e = expf(P[tid][s] - mx); P[tid][s] = e; sum += e; }
    float inv = 1.0f / sum;
    for (int s = 0; s < T; ++s) P[tid][s] *= inv;
  }
  __syncthreads();
  for (int idx = tid; idx < T*D; idx += 256) {
    int s = idx / D, kk2 = idx % D;
    float acc = 0.f;
    #pragma unroll
    for (int t = 0; t < 15; ++t)
      acc += qkv[((long)b*T + t)*ld + 1024 + kk2] * P[t][s];
    out[((long)b*T + s)*D + kk2] = (half_t)acc;
  }
}

// ------------------------------------------------------------------
// Persistent bidirectional LSTM. Cross-block exchange: relaxed agent
// atomics only. This round: u64 h-staging fully batched (one latency),
// pre prefetched at step top, y stored after the flag (ack overlaps poll).
// ------------------------------------------------------------------
#define MAXK 512
#define HSROW (MAXK + 8)

template<int N64, int HLOG>
__device__ __forceinline__ void stage_h(
    const unsigned long long* __restrict__ src, half_t (*hs)[HSROW], int tid)
{
  unsigned long long tmp[N64];
  #pragma unroll
  for (int u = 0; u < N64; ++u)
    tmp[u] = __hip_atomic_load(src + tid + u*256, __ATOMIC_RELAXED, __HIP_MEMORY_SCOPE_AGENT);
  #pragma unroll
  for (int u = 0; u < N64; ++u) {
    int idx = tid + u*256;
    int row = idx >> (HLOG - 2);
    int col = (idx & ((1 << (HLOG - 2)) - 1)) * 4;
    *reinterpret_cast<unsigned long long*>(&hs[row][col]) = tmp[u];
  }
}

__global__ __launch_bounds__(256, 1) void lstm_persistent_kernel(
    const float* __restrict__ preF, const float* __restrict__ preR,
    const float* __restrict__ whF, const float* __restrict__ whR,
    half_t* __restrict__ hbuf, half_t* __restrict__ y,
    int* __restrict__ flags, int H, int nblk,
    int ystride, int yoffF, int yoffR)
{
  __shared__ half_t BsT[64][HSROW];
  __shared__ half_t hs[32][HSROW];
  __shared__ float gates[32][65];
  int tid = threadIdx.x;
  int jb0 = blockIdx.x * 16;
  int H4 = 4 * H;
  int lane = tid & 63, wave = tid >> 6;
  int l15 = lane & 15, quad = lane >> 4;
  int bb = tid >> 3;            // batch this thread updates
  int jj0 = (tid & 7) * 2;      // unit pair within block's 16

  float cst[2] = {0.f, 0.f};

  for (int idx = tid; idx < H*64; idx += 256) {
    int k = idx >> 6, c = idx & 63;
    int g = c >> 4, jj = c & 15;
    BsT[c][k] = (half_t)whF[(long)k*H4 + g*H + jb0 + jj];
  }
  const float* pre = preF;
  int yoff = yoffF;
  __syncthreads();

  for (int s = 0; s < 30; ++s) {
    if (s == 15) {               // fwd -> rev (carry chains through)
      __syncthreads();
      for (int idx = tid; idx < H*64; idx += 256) {
        int k = idx >> 6, c = idx & 63;
        int g = c >> 4, jj = c & 15;
        BsT[c][k] = (half_t)whR[(long)k*H4 + g*H + jb0 + jj];
      }
      pre = preR; yoff = yoffR;
      __syncthreads();
    }
    int t = (s < 15) ? s : 29 - s;

    // prefetch pre (off the critical path, overlaps h staging)
    float pv[8];
    {
      const float* pp = pre + (long)(bb*15 + t)*H4 + jb0 + jj0;
      #pragma unroll
      for (int p = 0; p < 2; ++p) {
        pv[p*4+0] = pp[p];
        pv[p*4+1] = pp[H + p];
        pv[p*4+2] = pp[2*H + p];
        pv[p*4+3] = pp[3*H + p];
      }
    }

    // stage h(prev): u64 relaxed agent loads, all in flight
    const unsigned long long* hsrc =
        (const unsigned long long*)(hbuf + (long)(s & 1) * 32 * H);
    if (H == 512) stage_h<16, 9>(hsrc, hs, tid);
    else          stage_h<8, 8>(hsrc, hs, tid);
    __syncthreads();

    // recurrent GEMM: wave = gate, m-tiles = batches 0..15 / 16..31
    f32x4 acc0 = {0.f,0.f,0.f,0.f}, acc1 = {0.f,0.f,0.f,0.f};
    for (int k0 = 0; k0 < H; k0 += 32) {
      half8 bf = *reinterpret_cast<half8*>(&BsT[wave*16 + l15][k0 + quad*8]);
      half8 a0 = *reinterpret_cast<half8*>(&hs[l15][k0 + quad*8]);
      half8 a1 = *reinterpret_cast<half8*>(&hs[16 + l15][k0 + quad*8]);
      acc0 = __builtin_amdgcn_mfma_f32_16x16x32_f16(a0, bf, acc0, 0, 0, 0);
      acc1 = __builtin_amdgcn_mfma_f32_16x16x32_f16(a1, bf, acc1, 0, 0, 0);
    }
    #pragma unroll
    for (int r = 0; r < 4; ++r) {
      gates[quad*4 + r][wave*16 + l15]      = acc0[r];
      gates[16 + quad*4 + r][wave*16 + l15] = acc1[r];
    }
    __syncthreads();

    // c/h update
    unsigned hpack;
    {
      half_t hn2[2];
      #pragma unroll
      for (int p = 0; p < 2; ++p) {
        int jj = jj0 + p;
        float gi = pv[p*4+0] + gates[bb][jj];
        float gf = pv[p*4+1] + gates[bb][16 + jj];
        float gg = pv[p*4+2] + gates[bb][32 + jj];
        float go = pv[p*4+3] + gates[bb][48 + jj];
        gi = fsig_(gi); gf = fsig_(gf); gg = ftanh_(gg); go = fsig_(go);
        float cn = gf * cst[p] + gi * gg;
        cst[p] = cn;
        hn2[p] = (half_t)(go * ftanh_(cn));
      }
      hpack = *reinterpret_cast<unsigned*>(hn2);
      half_t* hdst = hbuf + (long)((s + 1) & 1) * 32 * H;
      __hip_atomic_store((unsigned*)(hdst + (long)bb*H + jb0 + jj0), hpack,
                         __ATOMIC_RELAXED, __HIP_MEMORY_SCOPE_AGENT);
    }

    if (s < 29) {
      __syncthreads();           // vmcnt(0): h stores acked at coherence point
      if (tid == 0)
        __hip_atomic_store(&flags[blockIdx.x*16], s + 1,
                           __ATOMIC_RELAXED, __HIP_MEMORY_SCOPE_AGENT);
      // y store after the flag: its ack overlaps the poll
      *reinterpret_cast<unsigned*>(&y[(long)(bb*15 + t)*ystride + yoff + jb0 + jj0]) = hpack;
      if (tid < 64) {
        int target = s + 1;
        for (;;) {
          int vv = (tid < nblk)
            ? __hip_atomic_load(&flags[tid*16], __ATOMIC_RELAXED, __HIP_MEMORY_SCOPE_AGENT)
            : target;
          if (__all(vv >= target)) break;
          __builtin_amdgcn_s_sleep(1);
        }
      }
      __syncthreads();
    } else {
      *reinterpret_cast<unsigned*>(&y[(long)(bb*15 + t)*ystride + yoff + jb0 + jj0]) = hpack;
    }
  }
}

// ------------------------------------------------------------------
// Host orchestration
// ------------------------------------------------------------------
extern "C" void kernel_launch(void* const* d_in, const int* in_sizes, int n_in,
                              void* d_out, int out_size, void* d_ws, size_t ws_size,
                              hipStream_t stream)
{
  const float* x       = (const float*)d_in[0];
  const float* c1w     = (const float*)d_in[1];  const float* c1b = (const float*)d_in[2];
  const float* c2w     = (const float*)d_in[3];  const float* c2b = (const float*)d_in[4];
  const float* c3w     = (const float*)d_in[5];  const float* c3b = (const float*)d_in[6];
  const float* bn1s    = (const float*)d_in[7];  const float* bn1b = (const float*)d_in[8];
  const float* c4w     = (const float*)d_in[9];  const float* c4b = (const float*)d_in[10];
  const float* bn2s    = (const float*)d_in[11]; const float* bn2b = (const float*)d_in[12];
  const float* c5w     = (const float*)d_in[13]; const float* c5b = (const float*)d_in[14];
  const float* bn3s    = (const float*)d_in[15]; const float* bn3b = (const float*)d_in[16];
  const float* c6w     = (const float*)d_in[17]; const float* c6b = (const float*)d_in[18];
  const float* bn4s    = (const float*)d_in[19]; const float* bn4b = (const float*)d_in[20];
  const float* c7w     = (const float*)d_in[21]; const float* c7b = (const float*)d_in[22];
  const float* bn5s    = (const float*)d_in[23]; const float* bn5b = (const float*)d_in[24];
  const float* wq      = (const float*)d_in[25]; const float* bq = (const float*)d_in[26];
  const float* wk      = (const float*)d_in[27]; const float* bk = (const float*)d_in[28];
  const float* wv      = (const float*)d_in[29]; const float* bv = (const float*)d_in[30];
  const float* l1f_wx  = (const float*)d_in[31]; const float* l1f_wh = (const float*)d_in[32]; const float* l1f_b = (const float*)d_in[33];
  const float* l1r_wx  = (const float*)d_in[34]; const float* l1r_wh = (const float*)d_in[35]; const float* l1r_b = (const float*)d_in[36];
  const float* l2f_wx  = (const float*)d_in[37]; const float* l2f_wh = (const float*)d_in[38]; const float* l2f_b = (const float*)d_in[39];
  const float* l2r_wx  = (const float*)d_in[40]; const float* l2r_wh = (const float*)d_in[41]; const float* l2r_b = (const float*)d_in[42];
  const float* wo      = (const float*)d_in[43]; const float* bo = (const float*)d_in[44];
  float* outp = (float*)d_out;

  char* base = (char*)d_ws;
  half_t* actA = (half_t*)base;
  half_t* actB = (half_t*)(base + 67108864);
  half_t* wtA  = (half_t*)(base + 100663296);
  float*  f32a = (float*)(base + 143687680);
  half_t* h16a = (half_t*)(base + 158736384);

  half_t* wt2  = wtA;
  half_t* wt3  = wtA + 73728;
  half_t* wt4  = wtA + 368640;
  half_t* wt5  = wtA + 958464;
  half_t* wt6  = wtA + 2138112;
  half_t* wt7  = wtA + 4497408;
  half_t* wtq  = wtA + 5545984;        // wtq|wtk|wtv contiguous -> [1536][7680]
  half_t* wtk  = wtA + 9478144;
  half_t* wtv  = wtA + 13410304;
  half_t* wt1f = wtA + 17342464;
  half_t* wt1r = wtA + 17866752;
  half_t* wt2f = wtA + 18391040;
  half_t* wt2r = wtA + 19439616;
  half_t* wto  = wtA + 20488192;

  float* qkvbuf = f32a;                // 480 x 1536 f32
  float* pre1f = f32a + 737280;
  float* pre1r = f32a + 1228800;
  float* pre2f = f32a + 1720320;
  float* pre2r = f32a + 2703360;

  half_t* ao  = h16a;
  half_t* x1  = h16a + 245760;
  half_t* x2  = h16a + 491520;
  half_t* hb1 = h16a + 983040;              // 2 x 32 x 256 fp16
  half_t* hb2 = hb1 + 16384;                // 2 x 32 x 512 fp16
  int*    flags1 = (int*)(hb2 + 32768);     // 512 ints
  int*    flags2 = flags1 + 512;
  half_t* zbuf   = (half_t*)(flags2 + 512); // 32 halves
  float*  bnz    = (float*)(zbuf + 32);     // 5 x 2048 floats

  auto convm = [&](const half_t* in, const half_t* wt, const float* b, void* out,
                   int N,int H,int W,int Ci,int Ho,int Wo,int Co,
                   int KH,int KW,int pH,int pW,int flags){
    int M = N*Ho*Wo, K = KH*KW*Ci;
    dim3 grid(DIV_UP(Co,128), DIV_UP(M,128), 1);
    GOut g{wt, b, out};
    mfma_conv_kernel<<<grid,256,0,stream>>>(in,g,g,g,zbuf,N,H,W,Ci,Ho,Wo,Co,
                                            KH,KW,pH,pW,M,K,flags,1);
  };
  auto gemm3 = [&](const half_t* A, GOut g0, GOut g1, GOut g2, int nz,
                   int M, int Nn, int K, int flags, int splitS){
    dim3 grid(DIV_UP(Nn,128), DIV_UP(M,128), nz);
    mfma_conv_kernel<<<grid,256,0,stream>>>(A,g0,g1,g2,zbuf,M,1,1,K,1,1,Nn,
                                            1,1,0,0,M,K,flags,splitS);
  };
  auto pool = [&](const half_t* in, half_t* out, int N,int H,int W,int C,
                  int Ho,int Wo,int sH,int sW){
    long total8 = (long)N*Ho*Wo*(C/8);
    maxpool8_kernel<<<(int)DIV_UP(total8,256),256,0,stream>>>(in,out,N,H,W,C,Ho,Wo,sH,sW);
  };
  auto bn = [&](half_t* buf, long nPix, int C, const float* s, const float* b,
                float* sums){
    bn_sums8_kernel<<<256,256,0,stream>>>(buf, sums, nPix, C);
    long total8 = nPix * C / 8;
    bn_apply_relu8_kernel<<<(int)DIV_UP(total8,256),256,0,stream>>>(buf, sums, s, b, total8, C, 1.0f/(float)nPix);
  };

  // one zero-fill for hb1..hb2, flags, zbuf, 5 bn-sum buffers
  hipMemsetAsync(hb1, 0, 143424, stream);

  // ---- ALL weight transposes in one launch ----
  {
    TpAll tp;
    const float* srcs[14] = {c2w,c3w,c4w,c5w,c6w,c7w,wq,wk,wv,l1f_wx,l1r_wx,l2f_wx,l2r_wx,wo};
    half_t* dsts[14] = {wt2,wt3,wt4,wt5,wt6,wt7,wtq,wtk,wtv,wt1f,wt1r,wt2f,wt2r,wto};
    int Ks[14] = {576,1152,2304,2304,4608,2048,7680,7680,7680,512,512,512,512,1024};
    int Ns[14] = {128,256,256,512,512,512,512,512,512,1024,1024,2048,2048,1000};
    int acc = 0;
    for (int i = 0; i < 14; ++i) {
      tp.src[i] = srcs[i]; tp.dst[i] = dsts[i]; tp.K[i] = Ks[i]; tp.N[i] = Ns[i];
      tp.prefix[i] = acc;
      acc += DIV_UP(Ks[i],32) * DIV_UP(Ns[i],32);
    }
    tp.prefix[14] = acc;
    transpose_cvt_all_kernel<<<acc,256,0,stream>>>(tp);
  }

  // ---- conv stack (activations fp16) ----
  conv1_kernel<<<2048,256,0,stream>>>(x, c1w, c1b, actA);
  pool(actA, actB, 32,64,256,64,  32,128, 2,2);
  convm(actB, wt2, c2b, actA, 32,32,128,64,  32,128,128, 3,3,1,1, FLAG_RELU);
  pool(actA, actB, 32,32,128,128, 16,64, 2,2);
  convm(actB, wt3, c3b, actA, 32,16,64,128,  16,64,256,  3,3,1,1, 0);
  bn(actA, 32768, 256, bn1s, bn1b, bnz);
  convm(actA, wt4, c4b, actB, 32,16,64,256,  16,64,256,  3,3,1,1, 0);
  bn(actB, 32768, 256, bn2s, bn2b, bnz + 2048);
  pool(actB, actA, 32,16,64,256,  16,32, 1,2);
  convm(actA, wt5, c5b, actB, 32,16,32,256,  16,32,512,  3,3,1,1, 0);
  bn(actB, 16384, 512, bn3s, bn3b, bnz + 4096);
  convm(actB, wt6, c6b, actA, 32,16,32,512,  16,32,512,  3,3,1,1, 0);
  bn(actA, 16384, 512, bn4s, bn4b, bnz + 6144);
  pool(actA, actB, 32,16,32,512,  16,16, 1,2);
  convm(actB, wt7, c7b, actA, 32,16,16,512,  15,15,512,  2,2,0,0, 0);
  bn(actA, 7200, 512, bn5s, bn5b, bnz + 8192);

  // ---- attention: single qkv GEMM (N=1536), split-K x4, atomic epilogue ----
  bias_fill_kernel<<<DIV_UP(480*1536,256),256,0,stream>>>(qkvbuf, bq, bk, bv, 480*1536);
  gemm3(actA, GOut{wtq, nullptr, qkvbuf}, GOut{wtq, nullptr, qkvbuf},
        GOut{wtq, nullptr, qkvbuf}, 4, 480, 1536, 7680, FLAG_SPLITK|FLAG_ATOMIC, 4);
  attention_kernel<<<32,256,0,stream>>>(qkvbuf, ao, 15, 512, 1536);

  // ---- LSTM stack 1 (H=256) ----
  gemm3(ao, GOut{wt1f, l1f_b, pre1f}, GOut{wt1r, l1r_b, pre1r},
        GOut{wt1r, l1r_b, pre1r}, 2, 480, 1024, 512, FLAG_OUTF32, 1);
  lstm_persistent_kernel<<<16,256,0,stream>>>(
      pre1f, pre1r, l1f_wh, l1r_wh, hb1, x1, flags1, 256, 16, 512, 0, 256);

  // ---- LSTM stack 2 (H=512) ----
  gemm3(x1, GOut{wt2f, l2f_b, pre2f}, GOut{wt2r, l2r_b, pre2r},
        GOut{wt2r, l2r_b, pre2r}, 2, 480, 2048, 512, FLAG_OUTF32, 1);
  lstm_persistent_kernel<<<32,256,0,stream>>>(
      pre2f, pre2r, l2f_wh, l2r_wh, hb2, x2, flags2, 512, 32, 1024, 512, 0);

  // ---- classifier ----
  gemm3(x2, GOut{wto, bo, outp}, GOut{wto, bo, outp}, GOut{wto, bo, outp}, 1,
        480, 1000, 1024, FLAG_OUTF32, 1);
}

// Round 8
// 1127.605 us; speedup vs baseline: 36.0702x; 1.3123x over previous
//
#include <hip/hip_runtime.h>
#include <math.h>

#define DIV_UP(a,b) (((a)+(b)-1)/(b))

typedef _Float16 half_t;
typedef _Float16 half8 __attribute__((ext_vector_type(8)));
typedef float f32x4 __attribute__((ext_vector_type(4)));

#define FLAG_RELU   1
#define FLAG_OUTF32 2
#define FLAG_SPLITK 4
#define FLAG_ATOMIC 8
#define FLAG_BNSUMS 16

#define GLDS16(src, dst) \
  __builtin_amdgcn_global_load_lds((const __attribute__((address_space(1))) void*)(src), \
                                   (__attribute__((address_space(3))) void*)(dst), 16, 0, 0)

__device__ __forceinline__ float fsig_(float x){ return 1.0f/(1.0f+__expf(-x)); }
__device__ __forceinline__ float ftanh_(float x){
  float ax = fabsf(x);
  float e = __expf(-2.0f*ax);
  float t = (1.0f - e)/(1.0f + e);
  return copysignf(t, x);
}

// ------------------------------------------------------------------
// ALL weight transposes (fp32 [K][N] -> fp16 [N][K]) in ONE launch.
// ------------------------------------------------------------------
struct TpAll {
  const float* src[14];
  half_t* dst[14];
  int K[14];
  int N[14];
  int prefix[15];
};

__global__ __launch_bounds__(256) void transpose_cvt_all_kernel(TpAll a)
{
  __shared__ float tile[32][33];
  int bid = blockIdx.x;
  int z = 0;
  while (bid >= a.prefix[z+1]) ++z;
  int local = bid - a.prefix[z];
  const float* w = a.src[z];
  half_t* wT = a.dst[z];
  int K = a.K[z], N = a.N[z];
  int tilesX = (N + 31) >> 5;
  int nt = (local % tilesX) * 32;
  int kt = (local / tilesX) * 32;
  int tx = threadIdx.x & 31, ty = threadIdx.x >> 5;
  #pragma unroll
  for (int r = 0; r < 4; ++r) {
    int k = kt + ty + r*8, n = nt + tx;
    tile[ty + r*8][tx] = (k < K && n < N) ? w[(long)k*N + n] : 0.f;
  }
  __syncthreads();
  #pragma unroll
  for (int r = 0; r < 4; ++r) {
    int n = nt + ty + r*8, k = kt + tx;
    if (n < N && k < K) wT[(long)n*K + k] = (half_t)tile[tx][ty + r*8];
  }
}

// ------------------------------------------------------------------
// conv1 special case: x (32,64,256,3) fp32, w (3,3,3,64), out fp16 + ReLU.
// ------------------------------------------------------------------
__global__ __launch_bounds__(256) void conv1_kernel(
    const float* __restrict__ x, const float* __restrict__ w,
    const float* __restrict__ bias, half_t* __restrict__ out)
{
  __shared__ float xs[3][258*3];
  int nb = blockIdx.x;            // n*64 + ho
  int n = nb >> 6, ho = nb & 63;
  int tid = threadIdx.x;
  int co = tid & 63;
  float wreg[27];
  #pragma unroll
  for (int k = 0; k < 27; ++k) wreg[k] = w[k*64 + co];
  float bco = bias[co];
  for (int i = tid; i < 3*258*3; i += 256) {
    int row = i / (258*3); int rem = i % (258*3);
    int col = rem / 3;     int ci  = rem % 3;
    int ih = ho - 1 + row; int iw = col - 1;
    float v = 0.f;
    if (ih >= 0 && ih < 64 && iw >= 0 && iw < 256)
      v = x[(((long)n*64 + ih)*256 + iw)*3 + ci];
    xs[row][col*3 + ci] = v;
  }
  __syncthreads();
  int wave = tid >> 6;
  for (int p = 0; p < 64; ++p) {
    int wo = wave*64 + p;
    float acc = bco;
    #pragma unroll
    for (int kh = 0; kh < 3; ++kh)
      #pragma unroll
      for (int kw = 0; kw < 3; ++kw)
        #pragma unroll
        for (int ci = 0; ci < 3; ++ci)
          acc = fmaf(xs[kh][(wo+kw)*3 + ci], wreg[(kh*3+kw)*3 + ci], acc);
    acc = fmaxf(acc, 0.f);
    out[(((long)n*64 + ho)*256 + wo)*64 + co] = (half_t)acc;
  }
}

// ------------------------------------------------------------------
// MFMA implicit-GEMM conv/GEMM. 128x128 tile, BK=64, 4 waves,
// mfma_f32_16x16x32_f16, global_load_lds width-16 staging with XOR
// chunk swizzle (pchunk = chunk ^ (row&7)) so fragment ds_read_b128s
// are conflict-free (2-way only). Requires Ci % 64 == 0 (true for all
// users). FLAG_BNSUMS: epilogue accumulates per-channel sum/sumsq of
// the f32 (acc+bias) values into bns via LDS reduce + 1 atomic/chan.
// ------------------------------------------------------------------
struct GOut { const half_t* wT; const float* bias; void* out; };

__global__ __launch_bounds__(256) void mfma_conv_kernel(
    const half_t* __restrict__ x, GOut g0, GOut g1, GOut g2,
    const half_t* __restrict__ zbuf, float* __restrict__ bns,
    int N,int H,int W,int Ci,int Ho,int Wo,int Co,
    int KH,int KW,int padH,int padW,
    int M,int K,int flags,int splitS)
{
  GOut g;
  int ciBeg = 0, ciEnd = Ci;
  if (flags & FLAG_SPLITK) {
    g = g0;
    int span = Ci / splitS;
    ciBeg = blockIdx.z * span;
    ciEnd = ciBeg + span;
  } else {
    g = (blockIdx.z == 0) ? g0 : (blockIdx.z == 1 ? g1 : g2);
  }
  const half_t* __restrict__ wT = g.wT;
  __shared__ half_t As[128*64];
  __shared__ half_t Bs[128*64];
  int tid = threadIdx.x;
  int m0 = blockIdx.y*128, n0 = blockIdx.x*128;
  int wave = tid >> 6, lane = tid & 63;
  int l15 = lane & 15, quad = lane >> 4;
  int x7 = lane & 7;
  int wm = (wave & 1) * 64, wn = (wave >> 1) * 64;

  // staging decode: 4 issues, row_i = i*32 + (tid>>3), source chunk swizzled
  int rSub = tid >> 3;
  int colHalf = (((tid & 7) ^ (rSub & 7))) * 8;

  int ho_[4], wo_[4], ni_[4]; bool av_[4];
  #pragma unroll
  for (int i = 0; i < 4; ++i) {
    int m = m0 + i*32 + rSub;
    av_[i] = m < M;
    int mm = av_[i] ? m : 0;
    wo_[i] = mm % Wo; int t2 = mm / Wo;
    ho_[i] = t2 % Ho; ni_[i] = t2 / Ho;
  }
  const half_t* bBase[4];
  #pragma unroll
  for (int i = 0; i < 4; ++i) {
    int n = n0 + i*32 + rSub;
    bBase[i] = (n < Co) ? (wT + (long)n*K + colHalf) : nullptr;
  }

  // fragment LDS chunk offsets per k-sub (conflict-free via XOR swizzle)
  int pch0 = ((quad)     ^ x7) * 8;
  int pch1 = ((4 + quad) ^ x7) * 8;

  f32x4 acc[4][4];
  #pragma unroll
  for (int i = 0; i < 4; ++i)
    #pragma unroll
    for (int j = 0; j < 4; ++j)
      acc[i][j] = (f32x4){0.f, 0.f, 0.f, 0.f};

  int kg = ciBeg;
  for (int kh = 0; kh < KH; ++kh) {
    for (int kw = 0; kw < KW; ++kw) {
      long aOff[4]; bool aval[4];
      #pragma unroll
      for (int i = 0; i < 4; ++i) {
        int ih = ho_[i] - padH + kh, iw = wo_[i] - padW + kw;
        bool ok = av_[i] && ih >= 0 && ih < H && iw >= 0 && iw < W;
        aval[i] = ok;
        aOff[i] = ok ? ((((long)ni_[i]*H + ih)*W + iw)*(long)Ci + colHalf) : 0;
      }
      for (int ci = ciBeg; ci < ciEnd; ci += 64, kg += 64) {
        #pragma unroll
        for (int i = 0; i < 4; ++i) {
          const half_t* sa = aval[i] ? (x + aOff[i] + ci) : zbuf;
          GLDS16(sa, As + i*2048 + wave*512);
          const half_t* sb = bBase[i] ? (bBase[i] + kg) : zbuf;
          GLDS16(sb, Bs + i*2048 + wave*512);
        }
        __syncthreads();
        {
          half8 af[4], bf[4];
          #pragma unroll
          for (int i = 0; i < 4; ++i)
            af[i] = *reinterpret_cast<half8*>(&As[(wm + i*16 + l15)*64 + pch0]);
          #pragma unroll
          for (int j = 0; j < 4; ++j)
            bf[j] = *reinterpret_cast<half8*>(&Bs[(wn + j*16 + l15)*64 + pch0]);
          #pragma unroll
          for (int i = 0; i < 4; ++i)
            #pragma unroll
            for (int j = 0; j < 4; ++j)
              acc[i][j] = __builtin_amdgcn_mfma_f32_16x16x32_f16(af[i], bf[j], acc[i][j], 0, 0, 0);
        }
        {
          half8 af[4], bf[4];
          #pragma unroll
          for (int i = 0; i < 4; ++i)
            af[i] = *reinterpret_cast<half8*>(&As[(wm + i*16 + l15)*64 + pch1]);
          #pragma unroll
          for (int j = 0; j < 4; ++j)
            bf[j] = *reinterpret_cast<half8*>(&Bs[(wn + j*16 + l15)*64 + pch1]);
          #pragma unroll
          for (int i = 0; i < 4; ++i)
            #pragma unroll
            for (int j = 0; j < 4; ++j)
              acc[i][j] = __builtin_amdgcn_mfma_f32_16x16x32_f16(af[i], bf[j], acc[i][j], 0, 0, 0);
        }
        __syncthreads();
      }
    }
  }

  // ---- BN sums from accumulators (f32, pre-relu value incl. bias) ----
  if (flags & FLAG_BNSUMS) {
    float* red = (float*)As;     // [wave][quad][l15][j][2] = 4*4*16*4*2 floats
    #pragma unroll
    for (int j = 0; j < 4; ++j) {
      int n = n0 + wn + j*16 + l15;
      float bv = g.bias[n];
      float s = 0.f, q = 0.f;
      #pragma unroll
      for (int i = 0; i < 4; ++i)
        #pragma unroll
        for (int r = 0; r < 4; ++r) {
          int m = m0 + wm + i*16 + quad*4 + r;
          if (m < M) { float v = acc[i][j][r] + bv; s += v; q += v*v; }
        }
      int idx = ((((wave*4 + quad)*16 + l15)*4) + j)*2;
      red[idx] = s; red[idx+1] = q;
    }
    __syncthreads();
    if (tid < 128) {
      int hi = tid >> 6;               // which 64-channel half (wn)
      int jj = (tid >> 4) & 3, ll = tid & 15;
      float s = 0.f, q = 0.f;
      #pragma unroll
      for (int w2 = 0; w2 < 2; ++w2)
        #pragma unroll
        for (int qd = 0; qd < 4; ++qd) {
          int idx = (((((hi*2 + w2)*4 + qd)*16 + ll)*4) + jj)*2;
          s += red[idx]; q += red[idx+1];
        }
      int n = n0 + tid;                // == n0 + hi*64 + jj*16 + ll
      atomicAdd(&bns[n], s);
      atomicAdd(&bns[Co + n], q);
    }
  }

  // ---- store ----
  #pragma unroll
  for (int i = 0; i < 4; ++i) {
    #pragma unroll
    for (int r = 0; r < 4; ++r) {
      int m = m0 + wm + i*16 + quad*4 + r;
      if (m >= M) continue;
      #pragma unroll
      for (int j = 0; j < 4; ++j) {
        int n = n0 + wn + j*16 + l15;
        if (n >= Co) continue;
        if (flags & FLAG_ATOMIC) {
          atomicAdd(&((float*)g.out)[(long)m*Co + n], acc[i][j][r]);
        } else {
          float v = acc[i][j][r] + g.bias[n];
          if (flags & FLAG_RELU) v = fmaxf(v, 0.f);
          if (flags & FLAG_OUTF32) ((float*)g.out)[(long)m*Co + n] = v;
          else ((half_t*)g.out)[(long)m*Co + n] = (half_t)v;
        }
      }
    }
  }
}

// ------------------------------------------------------------------
// Max pool fp16, NHWC, 8 channels per thread.
// ------------------------------------------------------------------
__global__ __launch_bounds__(256) void maxpool8_kernel(
    const half_t* __restrict__ x, half_t* __restrict__ out,
    int N,int H,int W,int C,int Ho,int Wo,int sH,int sW)
{
  int C8 = C >> 3;
  long idx = (long)blockIdx.x*256 + threadIdx.x;
  long total8 = (long)N*Ho*Wo*C8;
  if (idx >= total8) return;
  int cb = (int)(idx % C8);
  long pix = idx / C8;
  int wo = (int)(pix % Wo); long t2 = pix / Wo;
  int ho = (int)(t2 % Ho); int n = (int)(t2 / Ho);
  int c = cb * 8;
  float m[8];
  #pragma unroll
  for (int e = 0; e < 8; ++e) m[e] = -INFINITY;
  for (int i = 0; i < 2; ++i) {
    int ih = ho*sH + i;
    if (ih >= H) continue;
    for (int j = 0; j < 2; ++j) {
      int iw = wo*sW + j;
      if (iw >= W) continue;
      half8 v = *reinterpret_cast<const half8*>(x + (((long)n*H + ih)*W + iw)*C + c);
      #pragma unroll
      for (int e = 0; e < 8; ++e) m[e] = fmaxf(m[e], (float)v[e]);
    }
  }
  half8 o;
  #pragma unroll
  for (int e = 0; e < 8; ++e) o[e] = (half_t)m[e];
  *reinterpret_cast<half8*>(out + idx*8) = o;
}

// ------------------------------------------------------------------
// BN apply + ReLU (in place), 8 channels/thread.
// ------------------------------------------------------------------
__global__ __launch_bounds__(256) void bn_apply_relu8_kernel(
    half_t* __restrict__ x, const float* __restrict__ sums,
    const float* __restrict__ scale, const float* __restrict__ bias,
    long total8, int C, float invN)
{
  long idx = (long)blockIdx.x*256 + threadIdx.x;
  if (idx >= total8) return;
  int c = (int)((idx*8) % C);
  half8 v = *reinterpret_cast<half8*>(x + idx*8);
  half8 o;
  #pragma unroll
  for (int e = 0; e < 8; ++e) {
    float mean = sums[c+e] * invN;
    float var  = sums[C + c+e] * invN - mean*mean;
    float rstd = rsqrtf(var + 1e-5f);
    float y = ((float)v[e] - mean) * rstd * scale[c+e] + bias[c+e];
    o[e] = (half_t)fmaxf(y, 0.0f);
  }
  *reinterpret_cast<half8*>(x + idx*8) = o;
}

// ------------------------------------------------------------------
// Fused BN+ReLU+maxpool: out (N,Ho,Wo,C) from in (N,H,W,C).
// ------------------------------------------------------------------
__global__ __launch_bounds__(256) void bn_pool8_kernel(
    const half_t* __restrict__ x, half_t* __restrict__ out,
    const float* __restrict__ sums, const float* __restrict__ scale,
    const float* __restrict__ bias,
    int N,int H,int W,int C,int Ho,int Wo,int sH,int sW, float invN)
{
  int C8 = C >> 3;
  long idx = (long)blockIdx.x*256 + threadIdx.x;
  long total8 = (long)N*Ho*Wo*C8;
  if (idx >= total8) return;
  int cb = (int)(idx % C8);
  long pix = idx / C8;
  int wo = (int)(pix % Wo); long t2 = pix / Wo;
  int ho = (int)(t2 % Ho); int n = (int)(t2 / Ho);
  int c = cb * 8;
  float mean[8], rs[8], bb[8];
  #pragma unroll
  for (int e = 0; e < 8; ++e) {
    mean[e] = sums[c+e] * invN;
    float var = sums[C + c+e] * invN - mean[e]*mean[e];
    rs[e] = rsqrtf(var + 1e-5f) * scale[c+e];
    bb[e] = bias[c+e];
  }
  float m[8];
  #pragma unroll
  for (int e = 0; e < 8; ++e) m[e] = -INFINITY;
  for (int i = 0; i < 2; ++i) {
    int ih = ho*sH + i;
    if (ih >= H) continue;
    for (int j = 0; j < 2; ++j) {
      int iw = wo*sW + j;
      if (iw >= W) continue;
      half8 v = *reinterpret_cast<const half8*>(x + (((long)n*H + ih)*W + iw)*C + c);
      #pragma unroll
      for (int e = 0; e < 8; ++e) {
        float y = fmaxf(((float)v[e] - mean[e]) * rs[e] + bb[e], 0.f);
        m[e] = fmaxf(m[e], y);
      }
    }
  }
  half8 o;
  #pragma unroll
  for (int e = 0; e < 8; ++e) o[e] = (half_t)m[e];
  *reinterpret_cast<half8*>(out + idx*8) = o;
}

// ------------------------------------------------------------------
// Bias prefill for the split-K qkv GEMM output (480 x 1536 f32).
// ------------------------------------------------------------------
__global__ __launch_bounds__(256) void bias_fill_kernel(
    float* __restrict__ out, const float* __restrict__ b0,
    const float* __restrict__ b1, const float* __restrict__ b2, int total)
{
  int idx = blockIdx.x*256 + threadIdx.x;
  if (idx >= total) return;
  int n = idx % 1536;
  float v = (n < 512) ? b0[n] : (n < 1024 ? b1[n-512] : b2[n-1024]);
  out[idx] = v;
}

// ------------------------------------------------------------------
// Attention (T=15, D=512), qkv interleaved f32 rows of ld=1536, out fp16.
// ------------------------------------------------------------------
__global__ __launch_bounds__(256) void attention_kernel(
    const float* __restrict__ qkv, half_t* __restrict__ out,
    int T, int D, int ld)
{
  int b = blockIdx.x;
  int tid = threadIdx.x;
  __shared__ float P[15][16];
  if (tid < T*T) {
    int t = tid / T, s = tid % T;
    const float* qp = qkv + ((long)b*T + t)*ld;
    const float* kp = qkv + ((long)b*T + s)*ld + 512;
    float acc = 0.f;
    for (int d = 0; d < D; d += 4) {
      float4 qv = *reinterpret_cast<const float4*>(qp + d);
      float4 kv = *reinterpret_cast<const float4*>(kp + d);
      acc += qv.x*kv.x + qv.y*kv.y + qv.z*kv.z + qv.w*kv.w;
    }
    P[t][s] = acc * (1.0f/32.0f);
  }
  __syncthreads();
  if (tid < T) {
    float mx = -INFINITY;
    for (int s = 0; s < T; ++s) mx = fmaxf(mx, P[tid][s]);
    float sum = 0.f;
    for (int s = 0; s < T; ++s) { float e = expf(P[tid][s] - mx); P[tid][s] = e; sum += e; }
    float inv = 1.0f / sum;
    for (int s = 0; s < T; ++s) P[tid][s] *= inv;
  }
  __syncthreads();
  for (int idx = tid; idx < T*D; idx += 256) {
    int s = idx / D, kk2 = idx % D;
    float acc = 0.f;
    #pragma unroll
    for (int t = 0; t < 15; ++t)
      acc += qkv[((long)b*T + t)*ld + 1024 + kk2] * P[t][s];
    out[((long)b*T + s)*D + kk2] = (half_t)acc;
  }
}

// ------------------------------------------------------------------
// Persistent bidirectional LSTM (unchanged from round 7).
// ------------------------------------------------------------------
#define MAXK 512
#define HSROW (MAXK + 8)

template<int N64, int HLOG>
__device__ __forceinline__ void stage_h(
    const unsigned long long* __restrict__ src, half_t (*hs)[HSROW], int tid)
{
  unsigned long long tmp[N64];
  #pragma unroll
  for (int u = 0; u < N64; ++u)
    tmp[u] = __hip_atomic_load(src + tid + u*256, __ATOMIC_RELAXED, __HIP_MEMORY_SCOPE_AGENT);
  #pragma unroll
  for (int u = 0; u < N64; ++u) {
    int idx = tid + u*256;
    int row = idx >> (HLOG - 2);
    int col = (idx & ((1 << (HLOG - 2)) - 1)) * 4;
    *reinterpret_cast<unsigned long long*>(&hs[row][col]) = tmp[u];
  }
}

__global__ __launch_bounds__(256, 1) void lstm_persistent_kernel(
    const float* __restrict__ preF, const float* __restrict__ preR,
    const float* __restrict__ whF, const float* __restrict__ whR,
    half_t* __restrict__ hbuf, half_t* __restrict__ y,
    int* __restrict__ flags, int H, int nblk,
    int ystride, int yoffF, int yoffR)
{
  __shared__ half_t BsT[64][HSROW];
  __shared__ half_t hs[32][HSROW];
  __shared__ float gates[32][65];
  int tid = threadIdx.x;
  int jb0 = blockIdx.x * 16;
  int H4 = 4 * H;
  int lane = tid & 63, wave = tid >> 6;
  int l15 = lane & 15, quad = lane >> 4;
  int bb = tid >> 3;
  int jj0 = (tid & 7) * 2;

  float cst[2] = {0.f, 0.f};

  for (int idx = tid; idx < H*64; idx += 256) {
    int k = idx >> 6, c = idx & 63;
    int g = c >> 4, jj = c & 15;
    BsT[c][k] = (half_t)whF[(long)k*H4 + g*H + jb0 + jj];
  }
  const float* pre = preF;
  int yoff = yoffF;
  __syncthreads();

  for (int s = 0; s < 30; ++s) {
    if (s == 15) {
      __syncthreads();
      for (int idx = tid; idx < H*64; idx += 256) {
        int k = idx >> 6, c = idx & 63;
        int g = c >> 4, jj = c & 15;
        BsT[c][k] = (half_t)whR[(long)k*H4 + g*H + jb0 + jj];
      }
      pre = preR; yoff = yoffR;
      __syncthreads();
    }
    int t = (s < 15) ? s : 29 - s;

    float pv[8];
    {
      const float* pp = pre + (long)(bb*15 + t)*H4 + jb0 + jj0;
      #pragma unroll
      for (int p = 0; p < 2; ++p) {
        pv[p*4+0] = pp[p];
        pv[p*4+1] = pp[H + p];
        pv[p*4+2] = pp[2*H + p];
        pv[p*4+3] = pp[3*H + p];
      }
    }

    const unsigned long long* hsrc =
        (const unsigned long long*)(hbuf + (long)(s & 1) * 32 * H);
    if (H == 512) stage_h<16, 9>(hsrc, hs, tid);
    else          stage_h<8, 8>(hsrc, hs, tid);
    __syncthreads();

    f32x4 acc0 = {0.f,0.f,0.f,0.f}, acc1 = {0.f,0.f,0.f,0.f};
    for (int k0 = 0; k0 < H; k0 += 32) {
      half8 bf = *reinterpret_cast<half8*>(&BsT[wave*16 + l15][k0 + quad*8]);
      half8 a0 = *reinterpret_cast<half8*>(&hs[l15][k0 + quad*8]);
      half8 a1 = *reinterpret_cast<half8*>(&hs[16 + l15][k0 + quad*8]);
      acc0 = __builtin_amdgcn_mfma_f32_16x16x32_f16(a0, bf, acc0, 0, 0, 0);
      acc1 = __builtin_amdgcn_mfma_f32_16x16x32_f16(a1, bf, acc1, 0, 0, 0);
    }
    #pragma unroll
    for (int r = 0; r < 4; ++r) {
      gates[quad*4 + r][wave*16 + l15]      = acc0[r];
      gates[16 + quad*4 + r][wave*16 + l15] = acc1[r];
    }
    __syncthreads();

    unsigned hpack;
    {
      half_t hn2[2];
      #pragma unroll
      for (int p = 0; p < 2; ++p) {
        int jj = jj0 + p;
        float gi = pv[p*4+0] + gates[bb][jj];
        float gf = pv[p*4+1] + gates[bb][16 + jj];
        float gg = pv[p*4+2] + gates[bb][32 + jj];
        float go = pv[p*4+3] + gates[bb][48 + jj];
        gi = fsig_(gi); gf = fsig_(gf); gg = ftanh_(gg); go = fsig_(go);
        float cn = gf * cst[p] + gi * gg;
        cst[p] = cn;
        hn2[p] = (half_t)(go * ftanh_(cn));
      }
      hpack = *reinterpret_cast<unsigned*>(hn2);
      half_t* hdst = hbuf + (long)((s + 1) & 1) * 32 * H;
      __hip_atomic_store((unsigned*)(hdst + (long)bb*H + jb0 + jj0), hpack,
                         __ATOMIC_RELAXED, __HIP_MEMORY_SCOPE_AGENT);
    }

    if (s < 29) {
      __syncthreads();
      if (tid == 0)
        __hip_atomic_store(&flags[blockIdx.x*16], s + 1,
                           __ATOMIC_RELAXED, __HIP_MEMORY_SCOPE_AGENT);
      *reinterpret_cast<unsigned*>(&y[(long)(bb*15 + t)*ystride + yoff + jb0 + jj0]) = hpack;
      if (tid < 64) {
        int target = s + 1;
        for (;;) {
          int vv = (tid < nblk)
            ? __hip_atomic_load(&flags[tid*16], __ATOMIC_RELAXED, __HIP_MEMORY_SCOPE_AGENT)
            : target;
          if (__all(vv >= target)) break;
          __builtin_amdgcn_s_sleep(1);
        }
      }
      __syncthreads();
    } else {
      *reinterpret_cast<unsigned*>(&y[(long)(bb*15 + t)*ystride + yoff + jb0 + jj0]) = hpack;
    }
  }
}

// ------------------------------------------------------------------
// Host orchestration
// ------------------------------------------------------------------
extern "C" void kernel_launch(void* const* d_in, const int* in_sizes, int n_in,
                              void* d_out, int out_size, void* d_ws, size_t ws_size,
                              hipStream_t stream)
{
  const float* x       = (const float*)d_in[0];
  const float* c1w     = (const float*)d_in[1];  const float* c1b = (const float*)d_in[2];
  const float* c2w     = (const float*)d_in[3];  const float* c2b = (const float*)d_in[4];
  const float* c3w     = (const float*)d_in[5];  const float* c3b = (const float*)d_in[6];
  const float* bn1s    = (const float*)d_in[7];  const float* bn1b = (const float*)d_in[8];
  const float* c4w     = (const float*)d_in[9];  const float* c4b = (const float*)d_in[10];
  const float* bn2s    = (const float*)d_in[11]; const float* bn2b = (const float*)d_in[12];
  const float* c5w     = (const float*)d_in[13]; const float* c5b = (const float*)d_in[14];
  const float* bn3s    = (const float*)d_in[15]; const float* bn3b = (const float*)d_in[16];
  const float* c6w     = (const float*)d_in[17]; const float* c6b = (const float*)d_in[18];
  const float* bn4s    = (const float*)d_in[19]; const float* bn4b = (const float*)d_in[20];
  const float* c7w     = (const float*)d_in[21]; const float* c7b = (const float*)d_in[22];
  const float* bn5s    = (const float*)d_in[23]; const float* bn5b = (const float*)d_in[24];
  const float* wq      = (const float*)d_in[25]; const float* bq = (const float*)d_in[26];
  const float* wk      = (const float*)d_in[27]; const float* bk = (const float*)d_in[28];
  const float* wv      = (const float*)d_in[29]; const float* bv = (const float*)d_in[30];
  const float* l1f_wx  = (const float*)d_in[31]; const float* l1f_wh = (const float*)d_in[32]; const float* l1f_b = (const float*)d_in[33];
  const float* l1r_wx  = (const float*)d_in[34]; const float* l1r_wh = (const float*)d_in[35]; const float* l1r_b = (const float*)d_in[36];
  const float* l2f_wx  = (const float*)d_in[37]; const float* l2f_wh = (const float*)d_in[38]; const float* l2f_b = (const float*)d_in[39];
  const float* l2r_wx  = (const float*)d_in[40]; const float* l2r_wh = (const float*)d_in[41]; const float* l2r_b = (const float*)d_in[42];
  const float* wo      = (const float*)d_in[43]; const float* bo = (const float*)d_in[44];
  float* outp = (float*)d_out;

  char* base = (char*)d_ws;
  half_t* actA = (half_t*)base;
  half_t* actB = (half_t*)(base + 67108864);
  half_t* wtA  = (half_t*)(base + 100663296);
  float*  f32a = (float*)(base + 143687680);
  half_t* h16a = (half_t*)(base + 158736384);

  half_t* wt2  = wtA;
  half_t* wt3  = wtA + 73728;
  half_t* wt4  = wtA + 368640;
  half_t* wt5  = wtA + 958464;
  half_t* wt6  = wtA + 2138112;
  half_t* wt7  = wtA + 4497408;
  half_t* wtq  = wtA + 5545984;        // wtq|wtk|wtv contiguous -> [1536][7680]
  half_t* wtk  = wtA + 9478144;
  half_t* wtv  = wtA + 13410304;
  half_t* wt1f = wtA + 17342464;
  half_t* wt1r = wtA + 17866752;
  half_t* wt2f = wtA + 18391040;
  half_t* wt2r = wtA + 19439616;
  half_t* wto  = wtA + 20488192;

  float* qkvbuf = f32a;                // 480 x 1536 f32
  float* pre1f = f32a + 737280;
  float* pre1r = f32a + 1228800;
  float* pre2f = f32a + 1720320;
  float* pre2r = f32a + 2703360;

  half_t* ao  = h16a;
  half_t* x1  = h16a + 245760;
  half_t* x2  = h16a + 491520;
  half_t* hb1 = h16a + 983040;              // 2 x 32 x 256 fp16
  half_t* hb2 = hb1 + 16384;                // 2 x 32 x 512 fp16
  int*    flags1 = (int*)(hb2 + 32768);     // 512 ints
  int*    flags2 = flags1 + 512;
  half_t* zbuf   = (half_t*)(flags2 + 512); // 32 halves
  float*  bnz    = (float*)(zbuf + 32);     // 5 x 2048 floats

  auto convm = [&](const half_t* in, const half_t* wt, const float* b, void* out,
                   int N,int H,int W,int Ci,int Ho,int Wo,int Co,
                   int KH,int KW,int pH,int pW,int flags, float* bns){
    int M = N*Ho*Wo, K = KH*KW*Ci;
    dim3 grid(DIV_UP(Co,128), DIV_UP(M,128), 1);
    GOut g{wt, b, out};
    mfma_conv_kernel<<<grid,256,0,stream>>>(in,g,g,g,zbuf,bns,N,H,W,Ci,Ho,Wo,Co,
                                            KH,KW,pH,pW,M,K,flags,1);
  };
  auto gemm3 = [&](const half_t* A, GOut g0, GOut g1, GOut g2, int nz,
                   int M, int Nn, int K, int flags, int splitS){
    dim3 grid(DIV_UP(Nn,128), DIV_UP(M,128), nz);
    mfma_conv_kernel<<<grid,256,0,stream>>>(A,g0,g1,g2,zbuf,bnz,M,1,1,K,1,1,Nn,
                                            1,1,0,0,M,K,flags,splitS);
  };
  auto pool = [&](const half_t* in, half_t* out, int N,int H,int W,int C,
                  int Ho,int Wo,int sH,int sW){
    long total8 = (long)N*Ho*Wo*(C/8);
    maxpool8_kernel<<<(int)DIV_UP(total8,256),256,0,stream>>>(in,out,N,H,W,C,Ho,Wo,sH,sW);
  };
  auto bnApply = [&](half_t* buf, long nPix, int C, const float* s, const float* b,
                     float* sums){
    long total8 = nPix * C / 8;
    bn_apply_relu8_kernel<<<(int)DIV_UP(total8,256),256,0,stream>>>(buf, sums, s, b, total8, C, 1.0f/(float)nPix);
  };
  auto bnPool = [&](const half_t* in, half_t* out, int N,int H,int W,int C,
                    int Ho,int Wo,int sH,int sW, long nPix,
                    const float* s, const float* b, float* sums){
    long total8 = (long)N*Ho*Wo*(C/8);
    bn_pool8_kernel<<<(int)DIV_UP(total8,256),256,0,stream>>>(
        in,out,sums,s,b,N,H,W,C,Ho,Wo,sH,sW,1.0f/(float)nPix);
  };

  // one zero-fill: hb1/hb2, flags, zbuf, 5 bn-sum buffers
  hipMemsetAsync(hb1, 0, 143424, stream);

  // ---- ALL weight transposes in one launch ----
  {
    TpAll tp;
    const float* srcs[14] = {c2w,c3w,c4w,c5w,c6w,c7w,wq,wk,wv,l1f_wx,l1r_wx,l2f_wx,l2r_wx,wo};
    half_t* dsts[14] = {wt2,wt3,wt4,wt5,wt6,wt7,wtq,wtk,wtv,wt1f,wt1r,wt2f,wt2r,wto};
    int Ks[14] = {576,1152,2304,2304,4608,2048,7680,7680,7680,512,512,512,512,1024};
    int Ns[14] = {128,256,256,512,512,512,512,512,512,1024,1024,2048,2048,1000};
    int acc = 0;
    for (int i = 0; i < 14; ++i) {
      tp.src[i] = srcs[i]; tp.dst[i] = dsts[i]; tp.K[i] = Ks[i]; tp.N[i] = Ns[i];
      tp.prefix[i] = acc;
      acc += DIV_UP(Ks[i],32) * DIV_UP(Ns[i],32);
    }
    tp.prefix[14] = acc;
    transpose_cvt_all_kernel<<<acc,256,0,stream>>>(tp);
  }

  // ---- conv stack (activations fp16) ----
  conv1_kernel<<<2048,256,0,stream>>>(x, c1w, c1b, actA);
  pool(actA, actB, 32,64,256,64,  32,128, 2,2);
  convm(actB, wt2, c2b, actA, 32,32,128,64,  32,128,128, 3,3,1,1, FLAG_RELU, bnz);
  pool(actA, actB, 32,32,128,128, 16,64, 2,2);
  convm(actB, wt3, c3b, actA, 32,16,64,128,  16,64,256,  3,3,1,1, FLAG_BNSUMS, bnz);
  bnApply(actA, 32768, 256, bn1s, bn1b, bnz);
  convm(actA, wt4, c4b, actB, 32,16,64,256,  16,64,256,  3,3,1,1, FLAG_BNSUMS, bnz + 2048);
  bnPool(actB, actA, 32,16,64,256, 16,32, 1,2, 32768, bn2s, bn2b, bnz + 2048);
  convm(actA, wt5, c5b, actB, 32,16,32,256,  16,32,512,  3,3,1,1, FLAG_BNSUMS, bnz + 4096);
  bnApply(actB, 16384, 512, bn3s, bn3b, bnz + 4096);
  convm(actB, wt6, c6b, actA, 32,16,32,512,  16,32,512,  3,3,1,1, FLAG_BNSUMS, bnz + 6144);
  bnPool(actA, actB, 32,16,32,512, 16,16, 1,2, 16384, bn4s, bn4b, bnz + 6144);
  convm(actB, wt7, c7b, actA, 32,16,16,512,  15,15,512,  2,2,0,0, FLAG_BNSUMS, bnz + 8192);
  bnApply(actA, 7200, 512, bn5s, bn5b, bnz + 8192);

  // ---- attention: single qkv GEMM (N=1536), split-K x4, atomic epilogue ----
  bias_fill_kernel<<<DIV_UP(480*1536,256),256,0,stream>>>(qkvbuf, bq, bk, bv, 480*1536);
  gemm3(actA, GOut{wtq, nullptr, qkvbuf}, GOut{wtq, nullptr, qkvbuf},
        GOut{wtq, nullptr, qkvbuf}, 4, 480, 1536, 7680, FLAG_SPLITK|FLAG_ATOMIC, 4);
  attention_kernel<<<32,256,0,stream>>>(qkvbuf, ao, 15, 512, 1536);

  // ---- LSTM stack 1 (H=256) ----
  gemm3(ao, GOut{wt1f, l1f_b, pre1f}, GOut{wt1r, l1r_b, pre1r},
        GOut{wt1r, l1r_b, pre1r}, 2, 480, 1024, 512, FLAG_OUTF32, 1);
  lstm_persistent_kernel<<<16,256,0,stream>>>(
      pre1f, pre1r, l1f_wh, l1r_wh, hb1, x1, flags1, 256, 16, 512, 0, 256);

  // ---- LSTM stack 2 (H=512) ----
  gemm3(x1, GOut{wt2f, l2f_b, pre2f}, GOut{wt2r, l2r_b, pre2r},
        GOut{wt2r, l2r_b, pre2r}, 2, 480, 2048, 512, FLAG_OUTF32, 1);
  lstm_persistent_kernel<<<32,256,0,stream>>>(
      pre2f, pre2r, l2f_wh, l2r_wh, hb2, x2, flags2, 512, 32, 1024, 512, 0);

  // ---- classifier ----
  gemm3(x2, GOut{wto, bo, outp}, GOut{wto, bo, outp}, GOut{wto, bo, outp}, 1,
        480, 1000, 1024, FLAG_OUTF32, 1);
}